// Round 14
// baseline (605.504 us; speedup 1.0000x reference)
//
#include <hip/hip_runtime.h>
#include <hip/hip_bf16.h>

// MoE (img/txt mixture) transformer block for MI355X.
// Round 14: fused attn+wt dispatch was SLOT-limited (3 blocks/CU @41984B smem;
// 768 attn blocks filled all slots). Now smem=32768 (Psm aliases Ksm with an
// extra barrier; QK^T results held in regs) -> 5 blocks/CU. wt_body rebuilt
// conflict-free: XOR-swizzled [k][n] tile, packed 8B writes, u16 column reads.

typedef __hip_bfloat16 bf16;
typedef __attribute__((ext_vector_type(8))) __bf16 bf16x8;
typedef __attribute__((ext_vector_type(4))) float f32x4;

#define DEV __device__ __forceinline__

static constexpr int TT = 1536;
static constexpr int NHQ = 16, NKVH = 8, HDM = 128;

DEV void async_load16(const void* g, void* l) {
  typedef const __attribute__((address_space(1))) void* gas_t;
  typedef __attribute__((address_space(3))) void* las_t;
  __builtin_amdgcn_global_load_lds((gas_t)g, (las_t)l, 16, 0, 0);
}

DEV f32x4 mfma16(bf16x8 a, bf16x8 b, f32x4 c) {
  return __builtin_amdgcn_mfma_f32_16x16x32_bf16(a, b, c, 0, 0, 0);
}

DEV float bf2f(bf16 x) { return __bfloat162float(x); }
DEV bf16  f2bf(float x) { return __float2bfloat16(x); }

// ---------------------------------------------------------------------------
// Weight transpose+convert: f32 [K][N] -> bf16 [N][K]  (conflict-free)
// LDS tile logical [k 64][n 64], phys elem = k*72 + (n ^ (((k>>3)&7)<<3)).
// ---------------------------------------------------------------------------
struct TJob { const float* src; bf16* dst; int K; int N; };
struct TJobs { TJob j[14]; int cum[15]; };

DEV void wt_body(const TJob& jb, int rel, int t, char* smem) {
  bf16* tile = (bf16*)smem;  // 64*72 elems = 9216 B
  int ntc = jb.N >> 6;
  int tr = rel / ntc, tc = rel - tr * ntc;
  int r0 = tr << 6, c0 = tc << 6;  // r0: K offset, c0: N offset
  // phase 1: float4 along N (coalesced), packed 8B LDS write into tile[k][n^]
  #pragma unroll
  for (int i = 0; i < 4; i++) {
    int r = i * 16 + (t >> 4);
    int c = 4 * (t & 15);
    int q = (r >> 3) & 7;
    float4 v = *reinterpret_cast<const float4*>(
        jb.src + (size_t)(r0 + r) * jb.N + c0 + c);
    union { bf16 h[4]; uint2 u; } pk;
    pk.h[0] = f2bf(v.x); pk.h[1] = f2bf(v.y);
    pk.h[2] = f2bf(v.z); pk.h[3] = f2bf(v.w);
    *reinterpret_cast<uint2*>(tile + r * 72 + (c ^ (q << 3))) = pk.u;
  }
  __syncthreads();
  // phase 2: gather 8 k-values (swizzled column), coalesced bf16x8 store
  const __bf16* tb = (const __bf16*)tile;
  #pragma unroll
  for (int i = 0; i < 2; i++) {
    int n = (t >> 3) + 32 * i;
    int kc = t & 7;
    int nswz = n ^ (kc << 3);
    bf16x8 v;
    #pragma unroll
    for (int m = 0; m < 8; m++) v[m] = tb[(kc * 8 + m) * 72 + nswz];
    *reinterpret_cast<bf16x8*>(jb.dst + (size_t)(c0 + n) * jb.K + r0 + kc * 8) = v;
  }
}

__global__ __launch_bounds__(256) void wt_transpose(TJobs P) {
  __shared__ __align__(16) char smem[9216];
  int bid = blockIdx.x;
  int ji = 0;
  while (ji < 13 && bid >= P.cum[ji + 1]) ji++;
  wt_body(P.j[ji], bid - P.cum[ji], threadIdx.x, smem);
}

// bf16 transpose for V: v_all [B*TT][NKVH*HDM] -> vt [B*NKVH][HDM][TT]
__global__ __launch_bounds__(256) void transpose_v(const bf16* __restrict__ v_all,
                                                   bf16* __restrict__ vt) {
  int st = blockIdx.x, ht = blockIdx.y, bk = blockIdx.z;
  int b = bk >> 3, kv = bk & 7;
  __shared__ bf16 tile[64][65];
  int t = threadIdx.x;
  int s0 = st * 64, h0 = ht * 64;
  #pragma unroll
  for (int i = 0; i < 16; i++) {
    int idx = i * 256 + t;
    int r = idx >> 6, c = idx & 63;
    tile[c][r] = v_all[((size_t)(b * TT + s0 + r) * NKVH + kv) * HDM + h0 + c];
  }
  __syncthreads();
  #pragma unroll
  for (int i = 0; i < 16; i++) {
    int idx = i * 256 + t;
    int r = idx >> 6, c = idx & 63;
    vt[((size_t)bk * HDM + h0 + r) * TT + s0 + c] = tile[r][c];
  }
}

// ---------------------------------------------------------------------------
// RMSNorm (single input)
// ---------------------------------------------------------------------------
template <int DV>
__global__ __launch_bounds__(256) void rmsnorm_k(const float* __restrict__ x,
                                                 const float* __restrict__ sc,
                                                 bf16* __restrict__ out) {
  const int D = DV * 1024;
  int row = blockIdx.x, t = threadIdx.x;
  const float4* xr = reinterpret_cast<const float4*>(x + (size_t)row * D);
  float4 v[DV];
  float ss = 0.f;
  #pragma unroll
  for (int i = 0; i < DV; i++) {
    v[i] = xr[t + i * 256];
    ss += v[i].x * v[i].x + v[i].y * v[i].y + v[i].z * v[i].z + v[i].w * v[i].w;
  }
  #pragma unroll
  for (int o = 1; o < 64; o <<= 1) ss += __shfl_xor(ss, o);
  __shared__ float red[4];
  if ((t & 63) == 0) red[t >> 6] = ss;
  __syncthreads();
  float r = rsqrtf((red[0] + red[1] + red[2] + red[3]) * (1.0f / D) + 1e-6f);
  bf16* orow = out + (size_t)row * D;
  #pragma unroll
  for (int i = 0; i < DV; i++) {
    int c = (t + i * 256) * 4;
    orow[c + 0] = f2bf(v[i].x * r * (1.f + sc[c + 0]));
    orow[c + 1] = f2bf(v[i].y * r * (1.f + sc[c + 1]));
    orow[c + 2] = f2bf(v[i].z * r * (1.f + sc[c + 2]));
    orow[c + 3] = f2bf(v[i].w * r * (1.f + sc[c + 3]));
  }
}

// ---------------------------------------------------------------------------
// RMSNorm over (p0+p1+x): fused wo split-K=2 reduce + pre-FFW norm
// ---------------------------------------------------------------------------
template <int DV>
__global__ __launch_bounds__(256) void rmsnorm2_k(
    const float* __restrict__ p0, const float* __restrict__ p1,
    const float* __restrict__ x, const float* __restrict__ sc,
    bf16* __restrict__ out) {
  const int D = DV * 1024;
  int row = blockIdx.x, t = threadIdx.x;
  size_t rb = (size_t)row * (D / 4);
  const float4* r0 = reinterpret_cast<const float4*>(p0) + rb;
  const float4* r1 = reinterpret_cast<const float4*>(p1) + rb;
  const float4* xr = reinterpret_cast<const float4*>(x) + rb;
  float4 v[DV];
  float ss = 0.f;
  #pragma unroll
  for (int i = 0; i < DV; i++) {
    int idx = t + i * 256;
    float4 a = r0[idx], b = r1[idx], e = xr[idx];
    v[i] = make_float4(a.x + b.x + e.x, a.y + b.y + e.y,
                       a.z + b.z + e.z, a.w + b.w + e.w);
    ss += v[i].x * v[i].x + v[i].y * v[i].y + v[i].z * v[i].z + v[i].w * v[i].w;
  }
  #pragma unroll
  for (int o = 1; o < 64; o <<= 1) ss += __shfl_xor(ss, o);
  __shared__ float red[4];
  if ((t & 63) == 0) red[t >> 6] = ss;
  __syncthreads();
  float r = rsqrtf((red[0] + red[1] + red[2] + red[3]) * (1.0f / D) + 1e-6f);
  bf16* orow = out + (size_t)row * D;
  #pragma unroll
  for (int i = 0; i < DV; i++) {
    int c = (t + i * 256) * 4;
    orow[c + 0] = f2bf(v[i].x * r * (1.f + sc[c + 0]));
    orow[c + 1] = f2bf(v[i].y * r * (1.f + sc[c + 1]));
    orow[c + 2] = f2bf(v[i].z * r * (1.f + sc[c + 2]));
    orow[c + 3] = f2bf(v[i].w * r * (1.f + sc[c + 3]));
  }
}

// ---------------------------------------------------------------------------
// RoPE in-place
// ---------------------------------------------------------------------------
__global__ __launch_bounds__(256) void rope_inplace(bf16* __restrict__ x, int lognh,
                                                    float scale) {
  int gid = blockIdx.x * 256 + threadIdx.x;
  int i = gid & 63;
  int rh = gid >> 6;
  int row = rh >> lognh;
  int pos = row >= TT ? row - TT : row;
  float fr = expf(-9.210340371976184f * ((float)(2 * i) * (1.0f / 128.0f)));
  float th = (float)pos * fr;
  float s, c;
  sincosf(th, &s, &c);
  bf16* p = x + (size_t)rh * HDM;
  float x1 = bf2f(p[i]), x2 = bf2f(p[i + 64]);
  p[i]      = f2bf((x1 * c - x2 * s) * scale);
  p[i + 64] = f2bf((x2 * c + x1 * s) * scale);
}

// ---------------------------------------------------------------------------
// 256x256 GEMM - r9 reduced-barrier K-loop (3 barriers/tile). PROVEN.
// ---------------------------------------------------------------------------
struct G8Job {
  const bf16* A; const bf16* B; bf16* Cb; float* Cf;
  int K, N, lda, ldb;
  int a_base, a_lsh, a_lskip;
  int c_base, c_lsh, c_lskip, c_stride;
};
struct G8Jobs { G8Job j[8]; int cum[9]; int nj; };

#define G8_MFMA(MH, NH)                                            \
  __builtin_amdgcn_s_setprio(1);                                   \
  _Pragma("unroll")                                                \
  for (int i = 0; i < 4; i++)                                      \
    _Pragma("unroll")                                              \
    for (int nj2 = 0; nj2 < 2; nj2++)                              \
      _Pragma("unroll")                                            \
      for (int kk = 0; kk < 2; kk++)                               \
        acc[(MH)*4 + i][(NH)*2 + nj2] = mfma16(                    \
            afr[i][kk], bfr[(NH)*2 + nj2][kk],                     \
            acc[(MH)*4 + i][(NH)*2 + nj2]);                        \
  __builtin_amdgcn_s_setprio(0);

__global__ __launch_bounds__(512, 2) void gemm8(G8Jobs P) {
  extern __shared__ __align__(16) bf16 lds8[];
  int bid = blockIdx.x;
  int ji = 0;
  while (ji < P.nj - 1 && bid >= P.cum[ji + 1]) ji++;
  const G8Job jb = P.j[ji];
  int rel = bid - P.cum[ji];
  int tn = jb.N >> 8;
  int bm = rel / tn, bn = rel - bm * tn;
  const int m0 = bm << 8, n0 = bn << 8;
  const int K = jb.K;
  const int nk = K >> 6;

  const int tid = threadIdx.x;
  const int w = tid >> 6, l = tid & 63;
  const int lr = l & 15, lk = l >> 4;
  const int wr = w >> 2, wc = w & 3;

  const int r0 = tid >> 3, sl0 = (tid & 7) ^ (r0 & 7);
  const int dst0 = (w * 64) * 8;
  const int dst1 = (512 + w * 64) * 8;

  auto stage = [&](int ht, int hq) {
    int k0 = ht << 6;
    bf16* ldsb = lds8 + ((ht & 1) * 32768 + hq * 8192);
    if (hq < 2) {
      int ma = m0 + hq * 128;
      int mr0 = ma + r0, mr1 = ma + 64 + r0;
      int pr0 = jb.a_base + mr0 + ((mr0 >> jb.a_lsh) * jb.a_lskip);
      int pr1 = jb.a_base + mr1 + ((mr1 >> jb.a_lsh) * jb.a_lskip);
      async_load16(jb.A + (size_t)pr0 * jb.lda + k0 + sl0 * 8, ldsb + dst0);
      async_load16(jb.A + (size_t)pr1 * jb.lda + k0 + sl0 * 8, ldsb + dst1);
    } else {
      int nb = n0 + (hq - 2) * 128;
      async_load16(jb.B + (size_t)(nb + r0) * jb.ldb + k0 + sl0 * 8, ldsb + dst0);
      async_load16(jb.B + (size_t)(nb + 64 + r0) * jb.ldb + k0 + sl0 * 8, ldsb + dst1);
    }
  };

  f32x4 acc[8][4];
  #pragma unroll
  for (int i = 0; i < 8; i++)
    #pragma unroll
    for (int j = 0; j < 4; j++) acc[i][j] = (f32x4){0.f, 0.f, 0.f, 0.f};

  const int s0 = ((0 * 4 + lk) ^ (lr & 7)) * 8;
  const int s1 = ((1 * 4 + lk) ^ (lr & 7)) * 8;
  const int browb = (wc & 1) * 64;

  #pragma unroll
  for (int hq = 0; hq < 4; hq++) stage(0, hq);
  #pragma unroll
  for (int hq = 0; hq < 4; hq++) stage(1, hq);
  asm volatile("s_waitcnt vmcnt(8)" ::: "memory");
  __builtin_amdgcn_s_barrier();
  asm volatile("" ::: "memory");

  bf16x8 afr[4][2], bfr[4][2];

  for (int t = 0; t < nk; t++) {
    const bf16* bufA = lds8 + (t & 1) * 32768 + wr * 8192;
    const bf16* bufB = lds8 + (t & 1) * 32768 + 16384 + (wc >> 1) * 8192;
    const bool st = (t + 2 < nk);

    #pragma unroll
    for (int i = 0; i < 4; i++) {
      int rb = (i * 16 + lr) * 64;
      afr[i][0] = *reinterpret_cast<const bf16x8*>(bufA + rb + s0);
      afr[i][1] = *reinterpret_cast<const bf16x8*>(bufA + rb + s1);
    }
    #pragma unroll
    for (int ni = 0; ni < 2; ni++) {
      int rb = (browb + ni * 16 + lr) * 64;
      bfr[ni][0] = *reinterpret_cast<const bf16x8*>(bufB + rb + s0);
      bfr[ni][1] = *reinterpret_cast<const bf16x8*>(bufB + rb + s1);
    }
    asm volatile("s_waitcnt lgkmcnt(0)" ::: "memory");
    __builtin_amdgcn_sched_barrier(0);
    G8_MFMA(0, 0)

    #pragma unroll
    for (int ni = 2; ni < 4; ni++) {
      int rb = (browb + ni * 16 + lr) * 64;
      bfr[ni][0] = *reinterpret_cast<const bf16x8*>(bufB + rb + s0);
      bfr[ni][1] = *reinterpret_cast<const bf16x8*>(bufB + rb + s1);
    }
    asm volatile("s_waitcnt lgkmcnt(0)" ::: "memory");
    __builtin_amdgcn_sched_barrier(0);
    G8_MFMA(0, 1)
    __builtin_amdgcn_s_barrier();
    asm volatile("" ::: "memory");

    #pragma unroll
    for (int i = 0; i < 4; i++) {
      int rb = ((i + 4) * 16 + lr) * 64;
      afr[i][0] = *reinterpret_cast<const bf16x8*>(bufA + rb + s0);
      afr[i][1] = *reinterpret_cast<const bf16x8*>(bufA + rb + s1);
    }
    if (st) { stage(t + 2, 2); stage(t + 2, 3); }
    asm volatile("s_waitcnt lgkmcnt(0)" ::: "memory");
    __builtin_amdgcn_sched_barrier(0);
    G8_MFMA(1, 0)
    __builtin_amdgcn_s_barrier();
    asm volatile("" ::: "memory");

    if (st) {
      stage(t + 2, 0); stage(t + 2, 1);
      asm volatile("s_waitcnt vmcnt(8)" ::: "memory");
    } else if (t == nk - 2) {
      asm volatile("s_waitcnt vmcnt(0)" ::: "memory");
    }
    G8_MFMA(1, 1)
    __builtin_amdgcn_s_barrier();
    asm volatile("" ::: "memory");
  }

  if (jb.Cf) {
    #pragma unroll
    for (int mi = 0; mi < 8; mi++)
      #pragma unroll
      for (int jj = 0; jj < 4; jj++) {
        int m = m0 + wr * 128 + mi * 16 + lk * 4 + jj;
        float* drow = jb.Cf + (size_t)m * jb.c_stride + n0 + wc * 64;
        #pragma unroll
        for (int ni = 0; ni < 4; ni++) drow[ni * 16 + lr] = acc[mi][ni][jj];
      }
  } else {
    #pragma unroll
    for (int mi = 0; mi < 8; mi++)
      #pragma unroll
      for (int jj = 0; jj < 4; jj++) {
        int m = m0 + wr * 128 + mi * 16 + lk * 4 + jj;
        int crow = jb.c_base + m + ((m >> jb.c_lsh) * jb.c_lskip);
        bf16* drow = jb.Cb + (size_t)crow * jb.c_stride + n0 + wc * 64;
        #pragma unroll
        for (int ni = 0; ni < 4; ni++) drow[ni * 16 + lr] = f2bf(acc[mi][ni][jj]);
      }
  }
}

// ---------------------------------------------------------------------------
// Down split-K reduce: img out += p1+p2+p3+x ; txt out += q1..q7+x
// ---------------------------------------------------------------------------
__global__ __launch_bounds__(256) void reduce_down(
    float* __restrict__ oi, const float* __restrict__ a1,
    const float* __restrict__ a2, const float* __restrict__ a3,
    const float* __restrict__ xi, int n4i,
    float* __restrict__ ot, const float* __restrict__ b1,
    const float* __restrict__ b2, const float* __restrict__ b3,
    const float* __restrict__ b4, const float* __restrict__ b5,
    const float* __restrict__ b6, const float* __restrict__ b7,
    const float* __restrict__ xt, int n4t) {
  int tot = n4i + n4t;
  for (int idx = blockIdx.x * 256 + threadIdx.x; idx < tot; idx += gridDim.x * 256) {
    if (idx < n4i) {
      float4 d = ((const float4*)oi)[idx];
      float4 a = ((const float4*)a1)[idx];
      float4 b = ((const float4*)a2)[idx];
      float4 c = ((const float4*)a3)[idx];
      float4 e = ((const float4*)xi)[idx];
      ((float4*)oi)[idx] = make_float4(d.x + a.x + b.x + c.x + e.x,
                                       d.y + a.y + b.y + c.y + e.y,
                                       d.z + a.z + b.z + c.z + e.z,
                                       d.w + a.w + b.w + c.w + e.w);
    } else {
      int i = idx - n4i;
      float4 d = ((const float4*)ot)[i];
      float4 p1 = ((const float4*)b1)[i];
      float4 p2 = ((const float4*)b2)[i];
      float4 p3 = ((const float4*)b3)[i];
      float4 p4 = ((const float4*)b4)[i];
      float4 p5 = ((const float4*)b5)[i];
      float4 p6 = ((const float4*)b6)[i];
      float4 p7 = ((const float4*)b7)[i];
      float4 e = ((const float4*)xt)[i];
      ((float4*)ot)[i] = make_float4(
          d.x + p1.x + p2.x + p3.x + p4.x + p5.x + p6.x + p7.x + e.x,
          d.y + p1.y + p2.y + p3.y + p4.y + p5.y + p6.y + p7.y + e.y,
          d.z + p1.z + p2.z + p3.z + p4.z + p5.z + p6.z + p7.z + e.z,
          d.w + p1.w + p2.w + p3.w + p4.w + p5.w + p6.w + p7.w + e.w);
    }
  }
}

// ---------------------------------------------------------------------------
// In-place GELU(gate)*up over gu buffers: act written to gate half.
// ---------------------------------------------------------------------------
__global__ __launch_bounds__(256) void gelu_mul(bf16* __restrict__ gu_i,
                                                bf16* __restrict__ gu_t) {
  const int IMG_CH = 2048 * 8192 / 8;
  const int TXT_CH = 1024 * 4096 / 8;
  int idx = blockIdx.x * 256 + threadIdx.x;
  int total = IMG_CH + TXT_CH;
  if (idx >= total) return;
  bf16* base;
  int half, ci;
  if (idx < IMG_CH) { base = gu_i; half = 8192; ci = idx; }
  else              { base = gu_t; half = 4096; ci = idx - IMG_CH; }
  int rowlen = half * 2;
  int perrow = half / 8;
  int m = ci / perrow, n8 = ci - m * perrow;
  bf16* gp = base + (size_t)m * rowlen + n8 * 8;
  bf16* up = gp + half;
  bf16x8 g8 = *reinterpret_cast<const bf16x8*>(gp);
  bf16x8 u8 = *reinterpret_cast<const bf16x8*>(up);
  bf16x8 o8;
  #pragma unroll
  for (int i = 0; i < 8; i++) {
    float g = (float)g8[i], u = (float)u8[i];
    float t = tanhf(0.7978845608028654f * (g + 0.044715f * g * g * g));
    o8[i] = (__bf16)(0.5f * g * (1.f + t) * u);
  }
  *reinterpret_cast<bf16x8*>(gp) = o8;
}

// ---------------------------------------------------------------------------
// Fused: attention (blocks 0..767) + FFN weight transpose (blocks 768+).
// smem = 32768: Ksm [0,16K) (Psm aliases it), Vsm [16K,32K).
// Per tile: load K,V -> bar -> QK^T into regs -> bar (K reads retired) ->
// softcap/exp -> P into old-K space -> PV. Loop-top bar fences next K load.
// ---------------------------------------------------------------------------
struct FAArgs {
  const bf16* q_all; const bf16* k_all; const bf16* vt; bf16* attn_o;
  TJob j[6]; int cum[7];
};

__global__ __launch_bounds__(256) void attn_wt(FAArgs A) {
  __shared__ __align__(16) char smem[32768];
  const int bid = blockIdx.x;
  const int tid = threadIdx.x;
  if (bid >= 768) {
    int rel = bid - 768;
    int ji = 0;
    while (ji < 5 && rel >= A.cum[ji + 1]) ji++;
    wt_body(A.j[ji], rel - A.cum[ji], tid, smem);
    return;
  }
  // ---- attention ----
  const int qt = bid % 24;
  const int n = (bid / 24) & 15;
  const int b = bid / 384;
  const int kv = n >> 1;
  const int w = tid >> 6, l = tid & 63;
  const int lr = l & 15, lk = l >> 4;
  bf16* Ksm = (bf16*)smem;                   // [0, 16384)
  bf16* Vsm = (bf16*)(smem + 16384);         // [16384, 32768)
  typedef bf16 PsmRow[16][72];
  PsmRow* Psm = (PsmRow*)smem;               // aliases Ksm (9216 B)

  bf16x8 qf[4];
  {
    int t = qt * 64 + w * 16 + lr;
    const bf16* qp = A.q_all + ((size_t)(b * TT + t) * NHQ + n) * HDM;
    #pragma unroll
    for (int kk = 0; kk < 4; kk++)
      qf[kk] = *reinterpret_cast<const bf16x8*>(qp + kk * 32 + lk * 8);
  }
  f32x4 acc_o[8];
  #pragma unroll
  for (int i = 0; i < 8; i++) acc_o[i] = (f32x4){0.f, 0.f, 0.f, 0.f};
  float den[4] = {0.f, 0.f, 0.f, 0.f};

  for (int st = 0; st < TT / 64; st++) {
    __syncthreads();   // prev tile's Psm/Vsm consumers done
    #pragma unroll
    for (int i = 0; i < 4; i++) {
      int cb = (w * 4 + i) * 64;
      int c = cb + l;
      {
        int srow = c >> 4, c16 = c & 15;
        const bf16* g = A.k_all +
                        ((size_t)(b * TT + st * 64 + srow) * NKVH + kv) * HDM +
                        ((c16 ^ (srow & 7)) << 3);
        async_load16(g, Ksm + cb * 8);
      }
      {
        int hrow = c >> 3, c8 = c & 7;
        const bf16* g = A.vt + ((size_t)(b * NKVH + kv) * HDM + hrow) * TT +
                        st * 64 + ((c8 ^ (hrow & 7)) << 3);
        async_load16(g, Vsm + cb * 8);
      }
    }
    __syncthreads();
    // QK^T fully into registers
    f32x4 sq[4];
    #pragma unroll
    for (int sf = 0; sf < 4; sf++) {
      f32x4 s4 = (f32x4){0.f, 0.f, 0.f, 0.f};
      int sl = sf * 16 + lr;
      #pragma unroll
      for (int kk = 0; kk < 4; kk++) {
        int e = kk * 32 + lk * 8;
        bf16x8 kf = *reinterpret_cast<const bf16x8*>(
            Ksm + sl * 128 + ((((e >> 3) ^ (sl & 7))) << 3));
        s4 = mfma16(qf[kk], kf, s4);
      }
      sq[sf] = s4;
    }
    __syncthreads();   // all K reads retired -> Psm (alias) writable
    #pragma unroll
    for (int sf = 0; sf < 4; sf++) {
      #pragma unroll
      for (int j = 0; j < 4; j++) {
        float xv = sq[sf][j];
        float tcap = tanhf(xv * 0.02f) * 50.f;
        float p = __expf(tcap);
        Psm[w][lk * 4 + j][sf * 16 + lr] = f2bf(p);
        p += __shfl_xor(p, 1);
        p += __shfl_xor(p, 2);
        p += __shfl_xor(p, 4);
        p += __shfl_xor(p, 8);
        den[j] += p;
      }
    }
    #pragma unroll
    for (int kk2 = 0; kk2 < 2; kk2++) {
      bf16x8 pa = *reinterpret_cast<const bf16x8*>(&Psm[w][lr][kk2 * 32 + lk * 8]);
      #pragma unroll
      for (int hf = 0; hf < 8; hf++) {
        int h = hf * 16 + lr;
        int e2 = kk2 * 32 + lk * 8;
        bf16x8 vb = *reinterpret_cast<const bf16x8*>(
            Vsm + h * 64 + ((((e2 >> 3) ^ (h & 7))) << 3));
        acc_o[hf] = mfma16(pa, vb, acc_o[hf]);
      }
    }
  }
  #pragma unroll
  for (int hf = 0; hf < 8; hf++)
    #pragma unroll
    for (int j = 0; j < 4; j++) {
      int t = qt * 64 + w * 16 + lk * 4 + j;
      float val = acc_o[hf][j] / den[j];
      A.attn_o[((size_t)(b * TT + t)) * (NHQ * HDM) + n * HDM + hf * 16 + lr] =
          f2bf(val);
    }
}

// ---------------------------------------------------------------------------
extern "C" void kernel_launch(void* const* d_in, const int* in_sizes, int n_in,
                              void* d_out, int out_size, void* d_ws,
                              size_t ws_size, hipStream_t stream) {
  const float* x_img = (const float*)d_in[0];
  const float* x_txt = (const float*)d_in[1];
  const float* sc_attn_i = (const float*)d_in[3];
  const float* wq_i = (const float*)d_in[4];
  const float* wk_i = (const float*)d_in[5];
  const float* wv_i = (const float*)d_in[6];
  const float* wo_i = (const float*)d_in[7];
  const float* sc_ffw_i = (const float*)d_in[8];
  const float* wg_i = (const float*)d_in[9];
  const float* wu_i = (const float*)d_in[10];
  const float* wd_i = (const float*)d_in[11];
  const float* sc_attn_t = (const float*)d_in[12];
  const float* wq_t = (const float*)d_in[13];
  const float* wk_t = (const float*)d_in[14];
  const float* wv_t = (const float*)d_in[15];
  const float* wo_t = (const float*)d_in[16];
  const float* sc_ffw_t = (const float*)d_in[17];
  const float* wg_t = (const float*)d_in[18];
  const float* wu_t = (const float*)d_in[19];
  const float* wd_t = (const float*)d_in[20];
  float* outp = (float*)d_out;
  float* outp_t = outp + (size_t)2 * 1024 * 2048;

  char* ws = (char*)d_ws;
  size_t off = 0;
  auto alloc = [&](size_t n) {
    char* p = ws + off;
    off += (n + 255) & ~(size_t)255;
    return p;
  };
  bf16* WqT_i = (bf16*)alloc((size_t)2048 * 2048 * 2);
  bf16* WkT_i = (bf16*)alloc((size_t)1024 * 2048 * 2);
  bf16* WvT_i = (bf16*)alloc((size_t)1024 * 2048 * 2);
  bf16* WoT_i = (bf16*)alloc((size_t)2048 * 2048 * 2);
  bf16* WguT_i = (bf16*)alloc((size_t)16384 * 2048 * 2);  // 64 MB
  bf16* WdT_i = (bf16*)alloc((size_t)2048 * 8192 * 2);
  bf16* WqT_t = (bf16*)alloc((size_t)2048 * 1024 * 2);
  bf16* WkT_t = (bf16*)alloc((size_t)1024 * 1024 * 2);
  bf16* WvT_t = (bf16*)alloc((size_t)1024 * 1024 * 2);
  bf16* WoT_t = (bf16*)alloc((size_t)1024 * 2048 * 2);
  bf16* WguT_t = (bf16*)alloc((size_t)8192 * 1024 * 2);   // 16 MB
  bf16* WdT_t = (bf16*)alloc((size_t)1024 * 4096 * 2);
  bf16* xn_i = (bf16*)alloc((size_t)2048 * 2048 * 2);
  bf16* xn_t = (bf16*)alloc((size_t)1024 * 1024 * 2);
  float* h_i = (float*)alloc((size_t)2048 * 2048 * 4);  // wo p0 img
  float* h_t = (float*)alloc((size_t)1024 * 1024 * 4);  // wo p0 txt
  char* S = (char*)alloc((size_t)84 * 1024 * 1024);
  (void)ws_size;

  const size_t MB = 1024 * 1024;
  bf16* q_all = (bf16*)S;
  bf16* k_all = (bf16*)(S + 12 * MB);
  bf16* v_all = (bf16*)(S + 18 * MB);
  bf16* vtr   = (bf16*)(S + 24 * MB);
  bf16* attn_o= (bf16*)(S + 30 * MB);
  float* wp1_i = (float*)S;
  float* wp1_t = (float*)(S + 16 * MB);
  bf16* gu_i  = (bf16*)S;
  bf16* gu_t  = (bf16*)(S + 64 * MB);
  float* dp1 = (float*)WguT_i;
  float* dp2 = (float*)((char*)WguT_i + 16 * MB);
  float* dp3 = (float*)((char*)WguT_i + 32 * MB);
  float* dt1 = (float*)((char*)WguT_i + 48 * MB);
  float* dt2 = (float*)((char*)WguT_i + 52 * MB);
  float* dt3 = (float*)((char*)WguT_i + 56 * MB);
  float* dt4 = (float*)((char*)WguT_i + 60 * MB);
  float* dt5 = (float*)WguT_t;
  float* dt6 = (float*)((char*)WguT_t + 4 * MB);
  float* dt7 = (float*)((char*)WguT_t + 8 * MB);

  (void)hipFuncSetAttribute(reinterpret_cast<const void*>(gemm8),
                            hipFuncAttributeMaxDynamicSharedMemorySize, 131072);

  // 1. transpose attn weights only (4608 blocks)
  TJobs tj;
  auto setj = [&](int idx, const float* s, bf16* d, int K, int N) {
    tj.j[idx].src = s; tj.j[idx].dst = d; tj.j[idx].K = K; tj.j[idx].N = N;
  };
  setj(0, wq_i, WqT_i, 2048, 2048);
  setj(1, wk_i, WkT_i, 2048, 1024);
  setj(2, wv_i, WvT_i, 2048, 1024);
  setj(3, wo_i, WoT_i, 2048, 2048);
  setj(4, wq_t, WqT_t, 1024, 2048);
  setj(5, wk_t, WkT_t, 1024, 1024);
  setj(6, wv_t, WvT_t, 1024, 1024);
  setj(7, wo_t, WoT_t, 2048, 1024);
  tj.cum[0] = 0;
  for (int i = 0; i < 8; i++)
    tj.cum[i + 1] = tj.cum[i] + (tj.j[i].K >> 6) * (tj.j[i].N >> 6);
  for (int i = 8; i < 14; i++) tj.cum[i + 1] = tj.cum[8];
  wt_transpose<<<tj.cum[8], 256, 0, stream>>>(tj);

  // 2. pre-attn RMSNorm
  rmsnorm_k<2><<<2048, 256, 0, stream>>>(x_img, sc_attn_i, xn_i);
  rmsnorm_k<1><<<1024, 256, 0, stream>>>(x_txt, sc_attn_t, xn_t);

  auto mk8b = [](const bf16* A, const bf16* B, bf16* Cb, int K, int N, int lda,
                 int ldb, int ab, int ash, int ask, int cb2, int csh, int csk,
                 int cstr) {
    G8Job g{};
    g.A = A; g.B = B; g.Cb = Cb; g.Cf = nullptr;
    g.K = K; g.N = N; g.lda = lda; g.ldb = ldb;
    g.a_base = ab; g.a_lsh = ash; g.a_lskip = ask;
    g.c_base = cb2; g.c_lsh = csh; g.c_lskip = csk; g.c_stride = cstr;
    return g;
  };
  auto mk8f = [](const bf16* A, const bf16* B, float* Cf, int K, int N, int lda,
                 int ldb, int ab, int ash, int ask, int cstr) {
    G8Job g{};
    g.A = A; g.B = B; g.Cb = nullptr; g.Cf = Cf;
    g.K = K; g.N = N; g.lda = lda; g.ldb = ldb;
    g.a_base = ab; g.a_lsh = ash; g.a_lskip = ask;
    g.c_base = 0; g.c_lsh = 30; g.c_lskip = 0; g.c_stride = cstr;
    return g;
  };
  auto launch8 = [&](G8Jobs& P, int nj, const int* Mt) {
    P.nj = nj;
    P.cum[0] = 0;
    for (int i = 0; i < nj; i++) P.cum[i + 1] = P.cum[i] + Mt[i] * (P.j[i].N >> 8);
    gemm8<<<P.cum[nj], 512, 131072, stream>>>(P);
  };

  // 3. QKV via gemm8
  {
    G8Jobs P;
    P.j[0] = mk8b(xn_i, WqT_i, q_all, 2048, 2048, 2048, 2048, 0, 30, 0, 0, 10, 512, 2048);
    P.j[1] = mk8b(xn_i, WkT_i, k_all, 2048, 1024, 2048, 2048, 0, 30, 0, 0, 10, 512, 1024);
    P.j[2] = mk8b(xn_i, WvT_i, v_all, 2048, 1024, 2048, 2048, 0, 30, 0, 0, 10, 512, 1024);
    P.j[3] = mk8b(xn_t, WqT_t, q_all, 1024, 2048, 1024, 1024, 0, 30, 0, 1024, 9, 1024, 2048);
    P.j[4] = mk8b(xn_t, WkT_t, k_all, 1024, 1024, 1024, 1024, 0, 30, 0, 1024, 9, 1024, 1024);
    P.j[5] = mk8b(xn_t, WvT_t, v_all, 1024, 1024, 1024, 1024, 0, 30, 0, 1024, 9, 1024, 1024);
    int Mt[6] = {8, 8, 8, 4, 4, 4};
    launch8(P, 6, Mt);
  }

  // 4. RoPE
  rope_inplace<<<12288, 256, 0, stream>>>(q_all, 4, 0.08838834764831845f);
  rope_inplace<<<6144, 256, 0, stream>>>(k_all, 3, 1.0f);

  // 5. V transpose
  transpose_v<<<dim3(24, 2, 16), 256, 0, stream>>>(v_all, vtr);

  // 6. attention + FFN weight transpose fused (768 + 15360 blocks)
  {
    FAArgs A;
    A.q_all = q_all; A.k_all = k_all; A.vt = vtr; A.attn_o = attn_o;
    auto setf = [&](int idx, const float* s, bf16* d, int K, int N) {
      A.j[idx].src = s; A.j[idx].dst = d; A.j[idx].K = K; A.j[idx].N = N;
    };
    setf(0, wg_i, WguT_i, 2048, 8192);
    setf(1, wu_i, WguT_i + (size_t)8192 * 2048, 2048, 8192);
    setf(2, wd_i, WdT_i, 8192, 2048);
    setf(3, wg_t, WguT_t, 1024, 4096);
    setf(4, wu_t, WguT_t + (size_t)4096 * 1024, 1024, 4096);
    setf(5, wd_t, WdT_t, 4096, 1024);
    A.cum[0] = 0;
    for (int i = 0; i < 6; i++)
      A.cum[i + 1] = A.cum[i] + (A.j[i].K >> 6) * (A.j[i].N >> 6);
    attn_wt<<<768 + A.cum[6], 256, 0, stream>>>(A);
  }

  // 7. WO split-K=2 (160 blocks): p0 -> h, p1 -> wp1
  {
    G8Jobs P;
    P.j[0] = mk8f(attn_o,        WoT_i,        h_i,   1024, 2048, 2048, 2048, 0, 10, 512, 2048);
    P.j[1] = mk8f(attn_o + 1024, WoT_i + 1024, wp1_i, 1024, 2048, 2048, 2048, 0, 10, 512, 2048);
    P.j[2] = mk8f(attn_o,        WoT_t,        h_t,   1024, 1024, 2048, 2048, 1024, 9, 1024, 1024);
    P.j[3] = mk8f(attn_o + 1024, WoT_t + 1024, wp1_t, 1024, 1024, 2048, 2048, 1024, 9, 1024, 1024);
    int Mt[4] = {8, 8, 4, 4};
    launch8(P, 4, Mt);
  }

  // 8. fused (p0+p1+x) RMSNorm -> xn
  rmsnorm2_k<2><<<2048, 256, 0, stream>>>(h_i, wp1_i, x_img, sc_ffw_i, xn_i);
  rmsnorm2_k<1><<<1024, 256, 0, stream>>>(h_t, wp1_t, x_txt, sc_ffw_t, xn_t);

  // 9. gate|up via gemm8 -> gu (bf16), single launch (640 blocks)
  {
    G8Jobs P;
    P.j[0] = mk8b(xn_i, WguT_i, gu_i, 2048, 16384, 2048, 2048, 0, 30, 0, 0, 30, 0, 16384);
    P.j[1] = mk8b(xn_t, WguT_t, gu_t, 1024, 8192, 1024, 1024, 0, 30, 0, 0, 30, 0, 8192);
    int Mt[2] = {8, 4};
    launch8(P, 2, Mt);
  }
  {
    int total = 2048 * 8192 / 8 + 1024 * 4096 / 8;
    gelu_mul<<<(total + 255) / 256, 256, 0, stream>>>(gu_i, gu_t);
  }

  // 10a. DOWN img split-4 (256 blocks, 1 clean round); p0 -> d_out
  {
    G8Jobs P;
    P.j[0] = mk8f(gu_i,        WdT_i,        outp, 2048, 2048, 16384, 8192, 0, 30, 0, 2048);
    P.j[1] = mk8f(gu_i + 2048, WdT_i + 2048, dp1,  2048, 2048, 16384, 8192, 0, 30, 0, 2048);
    P.j[2] = mk8f(gu_i + 4096, WdT_i + 4096, dp2,  2048, 2048, 16384, 8192, 0, 30, 0, 2048);
    P.j[3] = mk8f(gu_i + 6144, WdT_i + 6144, dp3,  2048, 2048, 16384, 8192, 0, 30, 0, 2048);
    int Mt[4] = {8, 8, 8, 8};
    launch8(P, 4, Mt);
  }
  // 10b. DOWN txt split-8 (128 blocks, short round 2); p0 -> d_out
  {
    G8Jobs P;
    float* dst[8] = {outp_t, dt1, dt2, dt3, dt4, dt5, dt6, dt7};
    for (int s = 0; s < 8; s++)
      P.j[s] = mk8f(gu_t + s * 512, WdT_t + s * 512, dst[s], 512, 1024, 8192,
                    4096, 0, 30, 0, 1024);
    int Mt[8] = {4, 4, 4, 4, 4, 4, 4, 4};
    launch8(P, 8, Mt);
  }
  reduce_down<<<2048, 256, 0, stream>>>(
      outp, dp1, dp2, dp3, x_img, 2048 * 2048 / 4,
      outp_t, dt1, dt2, dt3, dt4, dt5, dt6, dt7, x_txt, 1024 * 1024 / 4);
}

// Round 15
// 602.786 us; speedup vs baseline: 1.0045x; 1.0045x over previous
//
#include <hip/hip_runtime.h>
#include <hip/hip_bf16.h>

// MoE (img/txt mixture) transformer block for MI355X.
// Round 15: attention rebuilt with T14 reg-staged K/V double buffering
// (prefetch t+1 into 32 VGPRs before tile t's compute; raw s_barriers so
// prefetch stays in flight) + fast softcap (50-100/(e^{.04x}+1), no tanhf).
// Swizzle moved to ds_write side; global K/V reads linear. Rest = r14.

typedef __hip_bfloat16 bf16;
typedef __attribute__((ext_vector_type(8))) __bf16 bf16x8;
typedef __attribute__((ext_vector_type(4))) float f32x4;

#define DEV __device__ __forceinline__

static constexpr int TT = 1536;
static constexpr int NHQ = 16, NKVH = 8, HDM = 128;

DEV void async_load16(const void* g, void* l) {
  typedef const __attribute__((address_space(1))) void* gas_t;
  typedef __attribute__((address_space(3))) void* las_t;
  __builtin_amdgcn_global_load_lds((gas_t)g, (las_t)l, 16, 0, 0);
}

DEV f32x4 mfma16(bf16x8 a, bf16x8 b, f32x4 c) {
  return __builtin_amdgcn_mfma_f32_16x16x32_bf16(a, b, c, 0, 0, 0);
}

DEV float bf2f(bf16 x) { return __bfloat162float(x); }
DEV bf16  f2bf(float x) { return __float2bfloat16(x); }

// ---------------------------------------------------------------------------
// Weight transpose+convert: f32 [K][N] -> bf16 [N][K]  (conflict-free)
// ---------------------------------------------------------------------------
struct TJob { const float* src; bf16* dst; int K; int N; };
struct TJobs { TJob j[14]; int cum[15]; };

DEV void wt_body(const TJob& jb, int rel, int t, char* smem) {
  bf16* tile = (bf16*)smem;  // 64*72 elems = 9216 B
  int ntc = jb.N >> 6;
  int tr = rel / ntc, tc = rel - tr * ntc;
  int r0 = tr << 6, c0 = tc << 6;
  #pragma unroll
  for (int i = 0; i < 4; i++) {
    int r = i * 16 + (t >> 4);
    int c = 4 * (t & 15);
    int q = (r >> 3) & 7;
    float4 v = *reinterpret_cast<const float4*>(
        jb.src + (size_t)(r0 + r) * jb.N + c0 + c);
    union { bf16 h[4]; uint2 u; } pk;
    pk.h[0] = f2bf(v.x); pk.h[1] = f2bf(v.y);
    pk.h[2] = f2bf(v.z); pk.h[3] = f2bf(v.w);
    *reinterpret_cast<uint2*>(tile + r * 72 + (c ^ (q << 3))) = pk.u;
  }
  __syncthreads();
  const __bf16* tb = (const __bf16*)tile;
  #pragma unroll
  for (int i = 0; i < 2; i++) {
    int n = (t >> 3) + 32 * i;
    int kc = t & 7;
    int nswz = n ^ (kc << 3);
    bf16x8 v;
    #pragma unroll
    for (int m = 0; m < 8; m++) v[m] = tb[(kc * 8 + m) * 72 + nswz];
    *reinterpret_cast<bf16x8*>(jb.dst + (size_t)(c0 + n) * jb.K + r0 + kc * 8) = v;
  }
}

__global__ __launch_bounds__(256) void wt_transpose(TJobs P) {
  __shared__ __align__(16) char smem[9216];
  int bid = blockIdx.x;
  int ji = 0;
  while (ji < 13 && bid >= P.cum[ji + 1]) ji++;
  wt_body(P.j[ji], bid - P.cum[ji], threadIdx.x, smem);
}

// bf16 transpose for V: v_all [B*TT][NKVH*HDM] -> vt [B*NKVH][HDM][TT]
__global__ __launch_bounds__(256) void transpose_v(const bf16* __restrict__ v_all,
                                                   bf16* __restrict__ vt) {
  int st = blockIdx.x, ht = blockIdx.y, bk = blockIdx.z;
  int b = bk >> 3, kv = bk & 7;
  __shared__ bf16 tile[64][65];
  int t = threadIdx.x;
  int s0 = st * 64, h0 = ht * 64;
  #pragma unroll
  for (int i = 0; i < 16; i++) {
    int idx = i * 256 + t;
    int r = idx >> 6, c = idx & 63;
    tile[c][r] = v_all[((size_t)(b * TT + s0 + r) * NKVH + kv) * HDM + h0 + c];
  }
  __syncthreads();
  #pragma unroll
  for (int i = 0; i < 16; i++) {
    int idx = i * 256 + t;
    int r = idx >> 6, c = idx & 63;
    vt[((size_t)bk * HDM + h0 + r) * TT + s0 + c] = tile[r][c];
  }
}

// ---------------------------------------------------------------------------
// RMSNorm (single input)
// ---------------------------------------------------------------------------
template <int DV>
__global__ __launch_bounds__(256) void rmsnorm_k(const float* __restrict__ x,
                                                 const float* __restrict__ sc,
                                                 bf16* __restrict__ out) {
  const int D = DV * 1024;
  int row = blockIdx.x, t = threadIdx.x;
  const float4* xr = reinterpret_cast<const float4*>(x + (size_t)row * D);
  float4 v[DV];
  float ss = 0.f;
  #pragma unroll
  for (int i = 0; i < DV; i++) {
    v[i] = xr[t + i * 256];
    ss += v[i].x * v[i].x + v[i].y * v[i].y + v[i].z * v[i].z + v[i].w * v[i].w;
  }
  #pragma unroll
  for (int o = 1; o < 64; o <<= 1) ss += __shfl_xor(ss, o);
  __shared__ float red[4];
  if ((t & 63) == 0) red[t >> 6] = ss;
  __syncthreads();
  float r = rsqrtf((red[0] + red[1] + red[2] + red[3]) * (1.0f / D) + 1e-6f);
  bf16* orow = out + (size_t)row * D;
  #pragma unroll
  for (int i = 0; i < DV; i++) {
    int c = (t + i * 256) * 4;
    orow[c + 0] = f2bf(v[i].x * r * (1.f + sc[c + 0]));
    orow[c + 1] = f2bf(v[i].y * r * (1.f + sc[c + 1]));
    orow[c + 2] = f2bf(v[i].z * r * (1.f + sc[c + 2]));
    orow[c + 3] = f2bf(v[i].w * r * (1.f + sc[c + 3]));
  }
}

// ---------------------------------------------------------------------------
// RMSNorm over (p0+p1+x): fused wo split-K=2 reduce + pre-FFW norm
// ---------------------------------------------------------------------------
template <int DV>
__global__ __launch_bounds__(256) void rmsnorm2_k(
    const float* __restrict__ p0, const float* __restrict__ p1,
    const float* __restrict__ x, const float* __restrict__ sc,
    bf16* __restrict__ out) {
  const int D = DV * 1024;
  int row = blockIdx.x, t = threadIdx.x;
  size_t rb = (size_t)row * (D / 4);
  const float4* r0 = reinterpret_cast<const float4*>(p0) + rb;
  const float4* r1 = reinterpret_cast<const float4*>(p1) + rb;
  const float4* xr = reinterpret_cast<const float4*>(x) + rb;
  float4 v[DV];
  float ss = 0.f;
  #pragma unroll
  for (int i = 0; i < DV; i++) {
    int idx = t + i * 256;
    float4 a = r0[idx], b = r1[idx], e = xr[idx];
    v[i] = make_float4(a.x + b.x + e.x, a.y + b.y + e.y,
                       a.z + b.z + e.z, a.w + b.w + e.w);
    ss += v[i].x * v[i].x + v[i].y * v[i].y + v[i].z * v[i].z + v[i].w * v[i].w;
  }
  #pragma unroll
  for (int o = 1; o < 64; o <<= 1) ss += __shfl_xor(ss, o);
  __shared__ float red[4];
  if ((t & 63) == 0) red[t >> 6] = ss;
  __syncthreads();
  float r = rsqrtf((red[0] + red[1] + red[2] + red[3]) * (1.0f / D) + 1e-6f);
  bf16* orow = out + (size_t)row * D;
  #pragma unroll
  for (int i = 0; i < DV; i++) {
    int c = (t + i * 256) * 4;
    orow[c + 0] = f2bf(v[i].x * r * (1.f + sc[c + 0]));
    orow[c + 1] = f2bf(v[i].y * r * (1.f + sc[c + 1]));
    orow[c + 2] = f2bf(v[i].z * r * (1.f + sc[c + 2]));
    orow[c + 3] = f2bf(v[i].w * r * (1.f + sc[c + 3]));
  }
}

// ---------------------------------------------------------------------------
// RoPE in-place
// ---------------------------------------------------------------------------
__global__ __launch_bounds__(256) void rope_inplace(bf16* __restrict__ x, int lognh,
                                                    float scale) {
  int gid = blockIdx.x * 256 + threadIdx.x;
  int i = gid & 63;
  int rh = gid >> 6;
  int row = rh >> lognh;
  int pos = row >= TT ? row - TT : row;
  float fr = expf(-9.210340371976184f * ((float)(2 * i) * (1.0f / 128.0f)));
  float th = (float)pos * fr;
  float s, c;
  sincosf(th, &s, &c);
  bf16* p = x + (size_t)rh * HDM;
  float x1 = bf2f(p[i]), x2 = bf2f(p[i + 64]);
  p[i]      = f2bf((x1 * c - x2 * s) * scale);
  p[i + 64] = f2bf((x2 * c + x1 * s) * scale);
}

// ---------------------------------------------------------------------------
// 256x256 GEMM - r9 reduced-barrier K-loop (3 barriers/tile). PROVEN.
// ---------------------------------------------------------------------------
struct G8Job {
  const bf16* A; const bf16* B; bf16* Cb; float* Cf;
  int K, N, lda, ldb;
  int a_base, a_lsh, a_lskip;
  int c_base, c_lsh, c_lskip, c_stride;
};
struct G8Jobs { G8Job j[8]; int cum[9]; int nj; };

#define G8_MFMA(MH, NH)                                            \
  __builtin_amdgcn_s_setprio(1);                                   \
  _Pragma("unroll")                                                \
  for (int i = 0; i < 4; i++)                                      \
    _Pragma("unroll")                                              \
    for (int nj2 = 0; nj2 < 2; nj2++)                              \
      _Pragma("unroll")                                            \
      for (int kk = 0; kk < 2; kk++)                               \
        acc[(MH)*4 + i][(NH)*2 + nj2] = mfma16(                    \
            afr[i][kk], bfr[(NH)*2 + nj2][kk],                     \
            acc[(MH)*4 + i][(NH)*2 + nj2]);                        \
  __builtin_amdgcn_s_setprio(0);

__global__ __launch_bounds__(512, 2) void gemm8(G8Jobs P) {
  extern __shared__ __align__(16) bf16 lds8[];
  int bid = blockIdx.x;
  int ji = 0;
  while (ji < P.nj - 1 && bid >= P.cum[ji + 1]) ji++;
  const G8Job jb = P.j[ji];
  int rel = bid - P.cum[ji];
  int tn = jb.N >> 8;
  int bm = rel / tn, bn = rel - bm * tn;
  const int m0 = bm << 8, n0 = bn << 8;
  const int K = jb.K;
  const int nk = K >> 6;

  const int tid = threadIdx.x;
  const int w = tid >> 6, l = tid & 63;
  const int lr = l & 15, lk = l >> 4;
  const int wr = w >> 2, wc = w & 3;

  const int r0 = tid >> 3, sl0 = (tid & 7) ^ (r0 & 7);
  const int dst0 = (w * 64) * 8;
  const int dst1 = (512 + w * 64) * 8;

  auto stage = [&](int ht, int hq) {
    int k0 = ht << 6;
    bf16* ldsb = lds8 + ((ht & 1) * 32768 + hq * 8192);
    if (hq < 2) {
      int ma = m0 + hq * 128;
      int mr0 = ma + r0, mr1 = ma + 64 + r0;
      int pr0 = jb.a_base + mr0 + ((mr0 >> jb.a_lsh) * jb.a_lskip);
      int pr1 = jb.a_base + mr1 + ((mr1 >> jb.a_lsh) * jb.a_lskip);
      async_load16(jb.A + (size_t)pr0 * jb.lda + k0 + sl0 * 8, ldsb + dst0);
      async_load16(jb.A + (size_t)pr1 * jb.lda + k0 + sl0 * 8, ldsb + dst1);
    } else {
      int nb = n0 + (hq - 2) * 128;
      async_load16(jb.B + (size_t)(nb + r0) * jb.ldb + k0 + sl0 * 8, ldsb + dst0);
      async_load16(jb.B + (size_t)(nb + 64 + r0) * jb.ldb + k0 + sl0 * 8, ldsb + dst1);
    }
  };

  f32x4 acc[8][4];
  #pragma unroll
  for (int i = 0; i < 8; i++)
    #pragma unroll
    for (int j = 0; j < 4; j++) acc[i][j] = (f32x4){0.f, 0.f, 0.f, 0.f};

  const int s0 = ((0 * 4 + lk) ^ (lr & 7)) * 8;
  const int s1 = ((1 * 4 + lk) ^ (lr & 7)) * 8;
  const int browb = (wc & 1) * 64;

  #pragma unroll
  for (int hq = 0; hq < 4; hq++) stage(0, hq);
  #pragma unroll
  for (int hq = 0; hq < 4; hq++) stage(1, hq);
  asm volatile("s_waitcnt vmcnt(8)" ::: "memory");
  __builtin_amdgcn_s_barrier();
  asm volatile("" ::: "memory");

  bf16x8 afr[4][2], bfr[4][2];

  for (int t = 0; t < nk; t++) {
    const bf16* bufA = lds8 + (t & 1) * 32768 + wr * 8192;
    const bf16* bufB = lds8 + (t & 1) * 32768 + 16384 + (wc >> 1) * 8192;
    const bool st = (t + 2 < nk);

    #pragma unroll
    for (int i = 0; i < 4; i++) {
      int rb = (i * 16 + lr) * 64;
      afr[i][0] = *reinterpret_cast<const bf16x8*>(bufA + rb + s0);
      afr[i][1] = *reinterpret_cast<const bf16x8*>(bufA + rb + s1);
    }
    #pragma unroll
    for (int ni = 0; ni < 2; ni++) {
      int rb = (browb + ni * 16 + lr) * 64;
      bfr[ni][0] = *reinterpret_cast<const bf16x8*>(bufB + rb + s0);
      bfr[ni][1] = *reinterpret_cast<const bf16x8*>(bufB + rb + s1);
    }
    asm volatile("s_waitcnt lgkmcnt(0)" ::: "memory");
    __builtin_amdgcn_sched_barrier(0);
    G8_MFMA(0, 0)

    #pragma unroll
    for (int ni = 2; ni < 4; ni++) {
      int rb = (browb + ni * 16 + lr) * 64;
      bfr[ni][0] = *reinterpret_cast<const bf16x8*>(bufB + rb + s0);
      bfr[ni][1] = *reinterpret_cast<const bf16x8*>(bufB + rb + s1);
    }
    asm volatile("s_waitcnt lgkmcnt(0)" ::: "memory");
    __builtin_amdgcn_sched_barrier(0);
    G8_MFMA(0, 1)
    __builtin_amdgcn_s_barrier();
    asm volatile("" ::: "memory");

    #pragma unroll
    for (int i = 0; i < 4; i++) {
      int rb = ((i + 4) * 16 + lr) * 64;
      afr[i][0] = *reinterpret_cast<const bf16x8*>(bufA + rb + s0);
      afr[i][1] = *reinterpret_cast<const bf16x8*>(bufA + rb + s1);
    }
    if (st) { stage(t + 2, 2); stage(t + 2, 3); }
    asm volatile("s_waitcnt lgkmcnt(0)" ::: "memory");
    __builtin_amdgcn_sched_barrier(0);
    G8_MFMA(1, 0)
    __builtin_amdgcn_s_barrier();
    asm volatile("" ::: "memory");

    if (st) {
      stage(t + 2, 0); stage(t + 2, 1);
      asm volatile("s_waitcnt vmcnt(8)" ::: "memory");
    } else if (t == nk - 2) {
      asm volatile("s_waitcnt vmcnt(0)" ::: "memory");
    }
    G8_MFMA(1, 1)
    __builtin_amdgcn_s_barrier();
    asm volatile("" ::: "memory");
  }

  if (jb.Cf) {
    #pragma unroll
    for (int mi = 0; mi < 8; mi++)
      #pragma unroll
      for (int jj = 0; jj < 4; jj++) {
        int m = m0 + wr * 128 + mi * 16 + lk * 4 + jj;
        float* drow = jb.Cf + (size_t)m * jb.c_stride + n0 + wc * 64;
        #pragma unroll
        for (int ni = 0; ni < 4; ni++) drow[ni * 16 + lr] = acc[mi][ni][jj];
      }
  } else {
    #pragma unroll
    for (int mi = 0; mi < 8; mi++)
      #pragma unroll
      for (int jj = 0; jj < 4; jj++) {
        int m = m0 + wr * 128 + mi * 16 + lk * 4 + jj;
        int crow = jb.c_base + m + ((m >> jb.c_lsh) * jb.c_lskip);
        bf16* drow = jb.Cb + (size_t)crow * jb.c_stride + n0 + wc * 64;
        #pragma unroll
        for (int ni = 0; ni < 4; ni++) drow[ni * 16 + lr] = f2bf(acc[mi][ni][jj]);
      }
  }
}

// ---------------------------------------------------------------------------
// Down split-K reduce: img out += p1+p2+p3+x ; txt out += q1..q7+x
// ---------------------------------------------------------------------------
__global__ __launch_bounds__(256) void reduce_down(
    float* __restrict__ oi, const float* __restrict__ a1,
    const float* __restrict__ a2, const float* __restrict__ a3,
    const float* __restrict__ xi, int n4i,
    float* __restrict__ ot, const float* __restrict__ b1,
    const float* __restrict__ b2, const float* __restrict__ b3,
    const float* __restrict__ b4, const float* __restrict__ b5,
    const float* __restrict__ b6, const float* __restrict__ b7,
    const float* __restrict__ xt, int n4t) {
  int tot = n4i + n4t;
  for (int idx = blockIdx.x * 256 + threadIdx.x; idx < tot; idx += gridDim.x * 256) {
    if (idx < n4i) {
      float4 d = ((const float4*)oi)[idx];
      float4 a = ((const float4*)a1)[idx];
      float4 b = ((const float4*)a2)[idx];
      float4 c = ((const float4*)a3)[idx];
      float4 e = ((const float4*)xi)[idx];
      ((float4*)oi)[idx] = make_float4(d.x + a.x + b.x + c.x + e.x,
                                       d.y + a.y + b.y + c.y + e.y,
                                       d.z + a.z + b.z + c.z + e.z,
                                       d.w + a.w + b.w + c.w + e.w);
    } else {
      int i = idx - n4i;
      float4 d = ((const float4*)ot)[i];
      float4 p1 = ((const float4*)b1)[i];
      float4 p2 = ((const float4*)b2)[i];
      float4 p3 = ((const float4*)b3)[i];
      float4 p4 = ((const float4*)b4)[i];
      float4 p5 = ((const float4*)b5)[i];
      float4 p6 = ((const float4*)b6)[i];
      float4 p7 = ((const float4*)b7)[i];
      float4 e = ((const float4*)xt)[i];
      ((float4*)ot)[i] = make_float4(
          d.x + p1.x + p2.x + p3.x + p4.x + p5.x + p6.x + p7.x + e.x,
          d.y + p1.y + p2.y + p3.y + p4.y + p5.y + p6.y + p7.y + e.y,
          d.z + p1.z + p2.z + p3.z + p4.z + p5.z + p6.z + p7.z + e.z,
          d.w + p1.w + p2.w + p3.w + p4.w + p5.w + p6.w + p7.w + e.w);
    }
  }
}

// ---------------------------------------------------------------------------
// In-place GELU(gate)*up over gu buffers: act written to gate half.
// ---------------------------------------------------------------------------
__global__ __launch_bounds__(256) void gelu_mul(bf16* __restrict__ gu_i,
                                                bf16* __restrict__ gu_t) {
  const int IMG_CH = 2048 * 8192 / 8;
  const int TXT_CH = 1024 * 4096 / 8;
  int idx = blockIdx.x * 256 + threadIdx.x;
  int total = IMG_CH + TXT_CH;
  if (idx >= total) return;
  bf16* base;
  int half, ci;
  if (idx < IMG_CH) { base = gu_i; half = 8192; ci = idx; }
  else              { base = gu_t; half = 4096; ci = idx - IMG_CH; }
  int rowlen = half * 2;
  int perrow = half / 8;
  int m = ci / perrow, n8 = ci - m * perrow;
  bf16* gp = base + (size_t)m * rowlen + n8 * 8;
  bf16* up = gp + half;
  bf16x8 g8 = *reinterpret_cast<const bf16x8*>(gp);
  bf16x8 u8 = *reinterpret_cast<const bf16x8*>(up);
  bf16x8 o8;
  #pragma unroll
  for (int i = 0; i < 8; i++) {
    float g = (float)g8[i], u = (float)u8[i];
    float t = tanhf(0.7978845608028654f * (g + 0.044715f * g * g * g));
    o8[i] = (__bf16)(0.5f * g * (1.f + t) * u);
  }
  *reinterpret_cast<bf16x8*>(gp) = o8;
}

// ---------------------------------------------------------------------------
// Fused: attention (blocks 0..767) + FFN weight transpose (blocks 768+).
// Attention: reg-staged K/V double buffer (T14), raw barriers, fast softcap.
// smem = 32768: Ksm [0,16K) (Psm aliases it), Vsm [16K,32K).
// ---------------------------------------------------------------------------
struct FAArgs {
  const bf16* q_all; const bf16* k_all; const bf16* vt; bf16* attn_o;
  TJob j[6]; int cum[7];
};

__global__ __launch_bounds__(256) void attn_wt(FAArgs A) {
  __shared__ __align__(16) char smem[32768];
  const int bid = blockIdx.x;
  const int tid = threadIdx.x;
  if (bid >= 768) {
    int rel = bid - 768;
    int ji = 0;
    while (ji < 5 && rel >= A.cum[ji + 1]) ji++;
    wt_body(A.j[ji], rel - A.cum[ji], tid, smem);
    return;
  }
  // ---- attention ----
  const int qt = bid % 24;
  const int n = (bid / 24) & 15;
  const int b = bid / 384;
  const int kv = n >> 1;
  const int w = tid >> 6, l = tid & 63;
  const int lr = l & 15, lk = l >> 4;
  bf16* Ksm = (bf16*)smem;                   // [0, 16384)
  bf16* Vsm = (bf16*)(smem + 16384);         // [16384, 32768)
  typedef bf16 PsmRow[16][72];
  PsmRow* Psm = (PsmRow*)smem;               // aliases Ksm (9216 B)

  bf16x8 qf[4];
  {
    int t = qt * 64 + w * 16 + lr;
    const bf16* qp = A.q_all + ((size_t)(b * TT + t) * NHQ + n) * HDM;
    #pragma unroll
    for (int kk = 0; kk < 4; kk++)
      qf[kk] = *reinterpret_cast<const bf16x8*>(qp + kk * 32 + lk * 8);
  }
  // per-thread staging geometry (chunk c = i*256+tid)
  int kwo[4], vwo[4];
  const bf16* kp[4];
  const bf16* vp[4];
  #pragma unroll
  for (int i = 0; i < 4; i++) {
    int c = i * 256 + tid;
    int krow = c >> 4, kcol = c & 15;
    kwo[i] = krow * 128 + ((kcol ^ (krow & 7)) << 3);
    kp[i] = A.k_all + ((size_t)(b * TT + krow) * NKVH + kv) * HDM + kcol * 8;
    int vrow = c >> 3, vcol = c & 7;
    vwo[i] = vrow * 64 + ((vcol ^ (vrow & 7)) << 3);
    vp[i] = A.vt + ((size_t)(b * NKVH + kv) * HDM + vrow) * TT + vcol * 8;
  }
  bf16x8 kreg[4], vreg[4];
  #pragma unroll
  for (int i = 0; i < 4; i++) {
    kreg[i] = *reinterpret_cast<const bf16x8*>(kp[i]); kp[i] += 64 * NKVH * HDM;
    vreg[i] = *reinterpret_cast<const bf16x8*>(vp[i]); vp[i] += 64;
  }

  f32x4 acc_o[8];
  #pragma unroll
  for (int i = 0; i < 8; i++) acc_o[i] = (f32x4){0.f, 0.f, 0.f, 0.f};
  float den[4] = {0.f, 0.f, 0.f, 0.f};

  for (int st = 0; st < TT / 64; st++) {
    // regs for tile st present; prev tile's LDS consumers done
    asm volatile("s_waitcnt vmcnt(0)" ::: "memory");
    __builtin_amdgcn_s_barrier();
    asm volatile("" ::: "memory");
    // ds_write K,V from regs (swizzled dest)
    #pragma unroll
    for (int i = 0; i < 4; i++) {
      *reinterpret_cast<bf16x8*>(Ksm + kwo[i]) = kreg[i];
      *reinterpret_cast<bf16x8*>(Vsm + vwo[i]) = vreg[i];
    }
    // prefetch tile st+1 into regs (stays in flight across barriers)
    if (st + 1 < TT / 64) {
      #pragma unroll
      for (int i = 0; i < 4; i++) {
        kreg[i] = *reinterpret_cast<const bf16x8*>(kp[i]); kp[i] += 64 * NKVH * HDM;
        vreg[i] = *reinterpret_cast<const bf16x8*>(vp[i]); vp[i] += 64;
      }
    }
    asm volatile("s_waitcnt lgkmcnt(0)" ::: "memory");
    __builtin_amdgcn_s_barrier();
    asm volatile("" ::: "memory");
    // QK^T fully into registers
    f32x4 sq[4];
    #pragma unroll
    for (int sf = 0; sf < 4; sf++) {
      f32x4 s4 = (f32x4){0.f, 0.f, 0.f, 0.f};
      int sl = sf * 16 + lr;
      #pragma unroll
      for (int kk = 0; kk < 4; kk++) {
        int e = kk * 32 + lk * 8;
        bf16x8 kf = *reinterpret_cast<const bf16x8*>(
            Ksm + sl * 128 + ((((e >> 3) ^ (sl & 7))) << 3));
        s4 = mfma16(qf[kk], kf, s4);
      }
      sq[sf] = s4;
    }
    asm volatile("s_waitcnt lgkmcnt(0)" ::: "memory");
    __builtin_amdgcn_s_barrier();   // all K reads retired -> Psm writable
    asm volatile("" ::: "memory");
    // fast softcap: 50*tanh(x/50) = 50 - 100/(e^{0.04x}+1); p = exp(that)
    #pragma unroll
    for (int sf = 0; sf < 4; sf++) {
      #pragma unroll
      for (int j = 0; j < 4; j++) {
        float xv = sq[sf][j];
        float e2 = __expf(xv * 0.04f);
        float rr = __builtin_amdgcn_rcpf(e2 + 1.0f);
        float p = __expf(50.0f - 100.0f * rr);
        Psm[w][lk * 4 + j][sf * 16 + lr] = f2bf(p);
        p += __shfl_xor(p, 1);
        p += __shfl_xor(p, 2);
        p += __shfl_xor(p, 4);
        p += __shfl_xor(p, 8);
        den[j] += p;
      }
    }
    #pragma unroll
    for (int kk2 = 0; kk2 < 2; kk2++) {
      bf16x8 pa = *reinterpret_cast<const bf16x8*>(&Psm[w][lr][kk2 * 32 + lk * 8]);
      #pragma unroll
      for (int hf = 0; hf < 8; hf++) {
        int h = hf * 16 + lr;
        int e2i = kk2 * 32 + lk * 8;
        bf16x8 vb = *reinterpret_cast<const bf16x8*>(
            Vsm + h * 64 + ((((e2i >> 3) ^ (h & 7))) << 3));
        acc_o[hf] = mfma16(pa, vb, acc_o[hf]);
      }
    }
  }
  #pragma unroll
  for (int hf = 0; hf < 8; hf++)
    #pragma unroll
    for (int j = 0; j < 4; j++) {
      int t = qt * 64 + w * 16 + lk * 4 + j;
      float val = acc_o[hf][j] / den[j];
      A.attn_o[((size_t)(b * TT + t)) * (NHQ * HDM) + n * HDM + hf * 16 + lr] =
          f2bf(val);
    }
}

// ---------------------------------------------------------------------------
extern "C" void kernel_launch(void* const* d_in, const int* in_sizes, int n_in,
                              void* d_out, int out_size, void* d_ws,
                              size_t ws_size, hipStream_t stream) {
  const float* x_img = (const float*)d_in[0];
  const float* x_txt = (const float*)d_in[1];
  const float* sc_attn_i = (const float*)d_in[3];
  const float* wq_i = (const float*)d_in[4];
  const float* wk_i = (const float*)d_in[5];
  const float* wv_i = (const float*)d_in[6];
  const float* wo_i = (const float*)d_in[7];
  const float* sc_ffw_i = (const float*)d_in[8];
  const float* wg_i = (const float*)d_in[9];
  const float* wu_i = (const float*)d_in[10];
  const float* wd_i = (const float*)d_in[11];
  const float* sc_attn_t = (const float*)d_in[12];
  const float* wq_t = (const float*)d_in[13];
  const float* wk_t = (const float*)d_in[14];
  const float* wv_t = (const float*)d_in[15];
  const float* wo_t = (const float*)d_in[16];
  const float* sc_ffw_t = (const float*)d_in[17];
  const float* wg_t = (const float*)d_in[18];
  const float* wu_t = (const float*)d_in[19];
  const float* wd_t = (const float*)d_in[20];
  float* outp = (float*)d_out;
  float* outp_t = outp + (size_t)2 * 1024 * 2048;

  char* ws = (char*)d_ws;
  size_t off = 0;
  auto alloc = [&](size_t n) {
    char* p = ws + off;
    off += (n + 255) & ~(size_t)255;
    return p;
  };
  bf16* WqT_i = (bf16*)alloc((size_t)2048 * 2048 * 2);
  bf16* WkT_i = (bf16*)alloc((size_t)1024 * 2048 * 2);
  bf16* WvT_i = (bf16*)alloc((size_t)1024 * 2048 * 2);
  bf16* WoT_i = (bf16*)alloc((size_t)2048 * 2048 * 2);
  bf16* WguT_i = (bf16*)alloc((size_t)16384 * 2048 * 2);  // 64 MB
  bf16* WdT_i = (bf16*)alloc((size_t)2048 * 8192 * 2);
  bf16* WqT_t = (bf16*)alloc((size_t)2048 * 1024 * 2);
  bf16* WkT_t = (bf16*)alloc((size_t)1024 * 1024 * 2);
  bf16* WvT_t = (bf16*)alloc((size_t)1024 * 1024 * 2);
  bf16* WoT_t = (bf16*)alloc((size_t)1024 * 2048 * 2);
  bf16* WguT_t = (bf16*)alloc((size_t)8192 * 1024 * 2);   // 16 MB
  bf16* WdT_t = (bf16*)alloc((size_t)1024 * 4096 * 2);
  bf16* xn_i = (bf16*)alloc((size_t)2048 * 2048 * 2);
  bf16* xn_t = (bf16*)alloc((size_t)1024 * 1024 * 2);
  float* h_i = (float*)alloc((size_t)2048 * 2048 * 4);  // wo p0 img
  float* h_t = (float*)alloc((size_t)1024 * 1024 * 4);  // wo p0 txt
  char* S = (char*)alloc((size_t)84 * 1024 * 1024);
  (void)ws_size;

  const size_t MB = 1024 * 1024;
  bf16* q_all = (bf16*)S;
  bf16* k_all = (bf16*)(S + 12 * MB);
  bf16* v_all = (bf16*)(S + 18 * MB);
  bf16* vtr   = (bf16*)(S + 24 * MB);
  bf16* attn_o= (bf16*)(S + 30 * MB);
  float* wp1_i = (float*)S;
  float* wp1_t = (float*)(S + 16 * MB);
  bf16* gu_i  = (bf16*)S;
  bf16* gu_t  = (bf16*)(S + 64 * MB);
  float* dp1 = (float*)WguT_i;
  float* dp2 = (float*)((char*)WguT_i + 16 * MB);
  float* dp3 = (float*)((char*)WguT_i + 32 * MB);
  float* dt1 = (float*)((char*)WguT_i + 48 * MB);
  float* dt2 = (float*)((char*)WguT_i + 52 * MB);
  float* dt3 = (float*)((char*)WguT_i + 56 * MB);
  float* dt4 = (float*)((char*)WguT_i + 60 * MB);
  float* dt5 = (float*)WguT_t;
  float* dt6 = (float*)((char*)WguT_t + 4 * MB);
  float* dt7 = (float*)((char*)WguT_t + 8 * MB);

  (void)hipFuncSetAttribute(reinterpret_cast<const void*>(gemm8),
                            hipFuncAttributeMaxDynamicSharedMemorySize, 131072);

  // 1. transpose attn weights only (4608 blocks)
  TJobs tj;
  auto setj = [&](int idx, const float* s, bf16* d, int K, int N) {
    tj.j[idx].src = s; tj.j[idx].dst = d; tj.j[idx].K = K; tj.j[idx].N = N;
  };
  setj(0, wq_i, WqT_i, 2048, 2048);
  setj(1, wk_i, WkT_i, 2048, 1024);
  setj(2, wv_i, WvT_i, 2048, 1024);
  setj(3, wo_i, WoT_i, 2048, 2048);
  setj(4, wq_t, WqT_t, 1024, 2048);
  setj(5, wk_t, WkT_t, 1024, 1024);
  setj(6, wv_t, WvT_t, 1024, 1024);
  setj(7, wo_t, WoT_t, 2048, 1024);
  tj.cum[0] = 0;
  for (int i = 0; i < 8; i++)
    tj.cum[i + 1] = tj.cum[i] + (tj.j[i].K >> 6) * (tj.j[i].N >> 6);
  for (int i = 8; i < 14; i++) tj.cum[i + 1] = tj.cum[8];
  wt_transpose<<<tj.cum[8], 256, 0, stream>>>(tj);

  // 2. pre-attn RMSNorm
  rmsnorm_k<2><<<2048, 256, 0, stream>>>(x_img, sc_attn_i, xn_i);
  rmsnorm_k<1><<<1024, 256, 0, stream>>>(x_txt, sc_attn_t, xn_t);

  auto mk8b = [](const bf16* A, const bf16* B, bf16* Cb, int K, int N, int lda,
                 int ldb, int ab, int ash, int ask, int cb2, int csh, int csk,
                 int cstr) {
    G8Job g{};
    g.A = A; g.B = B; g.Cb = Cb; g.Cf = nullptr;
    g.K = K; g.N = N; g.lda = lda; g.ldb = ldb;
    g.a_base = ab; g.a_lsh = ash; g.a_lskip = ask;
    g.c_base = cb2; g.c_lsh = csh; g.c_lskip = csk; g.c_stride = cstr;
    return g;
  };
  auto mk8f = [](const bf16* A, const bf16* B, float* Cf, int K, int N, int lda,
                 int ldb, int ab, int ash, int ask, int cstr) {
    G8Job g{};
    g.A = A; g.B = B; g.Cb = nullptr; g.Cf = Cf;
    g.K = K; g.N = N; g.lda = lda; g.ldb = ldb;
    g.a_base = ab; g.a_lsh = ash; g.a_lskip = ask;
    g.c_base = 0; g.c_lsh = 30; g.c_lskip = 0; g.c_stride = cstr;
    return g;
  };
  auto launch8 = [&](G8Jobs& P, int nj, const int* Mt) {
    P.nj = nj;
    P.cum[0] = 0;
    for (int i = 0; i < nj; i++) P.cum[i + 1] = P.cum[i] + Mt[i] * (P.j[i].N >> 8);
    gemm8<<<P.cum[nj], 512, 131072, stream>>>(P);
  };

  // 3. QKV via gemm8
  {
    G8Jobs P;
    P.j[0] = mk8b(xn_i, WqT_i, q_all, 2048, 2048, 2048, 2048, 0, 30, 0, 0, 10, 512, 2048);
    P.j[1] = mk8b(xn_i, WkT_i, k_all, 2048, 1024, 2048, 2048, 0, 30, 0, 0, 10, 512, 1024);
    P.j[2] = mk8b(xn_i, WvT_i, v_all, 2048, 1024, 2048, 2048, 0, 30, 0, 0, 10, 512, 1024);
    P.j[3] = mk8b(xn_t, WqT_t, q_all, 1024, 2048, 1024, 1024, 0, 30, 0, 1024, 9, 1024, 2048);
    P.j[4] = mk8b(xn_t, WkT_t, k_all, 1024, 1024, 1024, 1024, 0, 30, 0, 1024, 9, 1024, 1024);
    P.j[5] = mk8b(xn_t, WvT_t, v_all, 1024, 1024, 1024, 1024, 0, 30, 0, 1024, 9, 1024, 1024);
    int Mt[6] = {8, 8, 8, 4, 4, 4};
    launch8(P, 6, Mt);
  }

  // 4. RoPE
  rope_inplace<<<12288, 256, 0, stream>>>(q_all, 4, 0.08838834764831845f);
  rope_inplace<<<6144, 256, 0, stream>>>(k_all, 3, 1.0f);

  // 5. V transpose
  transpose_v<<<dim3(24, 2, 16), 256, 0, stream>>>(v_all, vtr);

  // 6. attention + FFN weight transpose fused (768 + 15360 blocks)
  {
    FAArgs A;
    A.q_all = q_all; A.k_all = k_all; A.vt = vtr; A.attn_o = attn_o;
    auto setf = [&](int idx, const float* s, bf16* d, int K, int N) {
      A.j[idx].src = s; A.j[idx].dst = d; A.j[idx].K = K; A.j[idx].N = N;
    };
    setf(0, wg_i, WguT_i, 2048, 8192);
    setf(1, wu_i, WguT_i + (size_t)8192 * 2048, 2048, 8192);
    setf(2, wd_i, WdT_i, 8192, 2048);
    setf(3, wg_t, WguT_t, 1024, 4096);
    setf(4, wu_t, WguT_t + (size_t)4096 * 1024, 1024, 4096);
    setf(5, wd_t, WdT_t, 4096, 1024);
    A.cum[0] = 0;
    for (int i = 0; i < 6; i++)
      A.cum[i + 1] = A.cum[i] + (A.j[i].K >> 6) * (A.j[i].N >> 6);
    attn_wt<<<768 + A.cum[6], 256, 0, stream>>>(A);
  }

  // 7. WO split-K=2 (160 blocks): p0 -> h, p1 -> wp1
  {
    G8Jobs P;
    P.j[0] = mk8f(attn_o,        WoT_i,        h_i,   1024, 2048, 2048, 2048, 0, 10, 512, 2048);
    P.j[1] = mk8f(attn_o + 1024, WoT_i + 1024, wp1_i, 1024, 2048, 2048, 2048, 0, 10, 512, 2048);
    P.j[2] = mk8f(attn_o,        WoT_t,        h_t,   1024, 1024, 2048, 2048, 1024, 9, 1024, 1024);
    P.j[3] = mk8f(attn_o + 1024, WoT_t + 1024, wp1_t, 1024, 1024, 2048, 2048, 1024, 9, 1024, 1024);
    int Mt[4] = {8, 8, 4, 4};
    launch8(P, 4, Mt);
  }

  // 8. fused (p0+p1+x) RMSNorm -> xn
  rmsnorm2_k<2><<<2048, 256, 0, stream>>>(h_i, wp1_i, x_img, sc_ffw_i, xn_i);
  rmsnorm2_k<1><<<1024, 256, 0, stream>>>(h_t, wp1_t, x_txt, sc_ffw_t, xn_t);

  // 9. gate|up via gemm8 -> gu (bf16), single launch (640 blocks)
  {
    G8Jobs P;
    P.j[0] = mk8b(xn_i, WguT_i, gu_i, 2048, 16384, 2048, 2048, 0, 30, 0, 0, 30, 0, 16384);
    P.j[1] = mk8b(xn_t, WguT_t, gu_t, 1024, 8192, 1024, 1024, 0, 30, 0, 0, 30, 0, 8192);
    int Mt[2] = {8, 4};
    launch8(P, 2, Mt);
  }
  {
    int total = 2048 * 8192 / 8 + 1024 * 4096 / 8;
    gelu_mul<<<(total + 255) / 256, 256, 0, stream>>>(gu_i, gu_t);
  }

  // 10a. DOWN img split-4 (256 blocks, 1 clean round); p0 -> d_out
  {
    G8Jobs P;
    P.j[0] = mk8f(gu_i,        WdT_i,        outp, 2048, 2048, 16384, 8192, 0, 30, 0, 2048);
    P.j[1] = mk8f(gu_i + 2048, WdT_i + 2048, dp1,  2048, 2048, 16384, 8192, 0, 30, 0, 2048);
    P.j[2] = mk8f(gu_i + 4096, WdT_i + 4096, dp2,  2048, 2048, 16384, 8192, 0, 30, 0, 2048);
    P.j[3] = mk8f(gu_i + 6144, WdT_i + 6144, dp3,  2048, 2048, 16384, 8192, 0, 30, 0, 2048);
    int Mt[4] = {8, 8, 8, 8};
    launch8(P, 4, Mt);
  }
  // 10b. DOWN txt split-8 (128 blocks, short round 2); p0 -> d_out
  {
    G8Jobs P;
    float* dst[8] = {outp_t, dt1, dt2, dt3, dt4, dt5, dt6, dt7};
    for (int s = 0; s < 8; s++)
      P.j[s] = mk8f(gu_t + s * 512, WdT_t + s * 512, dst[s], 512, 1024, 8192,
                    4096, 0, 30, 0, 1024);
    int Mt[8] = {4, 4, 4, 4, 4, 4, 4, 4};
    launch8(P, 8, Mt);
  }
  reduce_down<<<2048, 256, 0, stream>>>(
      outp, dp1, dp2, dp3, x_img, 2048 * 2048 / 4,
      outp_t, dt1, dt2, dt3, dt4, dt5, dt6, dt7, x_txt, 1024 * 1024 / 4);
}

// Round 16
// 567.978 us; speedup vs baseline: 1.0661x; 1.0613x over previous
//
#include <hip/hip_runtime.h>
#include <hip/hip_bf16.h>

// MoE (img/txt mixture) transformer block for MI355X.
// Round 16: r15 + attention denominator reduce moved OUT of the tile loop.
// Per tile each lane now just accumulates its own p (no shuffles); the
// 4x shfl_xor 16-lane reduce happens once in the epilogue. Removes
// 64 ds_bpermute per wave per KV-tile (the dominant LDS-op class).

typedef __hip_bfloat16 bf16;
typedef __attribute__((ext_vector_type(8))) __bf16 bf16x8;
typedef __attribute__((ext_vector_type(4))) float f32x4;

#define DEV __device__ __forceinline__

static constexpr int TT = 1536;
static constexpr int NHQ = 16, NKVH = 8, HDM = 128;

DEV void async_load16(const void* g, void* l) {
  typedef const __attribute__((address_space(1))) void* gas_t;
  typedef __attribute__((address_space(3))) void* las_t;
  __builtin_amdgcn_global_load_lds((gas_t)g, (las_t)l, 16, 0, 0);
}

DEV f32x4 mfma16(bf16x8 a, bf16x8 b, f32x4 c) {
  return __builtin_amdgcn_mfma_f32_16x16x32_bf16(a, b, c, 0, 0, 0);
}

DEV float bf2f(bf16 x) { return __bfloat162float(x); }
DEV bf16  f2bf(float x) { return __float2bfloat16(x); }

// ---------------------------------------------------------------------------
// Weight transpose+convert: f32 [K][N] -> bf16 [N][K]  (conflict-free)
// ---------------------------------------------------------------------------
struct TJob { const float* src; bf16* dst; int K; int N; };
struct TJobs { TJob j[14]; int cum[15]; };

DEV void wt_body(const TJob& jb, int rel, int t, char* smem) {
  bf16* tile = (bf16*)smem;  // 64*72 elems = 9216 B
  int ntc = jb.N >> 6;
  int tr = rel / ntc, tc = rel - tr * ntc;
  int r0 = tr << 6, c0 = tc << 6;
  #pragma unroll
  for (int i = 0; i < 4; i++) {
    int r = i * 16 + (t >> 4);
    int c = 4 * (t & 15);
    int q = (r >> 3) & 7;
    float4 v = *reinterpret_cast<const float4*>(
        jb.src + (size_t)(r0 + r) * jb.N + c0 + c);
    union { bf16 h[4]; uint2 u; } pk;
    pk.h[0] = f2bf(v.x); pk.h[1] = f2bf(v.y);
    pk.h[2] = f2bf(v.z); pk.h[3] = f2bf(v.w);
    *reinterpret_cast<uint2*>(tile + r * 72 + (c ^ (q << 3))) = pk.u;
  }
  __syncthreads();
  const __bf16* tb = (const __bf16*)tile;
  #pragma unroll
  for (int i = 0; i < 2; i++) {
    int n = (t >> 3) + 32 * i;
    int kc = t & 7;
    int nswz = n ^ (kc << 3);
    bf16x8 v;
    #pragma unroll
    for (int m = 0; m < 8; m++) v[m] = tb[(kc * 8 + m) * 72 + nswz];
    *reinterpret_cast<bf16x8*>(jb.dst + (size_t)(c0 + n) * jb.K + r0 + kc * 8) = v;
  }
}

__global__ __launch_bounds__(256) void wt_transpose(TJobs P) {
  __shared__ __align__(16) char smem[9216];
  int bid = blockIdx.x;
  int ji = 0;
  while (ji < 13 && bid >= P.cum[ji + 1]) ji++;
  wt_body(P.j[ji], bid - P.cum[ji], threadIdx.x, smem);
}

// bf16 transpose for V: v_all [B*TT][NKVH*HDM] -> vt [B*NKVH][HDM][TT]
__global__ __launch_bounds__(256) void transpose_v(const bf16* __restrict__ v_all,
                                                   bf16* __restrict__ vt) {
  int st = blockIdx.x, ht = blockIdx.y, bk = blockIdx.z;
  int b = bk >> 3, kv = bk & 7;
  __shared__ bf16 tile[64][65];
  int t = threadIdx.x;
  int s0 = st * 64, h0 = ht * 64;
  #pragma unroll
  for (int i = 0; i < 16; i++) {
    int idx = i * 256 + t;
    int r = idx >> 6, c = idx & 63;
    tile[c][r] = v_all[((size_t)(b * TT + s0 + r) * NKVH + kv) * HDM + h0 + c];
  }
  __syncthreads();
  #pragma unroll
  for (int i = 0; i < 16; i++) {
    int idx = i * 256 + t;
    int r = idx >> 6, c = idx & 63;
    vt[((size_t)bk * HDM + h0 + r) * TT + s0 + c] = tile[r][c];
  }
}

// ---------------------------------------------------------------------------
// RMSNorm (single input)
// ---------------------------------------------------------------------------
template <int DV>
__global__ __launch_bounds__(256) void rmsnorm_k(const float* __restrict__ x,
                                                 const float* __restrict__ sc,
                                                 bf16* __restrict__ out) {
  const int D = DV * 1024;
  int row = blockIdx.x, t = threadIdx.x;
  const float4* xr = reinterpret_cast<const float4*>(x + (size_t)row * D);
  float4 v[DV];
  float ss = 0.f;
  #pragma unroll
  for (int i = 0; i < DV; i++) {
    v[i] = xr[t + i * 256];
    ss += v[i].x * v[i].x + v[i].y * v[i].y + v[i].z * v[i].z + v[i].w * v[i].w;
  }
  #pragma unroll
  for (int o = 1; o < 64; o <<= 1) ss += __shfl_xor(ss, o);
  __shared__ float red[4];
  if ((t & 63) == 0) red[t >> 6] = ss;
  __syncthreads();
  float r = rsqrtf((red[0] + red[1] + red[2] + red[3]) * (1.0f / D) + 1e-6f);
  bf16* orow = out + (size_t)row * D;
  #pragma unroll
  for (int i = 0; i < DV; i++) {
    int c = (t + i * 256) * 4;
    orow[c + 0] = f2bf(v[i].x * r * (1.f + sc[c + 0]));
    orow[c + 1] = f2bf(v[i].y * r * (1.f + sc[c + 1]));
    orow[c + 2] = f2bf(v[i].z * r * (1.f + sc[c + 2]));
    orow[c + 3] = f2bf(v[i].w * r * (1.f + sc[c + 3]));
  }
}

// ---------------------------------------------------------------------------
// RMSNorm over (p0+p1+x): fused wo split-K=2 reduce + pre-FFW norm
// ---------------------------------------------------------------------------
template <int DV>
__global__ __launch_bounds__(256) void rmsnorm2_k(
    const float* __restrict__ p0, const float* __restrict__ p1,
    const float* __restrict__ x, const float* __restrict__ sc,
    bf16* __restrict__ out) {
  const int D = DV * 1024;
  int row = blockIdx.x, t = threadIdx.x;
  size_t rb = (size_t)row * (D / 4);
  const float4* r0 = reinterpret_cast<const float4*>(p0) + rb;
  const float4* r1 = reinterpret_cast<const float4*>(p1) + rb;
  const float4* xr = reinterpret_cast<const float4*>(x) + rb;
  float4 v[DV];
  float ss = 0.f;
  #pragma unroll
  for (int i = 0; i < DV; i++) {
    int idx = t + i * 256;
    float4 a = r0[idx], b = r1[idx], e = xr[idx];
    v[i] = make_float4(a.x + b.x + e.x, a.y + b.y + e.y,
                       a.z + b.z + e.z, a.w + b.w + e.w);
    ss += v[i].x * v[i].x + v[i].y * v[i].y + v[i].z * v[i].z + v[i].w * v[i].w;
  }
  #pragma unroll
  for (int o = 1; o < 64; o <<= 1) ss += __shfl_xor(ss, o);
  __shared__ float red[4];
  if ((t & 63) == 0) red[t >> 6] = ss;
  __syncthreads();
  float r = rsqrtf((red[0] + red[1] + red[2] + red[3]) * (1.0f / D) + 1e-6f);
  bf16* orow = out + (size_t)row * D;
  #pragma unroll
  for (int i = 0; i < DV; i++) {
    int c = (t + i * 256) * 4;
    orow[c + 0] = f2bf(v[i].x * r * (1.f + sc[c + 0]));
    orow[c + 1] = f2bf(v[i].y * r * (1.f + sc[c + 1]));
    orow[c + 2] = f2bf(v[i].z * r * (1.f + sc[c + 2]));
    orow[c + 3] = f2bf(v[i].w * r * (1.f + sc[c + 3]));
  }
}

// ---------------------------------------------------------------------------
// RoPE in-place
// ---------------------------------------------------------------------------
__global__ __launch_bounds__(256) void rope_inplace(bf16* __restrict__ x, int lognh,
                                                    float scale) {
  int gid = blockIdx.x * 256 + threadIdx.x;
  int i = gid & 63;
  int rh = gid >> 6;
  int row = rh >> lognh;
  int pos = row >= TT ? row - TT : row;
  float fr = expf(-9.210340371976184f * ((float)(2 * i) * (1.0f / 128.0f)));
  float th = (float)pos * fr;
  float s, c;
  sincosf(th, &s, &c);
  bf16* p = x + (size_t)rh * HDM;
  float x1 = bf2f(p[i]), x2 = bf2f(p[i + 64]);
  p[i]      = f2bf((x1 * c - x2 * s) * scale);
  p[i + 64] = f2bf((x2 * c + x1 * s) * scale);
}

// ---------------------------------------------------------------------------
// 256x256 GEMM - r9 reduced-barrier K-loop (3 barriers/tile). PROVEN.
// ---------------------------------------------------------------------------
struct G8Job {
  const bf16* A; const bf16* B; bf16* Cb; float* Cf;
  int K, N, lda, ldb;
  int a_base, a_lsh, a_lskip;
  int c_base, c_lsh, c_lskip, c_stride;
};
struct G8Jobs { G8Job j[8]; int cum[9]; int nj; };

#define G8_MFMA(MH, NH)                                            \
  __builtin_amdgcn_s_setprio(1);                                   \
  _Pragma("unroll")                                                \
  for (int i = 0; i < 4; i++)                                      \
    _Pragma("unroll")                                              \
    for (int nj2 = 0; nj2 < 2; nj2++)                              \
      _Pragma("unroll")                                            \
      for (int kk = 0; kk < 2; kk++)                               \
        acc[(MH)*4 + i][(NH)*2 + nj2] = mfma16(                    \
            afr[i][kk], bfr[(NH)*2 + nj2][kk],                     \
            acc[(MH)*4 + i][(NH)*2 + nj2]);                        \
  __builtin_amdgcn_s_setprio(0);

__global__ __launch_bounds__(512, 2) void gemm8(G8Jobs P) {
  extern __shared__ __align__(16) bf16 lds8[];
  int bid = blockIdx.x;
  int ji = 0;
  while (ji < P.nj - 1 && bid >= P.cum[ji + 1]) ji++;
  const G8Job jb = P.j[ji];
  int rel = bid - P.cum[ji];
  int tn = jb.N >> 8;
  int bm = rel / tn, bn = rel - bm * tn;
  const int m0 = bm << 8, n0 = bn << 8;
  const int K = jb.K;
  const int nk = K >> 6;

  const int tid = threadIdx.x;
  const int w = tid >> 6, l = tid & 63;
  const int lr = l & 15, lk = l >> 4;
  const int wr = w >> 2, wc = w & 3;

  const int r0 = tid >> 3, sl0 = (tid & 7) ^ (r0 & 7);
  const int dst0 = (w * 64) * 8;
  const int dst1 = (512 + w * 64) * 8;

  auto stage = [&](int ht, int hq) {
    int k0 = ht << 6;
    bf16* ldsb = lds8 + ((ht & 1) * 32768 + hq * 8192);
    if (hq < 2) {
      int ma = m0 + hq * 128;
      int mr0 = ma + r0, mr1 = ma + 64 + r0;
      int pr0 = jb.a_base + mr0 + ((mr0 >> jb.a_lsh) * jb.a_lskip);
      int pr1 = jb.a_base + mr1 + ((mr1 >> jb.a_lsh) * jb.a_lskip);
      async_load16(jb.A + (size_t)pr0 * jb.lda + k0 + sl0 * 8, ldsb + dst0);
      async_load16(jb.A + (size_t)pr1 * jb.lda + k0 + sl0 * 8, ldsb + dst1);
    } else {
      int nb = n0 + (hq - 2) * 128;
      async_load16(jb.B + (size_t)(nb + r0) * jb.ldb + k0 + sl0 * 8, ldsb + dst0);
      async_load16(jb.B + (size_t)(nb + 64 + r0) * jb.ldb + k0 + sl0 * 8, ldsb + dst1);
    }
  };

  f32x4 acc[8][4];
  #pragma unroll
  for (int i = 0; i < 8; i++)
    #pragma unroll
    for (int j = 0; j < 4; j++) acc[i][j] = (f32x4){0.f, 0.f, 0.f, 0.f};

  const int s0 = ((0 * 4 + lk) ^ (lr & 7)) * 8;
  const int s1 = ((1 * 4 + lk) ^ (lr & 7)) * 8;
  const int browb = (wc & 1) * 64;

  #pragma unroll
  for (int hq = 0; hq < 4; hq++) stage(0, hq);
  #pragma unroll
  for (int hq = 0; hq < 4; hq++) stage(1, hq);
  asm volatile("s_waitcnt vmcnt(8)" ::: "memory");
  __builtin_amdgcn_s_barrier();
  asm volatile("" ::: "memory");

  bf16x8 afr[4][2], bfr[4][2];

  for (int t = 0; t < nk; t++) {
    const bf16* bufA = lds8 + (t & 1) * 32768 + wr * 8192;
    const bf16* bufB = lds8 + (t & 1) * 32768 + 16384 + (wc >> 1) * 8192;
    const bool st = (t + 2 < nk);

    #pragma unroll
    for (int i = 0; i < 4; i++) {
      int rb = (i * 16 + lr) * 64;
      afr[i][0] = *reinterpret_cast<const bf16x8*>(bufA + rb + s0);
      afr[i][1] = *reinterpret_cast<const bf16x8*>(bufA + rb + s1);
    }
    #pragma unroll
    for (int ni = 0; ni < 2; ni++) {
      int rb = (browb + ni * 16 + lr) * 64;
      bfr[ni][0] = *reinterpret_cast<const bf16x8*>(bufB + rb + s0);
      bfr[ni][1] = *reinterpret_cast<const bf16x8*>(bufB + rb + s1);
    }
    asm volatile("s_waitcnt lgkmcnt(0)" ::: "memory");
    __builtin_amdgcn_sched_barrier(0);
    G8_MFMA(0, 0)

    #pragma unroll
    for (int ni = 2; ni < 4; ni++) {
      int rb = (browb + ni * 16 + lr) * 64;
      bfr[ni][0] = *reinterpret_cast<const bf16x8*>(bufB + rb + s0);
      bfr[ni][1] = *reinterpret_cast<const bf16x8*>(bufB + rb + s1);
    }
    asm volatile("s_waitcnt lgkmcnt(0)" ::: "memory");
    __builtin_amdgcn_sched_barrier(0);
    G8_MFMA(0, 1)
    __builtin_amdgcn_s_barrier();
    asm volatile("" ::: "memory");

    #pragma unroll
    for (int i = 0; i < 4; i++) {
      int rb = ((i + 4) * 16 + lr) * 64;
      afr[i][0] = *reinterpret_cast<const bf16x8*>(bufA + rb + s0);
      afr[i][1] = *reinterpret_cast<const bf16x8*>(bufA + rb + s1);
    }
    if (st) { stage(t + 2, 2); stage(t + 2, 3); }
    asm volatile("s_waitcnt lgkmcnt(0)" ::: "memory");
    __builtin_amdgcn_sched_barrier(0);
    G8_MFMA(1, 0)
    __builtin_amdgcn_s_barrier();
    asm volatile("" ::: "memory");

    if (st) {
      stage(t + 2, 0); stage(t + 2, 1);
      asm volatile("s_waitcnt vmcnt(8)" ::: "memory");
    } else if (t == nk - 2) {
      asm volatile("s_waitcnt vmcnt(0)" ::: "memory");
    }
    G8_MFMA(1, 1)
    __builtin_amdgcn_s_barrier();
    asm volatile("" ::: "memory");
  }

  if (jb.Cf) {
    #pragma unroll
    for (int mi = 0; mi < 8; mi++)
      #pragma unroll
      for (int jj = 0; jj < 4; jj++) {
        int m = m0 + wr * 128 + mi * 16 + lk * 4 + jj;
        float* drow = jb.Cf + (size_t)m * jb.c_stride + n0 + wc * 64;
        #pragma unroll
        for (int ni = 0; ni < 4; ni++) drow[ni * 16 + lr] = acc[mi][ni][jj];
      }
  } else {
    #pragma unroll
    for (int mi = 0; mi < 8; mi++)
      #pragma unroll
      for (int jj = 0; jj < 4; jj++) {
        int m = m0 + wr * 128 + mi * 16 + lk * 4 + jj;
        int crow = jb.c_base + m + ((m >> jb.c_lsh) * jb.c_lskip);
        bf16* drow = jb.Cb + (size_t)crow * jb.c_stride + n0 + wc * 64;
        #pragma unroll
        for (int ni = 0; ni < 4; ni++) drow[ni * 16 + lr] = f2bf(acc[mi][ni][jj]);
      }
  }
}

// ---------------------------------------------------------------------------
// Down split-K reduce: img out += p1+p2+p3+x ; txt out += q1..q7+x
// ---------------------------------------------------------------------------
__global__ __launch_bounds__(256) void reduce_down(
    float* __restrict__ oi, const float* __restrict__ a1,
    const float* __restrict__ a2, const float* __restrict__ a3,
    const float* __restrict__ xi, int n4i,
    float* __restrict__ ot, const float* __restrict__ b1,
    const float* __restrict__ b2, const float* __restrict__ b3,
    const float* __restrict__ b4, const float* __restrict__ b5,
    const float* __restrict__ b6, const float* __restrict__ b7,
    const float* __restrict__ xt, int n4t) {
  int tot = n4i + n4t;
  for (int idx = blockIdx.x * 256 + threadIdx.x; idx < tot; idx += gridDim.x * 256) {
    if (idx < n4i) {
      float4 d = ((const float4*)oi)[idx];
      float4 a = ((const float4*)a1)[idx];
      float4 b = ((const float4*)a2)[idx];
      float4 c = ((const float4*)a3)[idx];
      float4 e = ((const float4*)xi)[idx];
      ((float4*)oi)[idx] = make_float4(d.x + a.x + b.x + c.x + e.x,
                                       d.y + a.y + b.y + c.y + e.y,
                                       d.z + a.z + b.z + c.z + e.z,
                                       d.w + a.w + b.w + c.w + e.w);
    } else {
      int i = idx - n4i;
      float4 d = ((const float4*)ot)[i];
      float4 p1 = ((const float4*)b1)[i];
      float4 p2 = ((const float4*)b2)[i];
      float4 p3 = ((const float4*)b3)[i];
      float4 p4 = ((const float4*)b4)[i];
      float4 p5 = ((const float4*)b5)[i];
      float4 p6 = ((const float4*)b6)[i];
      float4 p7 = ((const float4*)b7)[i];
      float4 e = ((const float4*)xt)[i];
      ((float4*)ot)[i] = make_float4(
          d.x + p1.x + p2.x + p3.x + p4.x + p5.x + p6.x + p7.x + e.x,
          d.y + p1.y + p2.y + p3.y + p4.y + p5.y + p6.y + p7.y + e.y,
          d.z + p1.z + p2.z + p3.z + p4.z + p5.z + p6.z + p7.z + e.z,
          d.w + p1.w + p2.w + p3.w + p4.w + p5.w + p6.w + p7.w + e.w);
    }
  }
}

// ---------------------------------------------------------------------------
// In-place GELU(gate)*up over gu buffers: act written to gate half.
// ---------------------------------------------------------------------------
__global__ __launch_bounds__(256) void gelu_mul(bf16* __restrict__ gu_i,
                                                bf16* __restrict__ gu_t) {
  const int IMG_CH = 2048 * 8192 / 8;
  const int TXT_CH = 1024 * 4096 / 8;
  int idx = blockIdx.x * 256 + threadIdx.x;
  int total = IMG_CH + TXT_CH;
  if (idx >= total) return;
  bf16* base;
  int half, ci;
  if (idx < IMG_CH) { base = gu_i; half = 8192; ci = idx; }
  else              { base = gu_t; half = 4096; ci = idx - IMG_CH; }
  int rowlen = half * 2;
  int perrow = half / 8;
  int m = ci / perrow, n8 = ci - m * perrow;
  bf16* gp = base + (size_t)m * rowlen + n8 * 8;
  bf16* up = gp + half;
  bf16x8 g8 = *reinterpret_cast<const bf16x8*>(gp);
  bf16x8 u8 = *reinterpret_cast<const bf16x8*>(up);
  bf16x8 o8;
  #pragma unroll
  for (int i = 0; i < 8; i++) {
    float g = (float)g8[i], u = (float)u8[i];
    float t = tanhf(0.7978845608028654f * (g + 0.044715f * g * g * g));
    o8[i] = (__bf16)(0.5f * g * (1.f + t) * u);
  }
  *reinterpret_cast<bf16x8*>(gp) = o8;
}

// ---------------------------------------------------------------------------
// Fused: attention (blocks 0..767) + FFN weight transpose (blocks 768+).
// Attention: reg-staged K/V double buffer, raw barriers, fast softcap,
// lane-local denominator (one cross-lane reduce in the epilogue).
// smem = 32768: Ksm [0,16K) (Psm aliases it), Vsm [16K,32K).
// ---------------------------------------------------------------------------
struct FAArgs {
  const bf16* q_all; const bf16* k_all; const bf16* vt; bf16* attn_o;
  TJob j[6]; int cum[7];
};

__global__ __launch_bounds__(256) void attn_wt(FAArgs A) {
  __shared__ __align__(16) char smem[32768];
  const int bid = blockIdx.x;
  const int tid = threadIdx.x;
  if (bid >= 768) {
    int rel = bid - 768;
    int ji = 0;
    while (ji < 5 && rel >= A.cum[ji + 1]) ji++;
    wt_body(A.j[ji], rel - A.cum[ji], tid, smem);
    return;
  }
  // ---- attention ----
  const int qt = bid % 24;
  const int n = (bid / 24) & 15;
  const int b = bid / 384;
  const int kv = n >> 1;
  const int w = tid >> 6, l = tid & 63;
  const int lr = l & 15, lk = l >> 4;
  bf16* Ksm = (bf16*)smem;                   // [0, 16384)
  bf16* Vsm = (bf16*)(smem + 16384);         // [16384, 32768)
  typedef bf16 PsmRow[16][72];
  PsmRow* Psm = (PsmRow*)smem;               // aliases Ksm (9216 B)

  bf16x8 qf[4];
  {
    int t = qt * 64 + w * 16 + lr;
    const bf16* qp = A.q_all + ((size_t)(b * TT + t) * NHQ + n) * HDM;
    #pragma unroll
    for (int kk = 0; kk < 4; kk++)
      qf[kk] = *reinterpret_cast<const bf16x8*>(qp + kk * 32 + lk * 8);
  }
  // per-thread staging geometry (chunk c = i*256+tid)
  int kwo[4], vwo[4];
  const bf16* kp[4];
  const bf16* vp[4];
  #pragma unroll
  for (int i = 0; i < 4; i++) {
    int c = i * 256 + tid;
    int krow = c >> 4, kcol = c & 15;
    kwo[i] = krow * 128 + ((kcol ^ (krow & 7)) << 3);
    kp[i] = A.k_all + ((size_t)(b * TT + krow) * NKVH + kv) * HDM + kcol * 8;
    int vrow = c >> 3, vcol = c & 7;
    vwo[i] = vrow * 64 + ((vcol ^ (vrow & 7)) << 3);
    vp[i] = A.vt + ((size_t)(b * NKVH + kv) * HDM + vrow) * TT + vcol * 8;
  }
  bf16x8 kreg[4], vreg[4];
  #pragma unroll
  for (int i = 0; i < 4; i++) {
    kreg[i] = *reinterpret_cast<const bf16x8*>(kp[i]); kp[i] += 64 * NKVH * HDM;
    vreg[i] = *reinterpret_cast<const bf16x8*>(vp[i]); vp[i] += 64;
  }

  f32x4 acc_o[8];
  #pragma unroll
  for (int i = 0; i < 8; i++) acc_o[i] = (f32x4){0.f, 0.f, 0.f, 0.f};
  float den[4] = {0.f, 0.f, 0.f, 0.f};

  for (int st = 0; st < TT / 64; st++) {
    asm volatile("s_waitcnt vmcnt(0)" ::: "memory");
    __builtin_amdgcn_s_barrier();
    asm volatile("" ::: "memory");
    #pragma unroll
    for (int i = 0; i < 4; i++) {
      *reinterpret_cast<bf16x8*>(Ksm + kwo[i]) = kreg[i];
      *reinterpret_cast<bf16x8*>(Vsm + vwo[i]) = vreg[i];
    }
    if (st + 1 < TT / 64) {
      #pragma unroll
      for (int i = 0; i < 4; i++) {
        kreg[i] = *reinterpret_cast<const bf16x8*>(kp[i]); kp[i] += 64 * NKVH * HDM;
        vreg[i] = *reinterpret_cast<const bf16x8*>(vp[i]); vp[i] += 64;
      }
    }
    asm volatile("s_waitcnt lgkmcnt(0)" ::: "memory");
    __builtin_amdgcn_s_barrier();
    asm volatile("" ::: "memory");
    // QK^T fully into registers
    f32x4 sq[4];
    #pragma unroll
    for (int sf = 0; sf < 4; sf++) {
      f32x4 s4 = (f32x4){0.f, 0.f, 0.f, 0.f};
      int sl = sf * 16 + lr;
      #pragma unroll
      for (int kk = 0; kk < 4; kk++) {
        int e = kk * 32 + lk * 8;
        bf16x8 kf = *reinterpret_cast<const bf16x8*>(
            Ksm + sl * 128 + ((((e >> 3) ^ (sl & 7))) << 3));
        s4 = mfma16(qf[kk], kf, s4);
      }
      sq[sf] = s4;
    }
    asm volatile("s_waitcnt lgkmcnt(0)" ::: "memory");
    __builtin_amdgcn_s_barrier();   // all K reads retired -> Psm writable
    asm volatile("" ::: "memory");
    // fast softcap; denominator accumulated LANE-LOCALLY (no shuffles here)
    #pragma unroll
    for (int sf = 0; sf < 4; sf++) {
      #pragma unroll
      for (int j = 0; j < 4; j++) {
        float xv = sq[sf][j];
        float e2 = __expf(xv * 0.04f);
        float rr = __builtin_amdgcn_rcpf(e2 + 1.0f);
        float p = __expf(50.0f - 100.0f * rr);
        Psm[w][lk * 4 + j][sf * 16 + lr] = f2bf(p);
        den[j] += p;
      }
    }
    #pragma unroll
    for (int kk2 = 0; kk2 < 2; kk2++) {
      bf16x8 pa = *reinterpret_cast<const bf16x8*>(&Psm[w][lr][kk2 * 32 + lk * 8]);
      #pragma unroll
      for (int hf = 0; hf < 8; hf++) {
        int h = hf * 16 + lr;
        int e2i = kk2 * 32 + lk * 8;
        bf16x8 vb = *reinterpret_cast<const bf16x8*>(
            Vsm + h * 64 + ((((e2i >> 3) ^ (h & 7))) << 3));
        acc_o[hf] = mfma16(pa, vb, acc_o[hf]);
      }
    }
  }
  // one cross-lane reduce for the denominator (within 16-lane groups)
  #pragma unroll
  for (int j = 0; j < 4; j++) {
    den[j] += __shfl_xor(den[j], 1);
    den[j] += __shfl_xor(den[j], 2);
    den[j] += __shfl_xor(den[j], 4);
    den[j] += __shfl_xor(den[j], 8);
  }
  #pragma unroll
  for (int hf = 0; hf < 8; hf++)
    #pragma unroll
    for (int j = 0; j < 4; j++) {
      int t = qt * 64 + w * 16 + lk * 4 + j;
      float val = acc_o[hf][j] / den[j];
      A.attn_o[((size_t)(b * TT + t)) * (NHQ * HDM) + n * HDM + hf * 16 + lr] =
          f2bf(val);
    }
}

// ---------------------------------------------------------------------------
extern "C" void kernel_launch(void* const* d_in, const int* in_sizes, int n_in,
                              void* d_out, int out_size, void* d_ws,
                              size_t ws_size, hipStream_t stream) {
  const float* x_img = (const float*)d_in[0];
  const float* x_txt = (const float*)d_in[1];
  const float* sc_attn_i = (const float*)d_in[3];
  const float* wq_i = (const float*)d_in[4];
  const float* wk_i = (const float*)d_in[5];
  const float* wv_i = (const float*)d_in[6];
  const float* wo_i = (const float*)d_in[7];
  const float* sc_ffw_i = (const float*)d_in[8];
  const float* wg_i = (const float*)d_in[9];
  const float* wu_i = (const float*)d_in[10];
  const float* wd_i = (const float*)d_in[11];
  const float* sc_attn_t = (const float*)d_in[12];
  const float* wq_t = (const float*)d_in[13];
  const float* wk_t = (const float*)d_in[14];
  const float* wv_t = (const float*)d_in[15];
  const float* wo_t = (const float*)d_in[16];
  const float* sc_ffw_t = (const float*)d_in[17];
  const float* wg_t = (const float*)d_in[18];
  const float* wu_t = (const float*)d_in[19];
  const float* wd_t = (const float*)d_in[20];
  float* outp = (float*)d_out;
  float* outp_t = outp + (size_t)2 * 1024 * 2048;

  char* ws = (char*)d_ws;
  size_t off = 0;
  auto alloc = [&](size_t n) {
    char* p = ws + off;
    off += (n + 255) & ~(size_t)255;
    return p;
  };
  bf16* WqT_i = (bf16*)alloc((size_t)2048 * 2048 * 2);
  bf16* WkT_i = (bf16*)alloc((size_t)1024 * 2048 * 2);
  bf16* WvT_i = (bf16*)alloc((size_t)1024 * 2048 * 2);
  bf16* WoT_i = (bf16*)alloc((size_t)2048 * 2048 * 2);
  bf16* WguT_i = (bf16*)alloc((size_t)16384 * 2048 * 2);  // 64 MB
  bf16* WdT_i = (bf16*)alloc((size_t)2048 * 8192 * 2);
  bf16* WqT_t = (bf16*)alloc((size_t)2048 * 1024 * 2);
  bf16* WkT_t = (bf16*)alloc((size_t)1024 * 1024 * 2);
  bf16* WvT_t = (bf16*)alloc((size_t)1024 * 1024 * 2);
  bf16* WoT_t = (bf16*)alloc((size_t)1024 * 2048 * 2);
  bf16* WguT_t = (bf16*)alloc((size_t)8192 * 1024 * 2);   // 16 MB
  bf16* WdT_t = (bf16*)alloc((size_t)1024 * 4096 * 2);
  bf16* xn_i = (bf16*)alloc((size_t)2048 * 2048 * 2);
  bf16* xn_t = (bf16*)alloc((size_t)1024 * 1024 * 2);
  float* h_i = (float*)alloc((size_t)2048 * 2048 * 4);  // wo p0 img
  float* h_t = (float*)alloc((size_t)1024 * 1024 * 4);  // wo p0 txt
  char* S = (char*)alloc((size_t)84 * 1024 * 1024);
  (void)ws_size;

  const size_t MB = 1024 * 1024;
  bf16* q_all = (bf16*)S;
  bf16* k_all = (bf16*)(S + 12 * MB);
  bf16* v_all = (bf16*)(S + 18 * MB);
  bf16* vtr   = (bf16*)(S + 24 * MB);
  bf16* attn_o= (bf16*)(S + 30 * MB);
  float* wp1_i = (float*)S;
  float* wp1_t = (float*)(S + 16 * MB);
  bf16* gu_i  = (bf16*)S;
  bf16* gu_t  = (bf16*)(S + 64 * MB);
  float* dp1 = (float*)WguT_i;
  float* dp2 = (float*)((char*)WguT_i + 16 * MB);
  float* dp3 = (float*)((char*)WguT_i + 32 * MB);
  float* dt1 = (float*)((char*)WguT_i + 48 * MB);
  float* dt2 = (float*)((char*)WguT_i + 52 * MB);
  float* dt3 = (float*)((char*)WguT_i + 56 * MB);
  float* dt4 = (float*)((char*)WguT_i + 60 * MB);
  float* dt5 = (float*)WguT_t;
  float* dt6 = (float*)((char*)WguT_t + 4 * MB);
  float* dt7 = (float*)((char*)WguT_t + 8 * MB);

  (void)hipFuncSetAttribute(reinterpret_cast<const void*>(gemm8),
                            hipFuncAttributeMaxDynamicSharedMemorySize, 131072);

  // 1. transpose attn weights only (4608 blocks)
  TJobs tj;
  auto setj = [&](int idx, const float* s, bf16* d, int K, int N) {
    tj.j[idx].src = s; tj.j[idx].dst = d; tj.j[idx].K = K; tj.j[idx].N = N;
  };
  setj(0, wq_i, WqT_i, 2048, 2048);
  setj(1, wk_i, WkT_i, 2048, 1024);
  setj(2, wv_i, WvT_i, 2048, 1024);
  setj(3, wo_i, WoT_i, 2048, 2048);
  setj(4, wq_t, WqT_t, 1024, 2048);
  setj(5, wk_t, WkT_t, 1024, 1024);
  setj(6, wv_t, WvT_t, 1024, 1024);
  setj(7, wo_t, WoT_t, 2048, 1024);
  tj.cum[0] = 0;
  for (int i = 0; i < 8; i++)
    tj.cum[i + 1] = tj.cum[i] + (tj.j[i].K >> 6) * (tj.j[i].N >> 6);
  for (int i = 8; i < 14; i++) tj.cum[i + 1] = tj.cum[8];
  wt_transpose<<<tj.cum[8], 256, 0, stream>>>(tj);

  // 2. pre-attn RMSNorm
  rmsnorm_k<2><<<2048, 256, 0, stream>>>(x_img, sc_attn_i, xn_i);
  rmsnorm_k<1><<<1024, 256, 0, stream>>>(x_txt, sc_attn_t, xn_t);

  auto mk8b = [](const bf16* A, const bf16* B, bf16* Cb, int K, int N, int lda,
                 int ldb, int ab, int ash, int ask, int cb2, int csh, int csk,
                 int cstr) {
    G8Job g{};
    g.A = A; g.B = B; g.Cb = Cb; g.Cf = nullptr;
    g.K = K; g.N = N; g.lda = lda; g.ldb = ldb;
    g.a_base = ab; g.a_lsh = ash; g.a_lskip = ask;
    g.c_base = cb2; g.c_lsh = csh; g.c_lskip = csk; g.c_stride = cstr;
    return g;
  };
  auto mk8f = [](const bf16* A, const bf16* B, float* Cf, int K, int N, int lda,
                 int ldb, int ab, int ash, int ask, int cstr) {
    G8Job g{};
    g.A = A; g.B = B; g.Cb = nullptr; g.Cf = Cf;
    g.K = K; g.N = N; g.lda = lda; g.ldb = ldb;
    g.a_base = ab; g.a_lsh = ash; g.a_lskip = ask;
    g.c_base = 0; g.c_lsh = 30; g.c_lskip = 0; g.c_stride = cstr;
    return g;
  };
  auto launch8 = [&](G8Jobs& P, int nj, const int* Mt) {
    P.nj = nj;
    P.cum[0] = 0;
    for (int i = 0; i < nj; i++) P.cum[i + 1] = P.cum[i] + Mt[i] * (P.j[i].N >> 8);
    gemm8<<<P.cum[nj], 512, 131072, stream>>>(P);
  };

  // 3. QKV via gemm8
  {
    G8Jobs P;
    P.j[0] = mk8b(xn_i, WqT_i, q_all, 2048, 2048, 2048, 2048, 0, 30, 0, 0, 10, 512, 2048);
    P.j[1] = mk8b(xn_i, WkT_i, k_all, 2048, 1024, 2048, 2048, 0, 30, 0, 0, 10, 512, 1024);
    P.j[2] = mk8b(xn_i, WvT_i, v_all, 2048, 1024, 2048, 2048, 0, 30, 0, 0, 10, 512, 1024);
    P.j[3] = mk8b(xn_t, WqT_t, q_all, 1024, 2048, 1024, 1024, 0, 30, 0, 1024, 9, 1024, 2048);
    P.j[4] = mk8b(xn_t, WkT_t, k_all, 1024, 1024, 1024, 1024, 0, 30, 0, 1024, 9, 1024, 1024);
    P.j[5] = mk8b(xn_t, WvT_t, v_all, 1024, 1024, 1024, 1024, 0, 30, 0, 1024, 9, 1024, 1024);
    int Mt[6] = {8, 8, 8, 4, 4, 4};
    launch8(P, 6, Mt);
  }

  // 4. RoPE
  rope_inplace<<<12288, 256, 0, stream>>>(q_all, 4, 0.08838834764831845f);
  rope_inplace<<<6144, 256, 0, stream>>>(k_all, 3, 1.0f);

  // 5. V transpose
  transpose_v<<<dim3(24, 2, 16), 256, 0, stream>>>(v_all, vtr);

  // 6. attention + FFN weight transpose fused (768 + 15360 blocks)
  {
    FAArgs A;
    A.q_all = q_all; A.k_all = k_all; A.vt = vtr; A.attn_o = attn_o;
    auto setf = [&](int idx, const float* s, bf16* d, int K, int N) {
      A.j[idx].src = s; A.j[idx].dst = d; A.j[idx].K = K; A.j[idx].N = N;
    };
    setf(0, wg_i, WguT_i, 2048, 8192);
    setf(1, wu_i, WguT_i + (size_t)8192 * 2048, 2048, 8192);
    setf(2, wd_i, WdT_i, 8192, 2048);
    setf(3, wg_t, WguT_t, 1024, 4096);
    setf(4, wu_t, WguT_t + (size_t)4096 * 1024, 1024, 4096);
    setf(5, wd_t, WdT_t, 4096, 1024);
    A.cum[0] = 0;
    for (int i = 0; i < 6; i++)
      A.cum[i + 1] = A.cum[i] + (A.j[i].K >> 6) * (A.j[i].N >> 6);
    attn_wt<<<768 + A.cum[6], 256, 0, stream>>>(A);
  }

  // 7. WO split-K=2 (160 blocks): p0 -> h, p1 -> wp1
  {
    G8Jobs P;
    P.j[0] = mk8f(attn_o,        WoT_i,        h_i,   1024, 2048, 2048, 2048, 0, 10, 512, 2048);
    P.j[1] = mk8f(attn_o + 1024, WoT_i + 1024, wp1_i, 1024, 2048, 2048, 2048, 0, 10, 512, 2048);
    P.j[2] = mk8f(attn_o,        WoT_t,        h_t,   1024, 1024, 2048, 2048, 1024, 9, 1024, 1024);
    P.j[3] = mk8f(attn_o + 1024, WoT_t + 1024, wp1_t, 1024, 1024, 2048, 2048, 1024, 9, 1024, 1024);
    int Mt[4] = {8, 8, 4, 4};
    launch8(P, 4, Mt);
  }

  // 8. fused (p0+p1+x) RMSNorm -> xn
  rmsnorm2_k<2><<<2048, 256, 0, stream>>>(h_i, wp1_i, x_img, sc_ffw_i, xn_i);
  rmsnorm2_k<1><<<1024, 256, 0, stream>>>(h_t, wp1_t, x_txt, sc_ffw_t, xn_t);

  // 9. gate|up via gemm8 -> gu (bf16), single launch (640 blocks)
  {
    G8Jobs P;
    P.j[0] = mk8b(xn_i, WguT_i, gu_i, 2048, 16384, 2048, 2048, 0, 30, 0, 0, 30, 0, 16384);
    P.j[1] = mk8b(xn_t, WguT_t, gu_t, 1024, 8192, 1024, 1024, 0, 30, 0, 0, 30, 0, 8192);
    int Mt[2] = {8, 4};
    launch8(P, 2, Mt);
  }
  {
    int total = 2048 * 8192 / 8 + 1024 * 4096 / 8;
    gelu_mul<<<(total + 255) / 256, 256, 0, stream>>>(gu_i, gu_t);
  }

  // 10a. DOWN img split-4 (256 blocks, 1 clean round); p0 -> d_out
  {
    G8Jobs P;
    P.j[0] = mk8f(gu_i,        WdT_i,        outp, 2048, 2048, 16384, 8192, 0, 30, 0, 2048);
    P.j[1] = mk8f(gu_i + 2048, WdT_i + 2048, dp1,  2048, 2048, 16384, 8192, 0, 30, 0, 2048);
    P.j[2] = mk8f(gu_i + 4096, WdT_i + 4096, dp2,  2048, 2048, 16384, 8192, 0, 30, 0, 2048);
    P.j[3] = mk8f(gu_i + 6144, WdT_i + 6144, dp3,  2048, 2048, 16384, 8192, 0, 30, 0, 2048);
    int Mt[4] = {8, 8, 8, 8};
    launch8(P, 4, Mt);
  }
  // 10b. DOWN txt split-8 (128 blocks, short round 2); p0 -> d_out
  {
    G8Jobs P;
    float* dst[8] = {outp_t, dt1, dt2, dt3, dt4, dt5, dt6, dt7};
    for (int s = 0; s < 8; s++)
      P.j[s] = mk8f(gu_t + s * 512, WdT_t + s * 512, dst[s], 512, 1024, 8192,
                    4096, 0, 30, 0, 1024);
    int Mt[8] = {4, 4, 4, 4, 4, 4, 4, 4};
    launch8(P, 8, Mt);
  }
  reduce_down<<<2048, 256, 0, stream>>>(
      outp, dp1, dp2, dp3, x_img, 2048 * 2048 / 4,
      outp_t, dt1, dt2, dt3, dt4, dt5, dt6, dt7, x_txt, 1024 * 1024 / 4);
}

// Round 17
// 556.806 us; speedup vs baseline: 1.0875x; 1.0201x over previous
//
#include <hip/hip_runtime.h>
#include <hip/hip_bf16.h>

// MoE (img/txt mixture) transformer block for MI355X.
// Round 17: r16 (567us) + launch fusion: pre_k = {rmsnorm img, rmsnorm txt,
// attn-weight transpose}; mid_k = {rope q, rope k, V transpose};
// rmsnorm2_all = {img,txt}; down img+txt one 12-job launch. 10 launches.

typedef __hip_bfloat16 bf16;
typedef __attribute__((ext_vector_type(8))) __bf16 bf16x8;
typedef __attribute__((ext_vector_type(4))) float f32x4;

#define DEV __device__ __forceinline__

static constexpr int TT = 1536;
static constexpr int NHQ = 16, NKVH = 8, HDM = 128;

DEV void async_load16(const void* g, void* l) {
  typedef const __attribute__((address_space(1))) void* gas_t;
  typedef __attribute__((address_space(3))) void* las_t;
  __builtin_amdgcn_global_load_lds((gas_t)g, (las_t)l, 16, 0, 0);
}

DEV f32x4 mfma16(bf16x8 a, bf16x8 b, f32x4 c) {
  return __builtin_amdgcn_mfma_f32_16x16x32_bf16(a, b, c, 0, 0, 0);
}

DEV float bf2f(bf16 x) { return __bfloat162float(x); }
DEV bf16  f2bf(float x) { return __float2bfloat16(x); }

// ---------------------------------------------------------------------------
// Weight transpose body: f32 [K][N] -> bf16 [N][K]  (conflict-free)
// ---------------------------------------------------------------------------
struct TJob { const float* src; bf16* dst; int K; int N; };

DEV void wt_body(const TJob& jb, int rel, int t, char* smem) {
  bf16* tile = (bf16*)smem;  // 64*72 elems = 9216 B
  int ntc = jb.N >> 6;
  int tr = rel / ntc, tc = rel - tr * ntc;
  int r0 = tr << 6, c0 = tc << 6;
  #pragma unroll
  for (int i = 0; i < 4; i++) {
    int r = i * 16 + (t >> 4);
    int c = 4 * (t & 15);
    int q = (r >> 3) & 7;
    float4 v = *reinterpret_cast<const float4*>(
        jb.src + (size_t)(r0 + r) * jb.N + c0 + c);
    union { bf16 h[4]; uint2 u; } pk;
    pk.h[0] = f2bf(v.x); pk.h[1] = f2bf(v.y);
    pk.h[2] = f2bf(v.z); pk.h[3] = f2bf(v.w);
    *reinterpret_cast<uint2*>(tile + r * 72 + (c ^ (q << 3))) = pk.u;
  }
  __syncthreads();
  const __bf16* tb = (const __bf16*)tile;
  #pragma unroll
  for (int i = 0; i < 2; i++) {
    int n = (t >> 3) + 32 * i;
    int kc = t & 7;
    int nswz = n ^ (kc << 3);
    bf16x8 v;
    #pragma unroll
    for (int m = 0; m < 8; m++) v[m] = tb[(kc * 8 + m) * 72 + nswz];
    *reinterpret_cast<bf16x8*>(jb.dst + (size_t)(c0 + n) * jb.K + r0 + kc * 8) = v;
  }
}

// ---------------------------------------------------------------------------
// RMSNorm bodies
// ---------------------------------------------------------------------------
template <int DV>
DEV void rms_body(const float* __restrict__ x, const float* __restrict__ sc,
                  bf16* __restrict__ out, int row, int t, float* red) {
  const int D = DV * 1024;
  const float4* xr = reinterpret_cast<const float4*>(x + (size_t)row * D);
  float4 v[DV];
  float ss = 0.f;
  #pragma unroll
  for (int i = 0; i < DV; i++) {
    v[i] = xr[t + i * 256];
    ss += v[i].x * v[i].x + v[i].y * v[i].y + v[i].z * v[i].z + v[i].w * v[i].w;
  }
  #pragma unroll
  for (int o = 1; o < 64; o <<= 1) ss += __shfl_xor(ss, o);
  if ((t & 63) == 0) red[t >> 6] = ss;
  __syncthreads();
  float r = rsqrtf((red[0] + red[1] + red[2] + red[3]) * (1.0f / D) + 1e-6f);
  bf16* orow = out + (size_t)row * D;
  #pragma unroll
  for (int i = 0; i < DV; i++) {
    int c = (t + i * 256) * 4;
    orow[c + 0] = f2bf(v[i].x * r * (1.f + sc[c + 0]));
    orow[c + 1] = f2bf(v[i].y * r * (1.f + sc[c + 1]));
    orow[c + 2] = f2bf(v[i].z * r * (1.f + sc[c + 2]));
    orow[c + 3] = f2bf(v[i].w * r * (1.f + sc[c + 3]));
  }
}

template <int DV>
DEV void rms2_body(const float* __restrict__ p0, const float* __restrict__ p1,
                   const float* __restrict__ x, const float* __restrict__ sc,
                   bf16* __restrict__ out, int row, int t, float* red) {
  const int D = DV * 1024;
  size_t rb = (size_t)row * (D / 4);
  const float4* r0 = reinterpret_cast<const float4*>(p0) + rb;
  const float4* r1 = reinterpret_cast<const float4*>(p1) + rb;
  const float4* xr = reinterpret_cast<const float4*>(x) + rb;
  float4 v[DV];
  float ss = 0.f;
  #pragma unroll
  for (int i = 0; i < DV; i++) {
    int idx = t + i * 256;
    float4 a = r0[idx], b = r1[idx], e = xr[idx];
    v[i] = make_float4(a.x + b.x + e.x, a.y + b.y + e.y,
                       a.z + b.z + e.z, a.w + b.w + e.w);
    ss += v[i].x * v[i].x + v[i].y * v[i].y + v[i].z * v[i].z + v[i].w * v[i].w;
  }
  #pragma unroll
  for (int o = 1; o < 64; o <<= 1) ss += __shfl_xor(ss, o);
  if ((t & 63) == 0) red[t >> 6] = ss;
  __syncthreads();
  float r = rsqrtf((red[0] + red[1] + red[2] + red[3]) * (1.0f / D) + 1e-6f);
  bf16* orow = out + (size_t)row * D;
  #pragma unroll
  for (int i = 0; i < DV; i++) {
    int c = (t + i * 256) * 4;
    orow[c + 0] = f2bf(v[i].x * r * (1.f + sc[c + 0]));
    orow[c + 1] = f2bf(v[i].y * r * (1.f + sc[c + 1]));
    orow[c + 2] = f2bf(v[i].z * r * (1.f + sc[c + 2]));
    orow[c + 3] = f2bf(v[i].w * r * (1.f + sc[c + 3]));
  }
}

// ---------------------------------------------------------------------------
// pre_k: blocks [0,2048) rmsnorm img; [2048,3072) rmsnorm txt;
//        [3072, 3072+nwt) attn-weight transpose (8 jobs)
// ---------------------------------------------------------------------------
struct PreArgs {
  const float* xi; const float* sci; bf16* oi;
  const float* xt; const float* sct; bf16* ot;
  TJob j[8]; int cum[9];
};

__global__ __launch_bounds__(256) void pre_k(PreArgs A) {
  __shared__ __align__(16) char smem[9216];
  int bid = blockIdx.x;
  int t = threadIdx.x;
  if (bid < 2048) { rms_body<2>(A.xi, A.sci, A.oi, bid, t, (float*)smem); return; }
  if (bid < 3072) { rms_body<1>(A.xt, A.sct, A.ot, bid - 2048, t, (float*)smem); return; }
  int rel = bid - 3072;
  int ji = 0;
  while (ji < 7 && rel >= A.cum[ji + 1]) ji++;
  wt_body(A.j[ji], rel - A.cum[ji], t, smem);
}

// ---------------------------------------------------------------------------
// mid_k: blocks [0,12288) rope q; [12288,18432) rope k; [18432,19200) V-transp
// ---------------------------------------------------------------------------
struct MidArgs { bf16* q; bf16* k; const bf16* v; bf16* vt; };

DEV void rope_body(bf16* __restrict__ x, int lognh, float scale, int bid, int t) {
  int gid = bid * 256 + t;
  int i = gid & 63;
  int rh = gid >> 6;
  int row = rh >> lognh;
  int pos = row >= TT ? row - TT : row;
  float fr = __expf(-9.210340371976184f * ((float)(2 * i) * (1.0f / 128.0f)));
  float th = (float)pos * fr;
  float s, c;
  __sincosf(th, &s, &c);
  bf16* p = x + (size_t)rh * HDM;
  float x1 = bf2f(p[i]), x2 = bf2f(p[i + 64]);
  p[i]      = f2bf((x1 * c - x2 * s) * scale);
  p[i + 64] = f2bf((x2 * c + x1 * s) * scale);
}

__global__ __launch_bounds__(256) void mid_k(MidArgs A) {
  __shared__ bf16 tile[64][65];
  int bid = blockIdx.x;
  int t = threadIdx.x;
  if (bid < 12288) { rope_body(A.q, 4, 0.08838834764831845f, bid, t); return; }
  if (bid < 18432) { rope_body(A.k, 3, 1.0f, bid - 12288, t); return; }
  int r = bid - 18432;               // 768 = 24 st x 2 ht x 16 bk
  int st = r % 24;
  int rem = r / 24;
  int ht = rem & 1;
  int bk = rem >> 1;
  int b = bk >> 3, kv = bk & 7;
  int s0 = st * 64, h0 = ht * 64;
  #pragma unroll
  for (int i = 0; i < 16; i++) {
    int idx = i * 256 + t;
    int rr = idx >> 6, c = idx & 63;
    tile[c][rr] = A.v[((size_t)(b * TT + s0 + rr) * NKVH + kv) * HDM + h0 + c];
  }
  __syncthreads();
  #pragma unroll
  for (int i = 0; i < 16; i++) {
    int idx = i * 256 + t;
    int rr = idx >> 6, c = idx & 63;
    A.vt[((size_t)bk * HDM + h0 + rr) * TT + s0 + c] = tile[rr][c];
  }
}

// ---------------------------------------------------------------------------
// rmsnorm2_all: blocks [0,2048) img; [2048,3072) txt
// ---------------------------------------------------------------------------
__global__ __launch_bounds__(256) void rmsnorm2_all(
    const float* p0i, const float* p1i, const float* xi, const float* sci, bf16* oi,
    const float* p0t, const float* p1t, const float* xt, const float* sct, bf16* ot) {
  __shared__ float red[4];
  int bid = blockIdx.x;
  int t = threadIdx.x;
  if (bid < 2048) rms2_body<2>(p0i, p1i, xi, sci, oi, bid, t, red);
  else            rms2_body<1>(p0t, p1t, xt, sct, ot, bid - 2048, t, red);
}

// ---------------------------------------------------------------------------
// 256x256 GEMM - r9 reduced-barrier K-loop (3 barriers/tile). PROVEN.
// ---------------------------------------------------------------------------
struct G8Job {
  const bf16* A; const bf16* B; bf16* Cb; float* Cf;
  int K, N, lda, ldb;
  int a_base, a_lsh, a_lskip;
  int c_base, c_lsh, c_lskip, c_stride;
};
struct G8Jobs { G8Job j[12]; int cum[13]; int nj; };

#define G8_MFMA(MH, NH)                                            \
  __builtin_amdgcn_s_setprio(1);                                   \
  _Pragma("unroll")                                                \
  for (int i = 0; i < 4; i++)                                      \
    _Pragma("unroll")                                              \
    for (int nj2 = 0; nj2 < 2; nj2++)                              \
      _Pragma("unroll")                                            \
      for (int kk = 0; kk < 2; kk++)                               \
        acc[(MH)*4 + i][(NH)*2 + nj2] = mfma16(                    \
            afr[i][kk], bfr[(NH)*2 + nj2][kk],                     \
            acc[(MH)*4 + i][(NH)*2 + nj2]);                        \
  __builtin_amdgcn_s_setprio(0);

__global__ __launch_bounds__(512, 2) void gemm8(G8Jobs P) {
  extern __shared__ __align__(16) bf16 lds8[];
  int bid = blockIdx.x;
  int ji = 0;
  while (ji < P.nj - 1 && bid >= P.cum[ji + 1]) ji++;
  const G8Job jb = P.j[ji];
  int rel = bid - P.cum[ji];
  int tn = jb.N >> 8;
  int bm = rel / tn, bn = rel - bm * tn;
  const int m0 = bm << 8, n0 = bn << 8;
  const int K = jb.K;
  const int nk = K >> 6;

  const int tid = threadIdx.x;
  const int w = tid >> 6, l = tid & 63;
  const int lr = l & 15, lk = l >> 4;
  const int wr = w >> 2, wc = w & 3;

  const int r0 = tid >> 3, sl0 = (tid & 7) ^ (r0 & 7);
  const int dst0 = (w * 64) * 8;
  const int dst1 = (512 + w * 64) * 8;

  auto stage = [&](int ht, int hq) {
    int k0 = ht << 6;
    bf16* ldsb = lds8 + ((ht & 1) * 32768 + hq * 8192);
    if (hq < 2) {
      int ma = m0 + hq * 128;
      int mr0 = ma + r0, mr1 = ma + 64 + r0;
      int pr0 = jb.a_base + mr0 + ((mr0 >> jb.a_lsh) * jb.a_lskip);
      int pr1 = jb.a_base + mr1 + ((mr1 >> jb.a_lsh) * jb.a_lskip);
      async_load16(jb.A + (size_t)pr0 * jb.lda + k0 + sl0 * 8, ldsb + dst0);
      async_load16(jb.A + (size_t)pr1 * jb.lda + k0 + sl0 * 8, ldsb + dst1);
    } else {
      int nb = n0 + (hq - 2) * 128;
      async_load16(jb.B + (size_t)(nb + r0) * jb.ldb + k0 + sl0 * 8, ldsb + dst0);
      async_load16(jb.B + (size_t)(nb + 64 + r0) * jb.ldb + k0 + sl0 * 8, ldsb + dst1);
    }
  };

  f32x4 acc[8][4];
  #pragma unroll
  for (int i = 0; i < 8; i++)
    #pragma unroll
    for (int j = 0; j < 4; j++) acc[i][j] = (f32x4){0.f, 0.f, 0.f, 0.f};

  const int s0 = ((0 * 4 + lk) ^ (lr & 7)) * 8;
  const int s1 = ((1 * 4 + lk) ^ (lr & 7)) * 8;
  const int browb = (wc & 1) * 64;

  #pragma unroll
  for (int hq = 0; hq < 4; hq++) stage(0, hq);
  #pragma unroll
  for (int hq = 0; hq < 4; hq++) stage(1, hq);
  asm volatile("s_waitcnt vmcnt(8)" ::: "memory");
  __builtin_amdgcn_s_barrier();
  asm volatile("" ::: "memory");

  bf16x8 afr[4][2], bfr[4][2];

  for (int t = 0; t < nk; t++) {
    const bf16* bufA = lds8 + (t & 1) * 32768 + wr * 8192;
    const bf16* bufB = lds8 + (t & 1) * 32768 + 16384 + (wc >> 1) * 8192;
    const bool st = (t + 2 < nk);

    #pragma unroll
    for (int i = 0; i < 4; i++) {
      int rb = (i * 16 + lr) * 64;
      afr[i][0] = *reinterpret_cast<const bf16x8*>(bufA + rb + s0);
      afr[i][1] = *reinterpret_cast<const bf16x8*>(bufA + rb + s1);
    }
    #pragma unroll
    for (int ni = 0; ni < 2; ni++) {
      int rb = (browb + ni * 16 + lr) * 64;
      bfr[ni][0] = *reinterpret_cast<const bf16x8*>(bufB + rb + s0);
      bfr[ni][1] = *reinterpret_cast<const bf16x8*>(bufB + rb + s1);
    }
    asm volatile("s_waitcnt lgkmcnt(0)" ::: "memory");
    __builtin_amdgcn_sched_barrier(0);
    G8_MFMA(0, 0)

    #pragma unroll
    for (int ni = 2; ni < 4; ni++) {
      int rb = (browb + ni * 16 + lr) * 64;
      bfr[ni][0] = *reinterpret_cast<const bf16x8*>(bufB + rb + s0);
      bfr[ni][1] = *reinterpret_cast<const bf16x8*>(bufB + rb + s1);
    }
    asm volatile("s_waitcnt lgkmcnt(0)" ::: "memory");
    __builtin_amdgcn_sched_barrier(0);
    G8_MFMA(0, 1)
    __builtin_amdgcn_s_barrier();
    asm volatile("" ::: "memory");

    #pragma unroll
    for (int i = 0; i < 4; i++) {
      int rb = ((i + 4) * 16 + lr) * 64;
      afr[i][0] = *reinterpret_cast<const bf16x8*>(bufA + rb + s0);
      afr[i][1] = *reinterpret_cast<const bf16x8*>(bufA + rb + s1);
    }
    if (st) { stage(t + 2, 2); stage(t + 2, 3); }
    asm volatile("s_waitcnt lgkmcnt(0)" ::: "memory");
    __builtin_amdgcn_sched_barrier(0);
    G8_MFMA(1, 0)
    __builtin_amdgcn_s_barrier();
    asm volatile("" ::: "memory");

    if (st) {
      stage(t + 2, 0); stage(t + 2, 1);
      asm volatile("s_waitcnt vmcnt(8)" ::: "memory");
    } else if (t == nk - 2) {
      asm volatile("s_waitcnt vmcnt(0)" ::: "memory");
    }
    G8_MFMA(1, 1)
    __builtin_amdgcn_s_barrier();
    asm volatile("" ::: "memory");
  }

  if (jb.Cf) {
    #pragma unroll
    for (int mi = 0; mi < 8; mi++)
      #pragma unroll
      for (int jj = 0; jj < 4; jj++) {
        int m = m0 + wr * 128 + mi * 16 + lk * 4 + jj;
        float* drow = jb.Cf + (size_t)m * jb.c_stride + n0 + wc * 64;
        #pragma unroll
        for (int ni = 0; ni < 4; ni++) drow[ni * 16 + lr] = acc[mi][ni][jj];
      }
  } else {
    #pragma unroll
    for (int mi = 0; mi < 8; mi++)
      #pragma unroll
      for (int jj = 0; jj < 4; jj++) {
        int m = m0 + wr * 128 + mi * 16 + lk * 4 + jj;
        int crow = jb.c_base + m + ((m >> jb.c_lsh) * jb.c_lskip);
        bf16* drow = jb.Cb + (size_t)crow * jb.c_stride + n0 + wc * 64;
        #pragma unroll
        for (int ni = 0; ni < 4; ni++) drow[ni * 16 + lr] = f2bf(acc[mi][ni][jj]);
      }
  }
}

// ---------------------------------------------------------------------------
// Down split-K reduce: img out += p1+p2+p3+x ; txt out += q1..q7+x
// ---------------------------------------------------------------------------
__global__ __launch_bounds__(256) void reduce_down(
    float* __restrict__ oi, const float* __restrict__ a1,
    const float* __restrict__ a2, const float* __restrict__ a3,
    const float* __restrict__ xi, int n4i,
    float* __restrict__ ot, const float* __restrict__ b1,
    const float* __restrict__ b2, const float* __restrict__ b3,
    const float* __restrict__ b4, const float* __restrict__ b5,
    const float* __restrict__ b6, const float* __restrict__ b7,
    const float* __restrict__ xt, int n4t) {
  int tot = n4i + n4t;
  for (int idx = blockIdx.x * 256 + threadIdx.x; idx < tot; idx += gridDim.x * 256) {
    if (idx < n4i) {
      float4 d = ((const float4*)oi)[idx];
      float4 a = ((const float4*)a1)[idx];
      float4 b = ((const float4*)a2)[idx];
      float4 c = ((const float4*)a3)[idx];
      float4 e = ((const float4*)xi)[idx];
      ((float4*)oi)[idx] = make_float4(d.x + a.x + b.x + c.x + e.x,
                                       d.y + a.y + b.y + c.y + e.y,
                                       d.z + a.z + b.z + c.z + e.z,
                                       d.w + a.w + b.w + c.w + e.w);
    } else {
      int i = idx - n4i;
      float4 d = ((const float4*)ot)[i];
      float4 p1 = ((const float4*)b1)[i];
      float4 p2 = ((const float4*)b2)[i];
      float4 p3 = ((const float4*)b3)[i];
      float4 p4 = ((const float4*)b4)[i];
      float4 p5 = ((const float4*)b5)[i];
      float4 p6 = ((const float4*)b6)[i];
      float4 p7 = ((const float4*)b7)[i];
      float4 e = ((const float4*)xt)[i];
      ((float4*)ot)[i] = make_float4(
          d.x + p1.x + p2.x + p3.x + p4.x + p5.x + p6.x + p7.x + e.x,
          d.y + p1.y + p2.y + p3.y + p4.y + p5.y + p6.y + p7.y + e.y,
          d.z + p1.z + p2.z + p3.z + p4.z + p5.z + p6.z + p7.z + e.z,
          d.w + p1.w + p2.w + p3.w + p4.w + p5.w + p6.w + p7.w + e.w);
    }
  }
}

// ---------------------------------------------------------------------------
// In-place GELU(gate)*up over gu buffers: act written to gate half.
// ---------------------------------------------------------------------------
__global__ __launch_bounds__(256) void gelu_mul(bf16* __restrict__ gu_i,
                                                bf16* __restrict__ gu_t) {
  const int IMG_CH = 2048 * 8192 / 8;
  const int TXT_CH = 1024 * 4096 / 8;
  int idx = blockIdx.x * 256 + threadIdx.x;
  int total = IMG_CH + TXT_CH;
  if (idx >= total) return;
  bf16* base;
  int half, ci;
  if (idx < IMG_CH) { base = gu_i; half = 8192; ci = idx; }
  else              { base = gu_t; half = 4096; ci = idx - IMG_CH; }
  int rowlen = half * 2;
  int perrow = half / 8;
  int m = ci / perrow, n8 = ci - m * perrow;
  bf16* gp = base + (size_t)m * rowlen + n8 * 8;
  bf16* up = gp + half;
  bf16x8 g8 = *reinterpret_cast<const bf16x8*>(gp);
  bf16x8 u8 = *reinterpret_cast<const bf16x8*>(up);
  bf16x8 o8;
  #pragma unroll
  for (int i = 0; i < 8; i++) {
    float g = (float)g8[i], u = (float)u8[i];
    float t = tanhf(0.7978845608028654f * (g + 0.044715f * g * g * g));
    o8[i] = (__bf16)(0.5f * g * (1.f + t) * u);
  }
  *reinterpret_cast<bf16x8*>(gp) = o8;
}

// ---------------------------------------------------------------------------
// Fused: attention (blocks 0..767) + FFN weight transpose (blocks 768+).
// ---------------------------------------------------------------------------
struct FAArgs {
  const bf16* q_all; const bf16* k_all; const bf16* vt; bf16* attn_o;
  TJob j[6]; int cum[7];
};

__global__ __launch_bounds__(256) void attn_wt(FAArgs A) {
  __shared__ __align__(16) char smem[32768];
  const int bid = blockIdx.x;
  const int tid = threadIdx.x;
  if (bid >= 768) {
    int rel = bid - 768;
    int ji = 0;
    while (ji < 5 && rel >= A.cum[ji + 1]) ji++;
    wt_body(A.j[ji], rel - A.cum[ji], tid, smem);
    return;
  }
  const int qt = bid % 24;
  const int n = (bid / 24) & 15;
  const int b = bid / 384;
  const int kv = n >> 1;
  const int w = tid >> 6, l = tid & 63;
  const int lr = l & 15, lk = l >> 4;
  bf16* Ksm = (bf16*)smem;
  bf16* Vsm = (bf16*)(smem + 16384);
  typedef bf16 PsmRow[16][72];
  PsmRow* Psm = (PsmRow*)smem;

  bf16x8 qf[4];
  {
    int t = qt * 64 + w * 16 + lr;
    const bf16* qp = A.q_all + ((size_t)(b * TT + t) * NHQ + n) * HDM;
    #pragma unroll
    for (int kk = 0; kk < 4; kk++)
      qf[kk] = *reinterpret_cast<const bf16x8*>(qp + kk * 32 + lk * 8);
  }
  int kwo[4], vwo[4];
  const bf16* kp[4];
  const bf16* vp[4];
  #pragma unroll
  for (int i = 0; i < 4; i++) {
    int c = i * 256 + tid;
    int krow = c >> 4, kcol = c & 15;
    kwo[i] = krow * 128 + ((kcol ^ (krow & 7)) << 3);
    kp[i] = A.k_all + ((size_t)(b * TT + krow) * NKVH + kv) * HDM + kcol * 8;
    int vrow = c >> 3, vcol = c & 7;
    vwo[i] = vrow * 64 + ((vcol ^ (vrow & 7)) << 3);
    vp[i] = A.vt + ((size_t)(b * NKVH + kv) * HDM + vrow) * TT + vcol * 8;
  }
  bf16x8 kreg[4], vreg[4];
  #pragma unroll
  for (int i = 0; i < 4; i++) {
    kreg[i] = *reinterpret_cast<const bf16x8*>(kp[i]); kp[i] += 64 * NKVH * HDM;
    vreg[i] = *reinterpret_cast<const bf16x8*>(vp[i]); vp[i] += 64;
  }

  f32x4 acc_o[8];
  #pragma unroll
  for (int i = 0; i < 8; i++) acc_o[i] = (f32x4){0.f, 0.f, 0.f, 0.f};
  float den[4] = {0.f, 0.f, 0.f, 0.f};

  for (int st = 0; st < TT / 64; st++) {
    asm volatile("s_waitcnt vmcnt(0)" ::: "memory");
    __builtin_amdgcn_s_barrier();
    asm volatile("" ::: "memory");
    #pragma unroll
    for (int i = 0; i < 4; i++) {
      *reinterpret_cast<bf16x8*>(Ksm + kwo[i]) = kreg[i];
      *reinterpret_cast<bf16x8*>(Vsm + vwo[i]) = vreg[i];
    }
    if (st + 1 < TT / 64) {
      #pragma unroll
      for (int i = 0; i < 4; i++) {
        kreg[i] = *reinterpret_cast<const bf16x8*>(kp[i]); kp[i] += 64 * NKVH * HDM;
        vreg[i] = *reinterpret_cast<const bf16x8*>(vp[i]); vp[i] += 64;
      }
    }
    asm volatile("s_waitcnt lgkmcnt(0)" ::: "memory");
    __builtin_amdgcn_s_barrier();
    asm volatile("" ::: "memory");
    f32x4 sq[4];
    #pragma unroll
    for (int sf = 0; sf < 4; sf++) {
      f32x4 s4 = (f32x4){0.f, 0.f, 0.f, 0.f};
      int sl = sf * 16 + lr;
      #pragma unroll
      for (int kk = 0; kk < 4; kk++) {
        int e = kk * 32 + lk * 8;
        bf16x8 kf = *reinterpret_cast<const bf16x8*>(
            Ksm + sl * 128 + ((((e >> 3) ^ (sl & 7))) << 3));
        s4 = mfma16(qf[kk], kf, s4);
      }
      sq[sf] = s4;
    }
    asm volatile("s_waitcnt lgkmcnt(0)" ::: "memory");
    __builtin_amdgcn_s_barrier();
    asm volatile("" ::: "memory");
    #pragma unroll
    for (int sf = 0; sf < 4; sf++) {
      #pragma unroll
      for (int j = 0; j < 4; j++) {
        float xv = sq[sf][j];
        float e2 = __expf(xv * 0.04f);
        float rr = __builtin_amdgcn_rcpf(e2 + 1.0f);
        float p = __expf(50.0f - 100.0f * rr);
        Psm[w][lk * 4 + j][sf * 16 + lr] = f2bf(p);
        den[j] += p;
      }
    }
    #pragma unroll
    for (int kk2 = 0; kk2 < 2; kk2++) {
      bf16x8 pa = *reinterpret_cast<const bf16x8*>(&Psm[w][lr][kk2 * 32 + lk * 8]);
      #pragma unroll
      for (int hf = 0; hf < 8; hf++) {
        int h = hf * 16 + lr;
        int e2i = kk2 * 32 + lk * 8;
        bf16x8 vb = *reinterpret_cast<const bf16x8*>(
            Vsm + h * 64 + ((((e2i >> 3) ^ (h & 7))) << 3));
        acc_o[hf] = mfma16(pa, vb, acc_o[hf]);
      }
    }
  }
  #pragma unroll
  for (int j = 0; j < 4; j++) {
    den[j] += __shfl_xor(den[j], 1);
    den[j] += __shfl_xor(den[j], 2);
    den[j] += __shfl_xor(den[j], 4);
    den[j] += __shfl_xor(den[j], 8);
  }
  #pragma unroll
  for (int hf = 0; hf < 8; hf++)
    #pragma unroll
    for (int j = 0; j < 4; j++) {
      int t = qt * 64 + w * 16 + lk * 4 + j;
      float val = acc_o[hf][j] / den[j];
      A.attn_o[((size_t)(b * TT + t)) * (NHQ * HDM) + n * HDM + hf * 16 + lr] =
          f2bf(val);
    }
}

// ---------------------------------------------------------------------------
extern "C" void kernel_launch(void* const* d_in, const int* in_sizes, int n_in,
                              void* d_out, int out_size, void* d_ws,
                              size_t ws_size, hipStream_t stream) {
  const float* x_img = (const float*)d_in[0];
  const float* x_txt = (const float*)d_in[1];
  const float* sc_attn_i = (const float*)d_in[3];
  const float* wq_i = (const float*)d_in[4];
  const float* wk_i = (const float*)d_in[5];
  const float* wv_i = (const float*)d_in[6];
  const float* wo_i = (const float*)d_in[7];
  const float* sc_ffw_i = (const float*)d_in[8];
  const float* wg_i = (const float*)d_in[9];
  const float* wu_i = (const float*)d_in[10];
  const float* wd_i = (const float*)d_in[11];
  const float* sc_attn_t = (const float*)d_in[12];
  const float* wq_t = (const float*)d_in[13];
  const float* wk_t = (const float*)d_in[14];
  const float* wv_t = (const float*)d_in[15];
  const float* wo_t = (const float*)d_in[16];
  const float* sc_ffw_t = (const float*)d_in[17];
  const float* wg_t = (const float*)d_in[18];
  const float* wu_t = (const float*)d_in[19];
  const float* wd_t = (const float*)d_in[20];
  float* outp = (float*)d_out;
  float* outp_t = outp + (size_t)2 * 1024 * 2048;

  char* ws = (char*)d_ws;
  size_t off = 0;
  auto alloc = [&](size_t n) {
    char* p = ws + off;
    off += (n + 255) & ~(size_t)255;
    return p;
  };
  bf16* WqT_i = (bf16*)alloc((size_t)2048 * 2048 * 2);
  bf16* WkT_i = (bf16*)alloc((size_t)1024 * 2048 * 2);
  bf16* WvT_i = (bf16*)alloc((size_t)1024 * 2048 * 2);
  bf16* WoT_i = (bf16*)alloc((size_t)2048 * 2048 * 2);
  bf16* WguT_i = (bf16*)alloc((size_t)16384 * 2048 * 2);  // 64 MB
  bf16* WdT_i = (bf16*)alloc((size_t)2048 * 8192 * 2);
  bf16* WqT_t = (bf16*)alloc((size_t)2048 * 1024 * 2);
  bf16* WkT_t = (bf16*)alloc((size_t)1024 * 1024 * 2);
  bf16* WvT_t = (bf16*)alloc((size_t)1024 * 1024 * 2);
  bf16* WoT_t = (bf16*)alloc((size_t)1024 * 2048 * 2);
  bf16* WguT_t = (bf16*)alloc((size_t)8192 * 1024 * 2);   // 16 MB
  bf16* WdT_t = (bf16*)alloc((size_t)1024 * 4096 * 2);
  bf16* xn_i = (bf16*)alloc((size_t)2048 * 2048 * 2);
  bf16* xn_t = (bf16*)alloc((size_t)1024 * 1024 * 2);
  float* h_i = (float*)alloc((size_t)2048 * 2048 * 4);  // wo p0 img
  float* h_t = (float*)alloc((size_t)1024 * 1024 * 4);  // wo p0 txt
  char* S = (char*)alloc((size_t)84 * 1024 * 1024);
  (void)ws_size;

  const size_t MB = 1024 * 1024;
  bf16* q_all = (bf16*)S;
  bf16* k_all = (bf16*)(S + 12 * MB);
  bf16* v_all = (bf16*)(S + 18 * MB);
  bf16* vtr   = (bf16*)(S + 24 * MB);
  bf16* attn_o= (bf16*)(S + 30 * MB);
  float* wp1_i = (float*)S;
  float* wp1_t = (float*)(S + 16 * MB);
  bf16* gu_i  = (bf16*)S;
  bf16* gu_t  = (bf16*)(S + 64 * MB);
  float* dp1 = (float*)WguT_i;
  float* dp2 = (float*)((char*)WguT_i + 16 * MB);
  float* dp3 = (float*)((char*)WguT_i + 32 * MB);
  float* dt1 = (float*)((char*)WguT_i + 48 * MB);
  float* dt2 = (float*)((char*)WguT_i + 52 * MB);
  float* dt3 = (float*)((char*)WguT_i + 56 * MB);
  float* dt4 = (float*)((char*)WguT_i + 60 * MB);
  float* dt5 = (float*)WguT_t;
  float* dt6 = (float*)((char*)WguT_t + 4 * MB);
  float* dt7 = (float*)((char*)WguT_t + 8 * MB);

  (void)hipFuncSetAttribute(reinterpret_cast<const void*>(gemm8),
                            hipFuncAttributeMaxDynamicSharedMemorySize, 131072);

  // 1. pre_k: rmsnorm img/txt + attn weight transpose (7680 blocks)
  {
    PreArgs A;
    A.xi = x_img; A.sci = sc_attn_i; A.oi = xn_i;
    A.xt = x_txt; A.sct = sc_attn_t; A.ot = xn_t;
    auto setj = [&](int idx, const float* s, bf16* d, int K, int N) {
      A.j[idx].src = s; A.j[idx].dst = d; A.j[idx].K = K; A.j[idx].N = N;
    };
    setj(0, wq_i, WqT_i, 2048, 2048);
    setj(1, wk_i, WkT_i, 2048, 1024);
    setj(2, wv_i, WvT_i, 2048, 1024);
    setj(3, wo_i, WoT_i, 2048, 2048);
    setj(4, wq_t, WqT_t, 1024, 2048);
    setj(5, wk_t, WkT_t, 1024, 1024);
    setj(6, wv_t, WvT_t, 1024, 1024);
    setj(7, wo_t, WoT_t, 2048, 1024);
    A.cum[0] = 0;
    for (int i = 0; i < 8; i++)
      A.cum[i + 1] = A.cum[i] + (A.j[i].K >> 6) * (A.j[i].N >> 6);
    pre_k<<<3072 + A.cum[8], 256, 0, stream>>>(A);
  }

  auto mk8b = [](const bf16* A, const bf16* B, bf16* Cb, int K, int N, int lda,
                 int ldb, int ab, int ash, int ask, int cb2, int csh, int csk,
                 int cstr) {
    G8Job g{};
    g.A = A; g.B = B; g.Cb = Cb; g.Cf = nullptr;
    g.K = K; g.N = N; g.lda = lda; g.ldb = ldb;
    g.a_base = ab; g.a_lsh = ash; g.a_lskip = ask;
    g.c_base = cb2; g.c_lsh = csh; g.c_lskip = csk; g.c_stride = cstr;
    return g;
  };
  auto mk8f = [](const bf16* A, const bf16* B, float* Cf, int K, int N, int lda,
                 int ldb, int ab, int ash, int ask, int cstr) {
    G8Job g{};
    g.A = A; g.B = B; g.Cb = nullptr; g.Cf = Cf;
    g.K = K; g.N = N; g.lda = lda; g.ldb = ldb;
    g.a_base = ab; g.a_lsh = ash; g.a_lskip = ask;
    g.c_base = 0; g.c_lsh = 30; g.c_lskip = 0; g.c_stride = cstr;
    return g;
  };
  auto launch8 = [&](G8Jobs& P, int nj, const int* Mt) {
    P.nj = nj;
    P.cum[0] = 0;
    for (int i = 0; i < nj; i++) P.cum[i + 1] = P.cum[i] + Mt[i] * (P.j[i].N >> 8);
    gemm8<<<P.cum[nj], 512, 131072, stream>>>(P);
  };

  // 2. QKV via gemm8 (192 blocks)
  {
    G8Jobs P;
    P.j[0] = mk8b(xn_i, WqT_i, q_all, 2048, 2048, 2048, 2048, 0, 30, 0, 0, 10, 512, 2048);
    P.j[1] = mk8b(xn_i, WkT_i, k_all, 2048, 1024, 2048, 2048, 0, 30, 0, 0, 10, 512, 1024);
    P.j[2] = mk8b(xn_i, WvT_i, v_all, 2048, 1024, 2048, 2048, 0, 30, 0, 0, 10, 512, 1024);
    P.j[3] = mk8b(xn_t, WqT_t, q_all, 1024, 2048, 1024, 1024, 0, 30, 0, 1024, 9, 1024, 2048);
    P.j[4] = mk8b(xn_t, WkT_t, k_all, 1024, 1024, 1024, 1024, 0, 30, 0, 1024, 9, 1024, 1024);
    P.j[5] = mk8b(xn_t, WvT_t, v_all, 1024, 1024, 1024, 1024, 0, 30, 0, 1024, 9, 1024, 1024);
    int Mt[6] = {8, 8, 8, 4, 4, 4};
    launch8(P, 6, Mt);
  }

  // 3. mid_k: rope q + rope k + V transpose (19200 blocks)
  {
    MidArgs A;
    A.q = q_all; A.k = k_all; A.v = v_all; A.vt = vtr;
    mid_k<<<19200, 256, 0, stream>>>(A);
  }

  // 4. attention + FFN weight transpose fused (768 + 15360 blocks)
  {
    FAArgs A;
    A.q_all = q_all; A.k_all = k_all; A.vt = vtr; A.attn_o = attn_o;
    auto setf = [&](int idx, const float* s, bf16* d, int K, int N) {
      A.j[idx].src = s; A.j[idx].dst = d; A.j[idx].K = K; A.j[idx].N = N;
    };
    setf(0, wg_i, WguT_i, 2048, 8192);
    setf(1, wu_i, WguT_i + (size_t)8192 * 2048, 2048, 8192);
    setf(2, wd_i, WdT_i, 8192, 2048);
    setf(3, wg_t, WguT_t, 1024, 4096);
    setf(4, wu_t, WguT_t + (size_t)4096 * 1024, 1024, 4096);
    setf(5, wd_t, WdT_t, 4096, 1024);
    A.cum[0] = 0;
    for (int i = 0; i < 6; i++)
      A.cum[i + 1] = A.cum[i] + (A.j[i].K >> 6) * (A.j[i].N >> 6);
    attn_wt<<<768 + A.cum[6], 256, 0, stream>>>(A);
  }

  // 5. WO split-K=2 (160 blocks): p0 -> h, p1 -> wp1
  {
    G8Jobs P;
    P.j[0] = mk8f(attn_o,        WoT_i,        h_i,   1024, 2048, 2048, 2048, 0, 10, 512, 2048);
    P.j[1] = mk8f(attn_o + 1024, WoT_i + 1024, wp1_i, 1024, 2048, 2048, 2048, 0, 10, 512, 2048);
    P.j[2] = mk8f(attn_o,        WoT_t,        h_t,   1024, 1024, 2048, 2048, 1024, 9, 1024, 1024);
    P.j[3] = mk8f(attn_o + 1024, WoT_t + 1024, wp1_t, 1024, 1024, 2048, 2048, 1024, 9, 1024, 1024);
    int Mt[4] = {8, 8, 4, 4};
    launch8(P, 4, Mt);
  }

  // 6. fused (p0+p1+x) RMSNorm -> xn (img+txt one launch)
  rmsnorm2_all<<<3072, 256, 0, stream>>>(h_i, wp1_i, x_img, sc_ffw_i, xn_i,
                                         h_t, wp1_t, x_txt, sc_ffw_t, xn_t);

  // 7. gate|up via gemm8 -> gu (bf16), single launch (640 blocks)
  {
    G8Jobs P;
    P.j[0] = mk8b(xn_i, WguT_i, gu_i, 2048, 16384, 2048, 2048, 0, 30, 0, 0, 30, 0, 16384);
    P.j[1] = mk8b(xn_t, WguT_t, gu_t, 1024, 8192, 1024, 1024, 0, 30, 0, 0, 30, 0, 8192);
    int Mt[2] = {8, 4};
    launch8(P, 2, Mt);
  }
  {
    int total = 2048 * 8192 / 8 + 1024 * 4096 / 8;
    gelu_mul<<<(total + 255) / 256, 256, 0, stream>>>(gu_i, gu_t);
  }

  // 8. DOWN: img split-4 (256 blocks nk=32) + txt split-8 (128 blocks nk=8),
  //    one 12-job launch (384 blocks); p0 -> d_out, partials over dead WguT
  {
    G8Jobs P;
    P.j[0] = mk8f(gu_i,        WdT_i,        outp, 2048, 2048, 16384, 8192, 0, 30, 0, 2048);
    P.j[1] = mk8f(gu_i + 2048, WdT_i + 2048, dp1,  2048, 2048, 16384, 8192, 0, 30, 0, 2048);
    P.j[2] = mk8f(gu_i + 4096, WdT_i + 4096, dp2,  2048, 2048, 16384, 8192, 0, 30, 0, 2048);
    P.j[3] = mk8f(gu_i + 6144, WdT_i + 6144, dp3,  2048, 2048, 16384, 8192, 0, 30, 0, 2048);
    float* dstT[8] = {outp_t, dt1, dt2, dt3, dt4, dt5, dt6, dt7};
    for (int s = 0; s < 8; s++)
      P.j[4 + s] = mk8f(gu_t + s * 512, WdT_t + s * 512, dstT[s], 512, 1024,
                        8192, 4096, 0, 30, 0, 1024);
    int Mt[12] = {8, 8, 8, 8, 4, 4, 4, 4, 4, 4, 4, 4};
    launch8(P, 12, Mt);
  }
  reduce_down<<<2048, 256, 0, stream>>>(
      outp, dp1, dp2, dp3, x_img, 2048 * 2048 / 4,
      outp_t, dt1, dt2, dt3, dt4, dt5, dt6, dt7, x_txt, 1024 * 1024 / 4);
}

// Round 18
// 551.130 us; speedup vs baseline: 1.0987x; 1.0103x over previous
//
#include <hip/hip_runtime.h>
#include <hip/hip_bf16.h>

// MoE (img/txt mixture) transformer block for MI355X.
// Round 18: r17 (556us) + RoPE-q folded into attention's Q load (lane-local
// pairs i / i+64 live in qf[kk] / qf[kk+2]); qkv writes raw q; mid_k is now
// rope-k + V-transpose only (6912 blocks, was 19200). Rest identical.

typedef __hip_bfloat16 bf16;
typedef __attribute__((ext_vector_type(8))) __bf16 bf16x8;
typedef __attribute__((ext_vector_type(4))) float f32x4;

#define DEV __device__ __forceinline__

static constexpr int TT = 1536;
static constexpr int NHQ = 16, NKVH = 8, HDM = 128;

DEV void async_load16(const void* g, void* l) {
  typedef const __attribute__((address_space(1))) void* gas_t;
  typedef __attribute__((address_space(3))) void* las_t;
  __builtin_amdgcn_global_load_lds((gas_t)g, (las_t)l, 16, 0, 0);
}

DEV f32x4 mfma16(bf16x8 a, bf16x8 b, f32x4 c) {
  return __builtin_amdgcn_mfma_f32_16x16x32_bf16(a, b, c, 0, 0, 0);
}

DEV float bf2f(bf16 x) { return __bfloat162float(x); }
DEV bf16  f2bf(float x) { return __float2bfloat16(x); }

// ---------------------------------------------------------------------------
// Weight transpose body: f32 [K][N] -> bf16 [N][K]  (conflict-free)
// ---------------------------------------------------------------------------
struct TJob { const float* src; bf16* dst; int K; int N; };

DEV void wt_body(const TJob& jb, int rel, int t, char* smem) {
  bf16* tile = (bf16*)smem;  // 64*72 elems = 9216 B
  int ntc = jb.N >> 6;
  int tr = rel / ntc, tc = rel - tr * ntc;
  int r0 = tr << 6, c0 = tc << 6;
  #pragma unroll
  for (int i = 0; i < 4; i++) {
    int r = i * 16 + (t >> 4);
    int c = 4 * (t & 15);
    int q = (r >> 3) & 7;
    float4 v = *reinterpret_cast<const float4*>(
        jb.src + (size_t)(r0 + r) * jb.N + c0 + c);
    union { bf16 h[4]; uint2 u; } pk;
    pk.h[0] = f2bf(v.x); pk.h[1] = f2bf(v.y);
    pk.h[2] = f2bf(v.z); pk.h[3] = f2bf(v.w);
    *reinterpret_cast<uint2*>(tile + r * 72 + (c ^ (q << 3))) = pk.u;
  }
  __syncthreads();
  const __bf16* tb = (const __bf16*)tile;
  #pragma unroll
  for (int i = 0; i < 2; i++) {
    int n = (t >> 3) + 32 * i;
    int kc = t & 7;
    int nswz = n ^ (kc << 3);
    bf16x8 v;
    #pragma unroll
    for (int m = 0; m < 8; m++) v[m] = tb[(kc * 8 + m) * 72 + nswz];
    *reinterpret_cast<bf16x8*>(jb.dst + (size_t)(c0 + n) * jb.K + r0 + kc * 8) = v;
  }
}

// ---------------------------------------------------------------------------
// RMSNorm bodies
// ---------------------------------------------------------------------------
template <int DV>
DEV void rms_body(const float* __restrict__ x, const float* __restrict__ sc,
                  bf16* __restrict__ out, int row, int t, float* red) {
  const int D = DV * 1024;
  const float4* xr = reinterpret_cast<const float4*>(x + (size_t)row * D);
  float4 v[DV];
  float ss = 0.f;
  #pragma unroll
  for (int i = 0; i < DV; i++) {
    v[i] = xr[t + i * 256];
    ss += v[i].x * v[i].x + v[i].y * v[i].y + v[i].z * v[i].z + v[i].w * v[i].w;
  }
  #pragma unroll
  for (int o = 1; o < 64; o <<= 1) ss += __shfl_xor(ss, o);
  if ((t & 63) == 0) red[t >> 6] = ss;
  __syncthreads();
  float r = rsqrtf((red[0] + red[1] + red[2] + red[3]) * (1.0f / D) + 1e-6f);
  bf16* orow = out + (size_t)row * D;
  #pragma unroll
  for (int i = 0; i < DV; i++) {
    int c = (t + i * 256) * 4;
    orow[c + 0] = f2bf(v[i].x * r * (1.f + sc[c + 0]));
    orow[c + 1] = f2bf(v[i].y * r * (1.f + sc[c + 1]));
    orow[c + 2] = f2bf(v[i].z * r * (1.f + sc[c + 2]));
    orow[c + 3] = f2bf(v[i].w * r * (1.f + sc[c + 3]));
  }
}

template <int DV>
DEV void rms2_body(const float* __restrict__ p0, const float* __restrict__ p1,
                   const float* __restrict__ x, const float* __restrict__ sc,
                   bf16* __restrict__ out, int row, int t, float* red) {
  const int D = DV * 1024;
  size_t rb = (size_t)row * (D / 4);
  const float4* r0 = reinterpret_cast<const float4*>(p0) + rb;
  const float4* r1 = reinterpret_cast<const float4*>(p1) + rb;
  const float4* xr = reinterpret_cast<const float4*>(x) + rb;
  float4 v[DV];
  float ss = 0.f;
  #pragma unroll
  for (int i = 0; i < DV; i++) {
    int idx = t + i * 256;
    float4 a = r0[idx], b = r1[idx], e = xr[idx];
    v[i] = make_float4(a.x + b.x + e.x, a.y + b.y + e.y,
                       a.z + b.z + e.z, a.w + b.w + e.w);
    ss += v[i].x * v[i].x + v[i].y * v[i].y + v[i].z * v[i].z + v[i].w * v[i].w;
  }
  #pragma unroll
  for (int o = 1; o < 64; o <<= 1) ss += __shfl_xor(ss, o);
  if ((t & 63) == 0) red[t >> 6] = ss;
  __syncthreads();
  float r = rsqrtf((red[0] + red[1] + red[2] + red[3]) * (1.0f / D) + 1e-6f);
  bf16* orow = out + (size_t)row * D;
  #pragma unroll
  for (int i = 0; i < DV; i++) {
    int c = (t + i * 256) * 4;
    orow[c + 0] = f2bf(v[i].x * r * (1.f + sc[c + 0]));
    orow[c + 1] = f2bf(v[i].y * r * (1.f + sc[c + 1]));
    orow[c + 2] = f2bf(v[i].z * r * (1.f + sc[c + 2]));
    orow[c + 3] = f2bf(v[i].w * r * (1.f + sc[c + 3]));
  }
}

// ---------------------------------------------------------------------------
// pre_k: blocks [0,2048) rmsnorm img; [2048,3072) rmsnorm txt;
//        [3072, 3072+nwt) attn-weight transpose (8 jobs)
// ---------------------------------------------------------------------------
struct PreArgs {
  const float* xi; const float* sci; bf16* oi;
  const float* xt; const float* sct; bf16* ot;
  TJob j[8]; int cum[9];
};

__global__ __launch_bounds__(256) void pre_k(PreArgs A) {
  __shared__ __align__(16) char smem[9216];
  int bid = blockIdx.x;
  int t = threadIdx.x;
  if (bid < 2048) { rms_body<2>(A.xi, A.sci, A.oi, bid, t, (float*)smem); return; }
  if (bid < 3072) { rms_body<1>(A.xt, A.sct, A.ot, bid - 2048, t, (float*)smem); return; }
  int rel = bid - 3072;
  int ji = 0;
  while (ji < 7 && rel >= A.cum[ji + 1]) ji++;
  wt_body(A.j[ji], rel - A.cum[ji], t, smem);
}

// ---------------------------------------------------------------------------
// mid_k: blocks [0,6144) rope k; [6144,6912) V-transpose
// ---------------------------------------------------------------------------
struct MidArgs { bf16* k; const bf16* v; bf16* vt; };

DEV void rope_body(bf16* __restrict__ x, int lognh, float scale, int bid, int t) {
  int gid = bid * 256 + t;
  int i = gid & 63;
  int rh = gid >> 6;
  int row = rh >> lognh;
  int pos = row >= TT ? row - TT : row;
  float fr = __expf(-9.210340371976184f * ((float)(2 * i) * (1.0f / 128.0f)));
  float th = (float)pos * fr;
  float s, c;
  __sincosf(th, &s, &c);
  bf16* p = x + (size_t)rh * HDM;
  float x1 = bf2f(p[i]), x2 = bf2f(p[i + 64]);
  p[i]      = f2bf((x1 * c - x2 * s) * scale);
  p[i + 64] = f2bf((x2 * c + x1 * s) * scale);
}

__global__ __launch_bounds__(256) void mid_k(MidArgs A) {
  __shared__ bf16 tile[64][65];
  int bid = blockIdx.x;
  int t = threadIdx.x;
  if (bid < 6144) { rope_body(A.k, 3, 1.0f, bid, t); return; }
  int r = bid - 6144;                // 768 = 24 st x 2 ht x 16 bk
  int st = r % 24;
  int rem = r / 24;
  int ht = rem & 1;
  int bk = rem >> 1;
  int b = bk >> 3, kv = bk & 7;
  int s0 = st * 64, h0 = ht * 64;
  #pragma unroll
  for (int i = 0; i < 16; i++) {
    int idx = i * 256 + t;
    int rr = idx >> 6, c = idx & 63;
    tile[c][rr] = A.v[((size_t)(b * TT + s0 + rr) * NKVH + kv) * HDM + h0 + c];
  }
  __syncthreads();
  #pragma unroll
  for (int i = 0; i < 16; i++) {
    int idx = i * 256 + t;
    int rr = idx >> 6, c = idx & 63;
    A.vt[((size_t)bk * HDM + h0 + rr) * TT + s0 + c] = tile[rr][c];
  }
}

// ---------------------------------------------------------------------------
// rmsnorm2_all: blocks [0,2048) img; [2048,3072) txt
// ---------------------------------------------------------------------------
__global__ __launch_bounds__(256) void rmsnorm2_all(
    const float* p0i, const float* p1i, const float* xi, const float* sci, bf16* oi,
    const float* p0t, const float* p1t, const float* xt, const float* sct, bf16* ot) {
  __shared__ float red[4];
  int bid = blockIdx.x;
  int t = threadIdx.x;
  if (bid < 2048) rms2_body<2>(p0i, p1i, xi, sci, oi, bid, t, red);
  else            rms2_body<1>(p0t, p1t, xt, sct, ot, bid - 2048, t, red);
}

// ---------------------------------------------------------------------------
// 256x256 GEMM - r9 reduced-barrier K-loop (3 barriers/tile). PROVEN.
// ---------------------------------------------------------------------------
struct G8Job {
  const bf16* A; const bf16* B; bf16* Cb; float* Cf;
  int K, N, lda, ldb;
  int a_base, a_lsh, a_lskip;
  int c_base, c_lsh, c_lskip, c_stride;
};
struct G8Jobs { G8Job j[12]; int cum[13]; int nj; };

#define G8_MFMA(MH, NH)                                            \
  __builtin_amdgcn_s_setprio(1);                                   \
  _Pragma("unroll")                                                \
  for (int i = 0; i < 4; i++)                                      \
    _Pragma("unroll")                                              \
    for (int nj2 = 0; nj2 < 2; nj2++)                              \
      _Pragma("unroll")                                            \
      for (int kk = 0; kk < 2; kk++)                               \
        acc[(MH)*4 + i][(NH)*2 + nj2] = mfma16(                    \
            afr[i][kk], bfr[(NH)*2 + nj2][kk],                     \
            acc[(MH)*4 + i][(NH)*2 + nj2]);                        \
  __builtin_amdgcn_s_setprio(0);

__global__ __launch_bounds__(512, 2) void gemm8(G8Jobs P) {
  extern __shared__ __align__(16) bf16 lds8[];
  int bid = blockIdx.x;
  int ji = 0;
  while (ji < P.nj - 1 && bid >= P.cum[ji + 1]) ji++;
  const G8Job jb = P.j[ji];
  int rel = bid - P.cum[ji];
  int tn = jb.N >> 8;
  int bm = rel / tn, bn = rel - bm * tn;
  const int m0 = bm << 8, n0 = bn << 8;
  const int K = jb.K;
  const int nk = K >> 6;

  const int tid = threadIdx.x;
  const int w = tid >> 6, l = tid & 63;
  const int lr = l & 15, lk = l >> 4;
  const int wr = w >> 2, wc = w & 3;

  const int r0 = tid >> 3, sl0 = (tid & 7) ^ (r0 & 7);
  const int dst0 = (w * 64) * 8;
  const int dst1 = (512 + w * 64) * 8;

  auto stage = [&](int ht, int hq) {
    int k0 = ht << 6;
    bf16* ldsb = lds8 + ((ht & 1) * 32768 + hq * 8192);
    if (hq < 2) {
      int ma = m0 + hq * 128;
      int mr0 = ma + r0, mr1 = ma + 64 + r0;
      int pr0 = jb.a_base + mr0 + ((mr0 >> jb.a_lsh) * jb.a_lskip);
      int pr1 = jb.a_base + mr1 + ((mr1 >> jb.a_lsh) * jb.a_lskip);
      async_load16(jb.A + (size_t)pr0 * jb.lda + k0 + sl0 * 8, ldsb + dst0);
      async_load16(jb.A + (size_t)pr1 * jb.lda + k0 + sl0 * 8, ldsb + dst1);
    } else {
      int nb = n0 + (hq - 2) * 128;
      async_load16(jb.B + (size_t)(nb + r0) * jb.ldb + k0 + sl0 * 8, ldsb + dst0);
      async_load16(jb.B + (size_t)(nb + 64 + r0) * jb.ldb + k0 + sl0 * 8, ldsb + dst1);
    }
  };

  f32x4 acc[8][4];
  #pragma unroll
  for (int i = 0; i < 8; i++)
    #pragma unroll
    for (int j = 0; j < 4; j++) acc[i][j] = (f32x4){0.f, 0.f, 0.f, 0.f};

  const int s0 = ((0 * 4 + lk) ^ (lr & 7)) * 8;
  const int s1 = ((1 * 4 + lk) ^ (lr & 7)) * 8;
  const int browb = (wc & 1) * 64;

  #pragma unroll
  for (int hq = 0; hq < 4; hq++) stage(0, hq);
  #pragma unroll
  for (int hq = 0; hq < 4; hq++) stage(1, hq);
  asm volatile("s_waitcnt vmcnt(8)" ::: "memory");
  __builtin_amdgcn_s_barrier();
  asm volatile("" ::: "memory");

  bf16x8 afr[4][2], bfr[4][2];

  for (int t = 0; t < nk; t++) {
    const bf16* bufA = lds8 + (t & 1) * 32768 + wr * 8192;
    const bf16* bufB = lds8 + (t & 1) * 32768 + 16384 + (wc >> 1) * 8192;
    const bool st = (t + 2 < nk);

    #pragma unroll
    for (int i = 0; i < 4; i++) {
      int rb = (i * 16 + lr) * 64;
      afr[i][0] = *reinterpret_cast<const bf16x8*>(bufA + rb + s0);
      afr[i][1] = *reinterpret_cast<const bf16x8*>(bufA + rb + s1);
    }
    #pragma unroll
    for (int ni = 0; ni < 2; ni++) {
      int rb = (browb + ni * 16 + lr) * 64;
      bfr[ni][0] = *reinterpret_cast<const bf16x8*>(bufB + rb + s0);
      bfr[ni][1] = *reinterpret_cast<const bf16x8*>(bufB + rb + s1);
    }
    asm volatile("s_waitcnt lgkmcnt(0)" ::: "memory");
    __builtin_amdgcn_sched_barrier(0);
    G8_MFMA(0, 0)

    #pragma unroll
    for (int ni = 2; ni < 4; ni++) {
      int rb = (browb + ni * 16 + lr) * 64;
      bfr[ni][0] = *reinterpret_cast<const bf16x8*>(bufB + rb + s0);
      bfr[ni][1] = *reinterpret_cast<const bf16x8*>(bufB + rb + s1);
    }
    asm volatile("s_waitcnt lgkmcnt(0)" ::: "memory");
    __builtin_amdgcn_sched_barrier(0);
    G8_MFMA(0, 1)
    __builtin_amdgcn_s_barrier();
    asm volatile("" ::: "memory");

    #pragma unroll
    for (int i = 0; i < 4; i++) {
      int rb = ((i + 4) * 16 + lr) * 64;
      afr[i][0] = *reinterpret_cast<const bf16x8*>(bufA + rb + s0);
      afr[i][1] = *reinterpret_cast<const bf16x8*>(bufA + rb + s1);
    }
    if (st) { stage(t + 2, 2); stage(t + 2, 3); }
    asm volatile("s_waitcnt lgkmcnt(0)" ::: "memory");
    __builtin_amdgcn_sched_barrier(0);
    G8_MFMA(1, 0)
    __builtin_amdgcn_s_barrier();
    asm volatile("" ::: "memory");

    if (st) {
      stage(t + 2, 0); stage(t + 2, 1);
      asm volatile("s_waitcnt vmcnt(8)" ::: "memory");
    } else if (t == nk - 2) {
      asm volatile("s_waitcnt vmcnt(0)" ::: "memory");
    }
    G8_MFMA(1, 1)
    __builtin_amdgcn_s_barrier();
    asm volatile("" ::: "memory");
  }

  if (jb.Cf) {
    #pragma unroll
    for (int mi = 0; mi < 8; mi++)
      #pragma unroll
      for (int jj = 0; jj < 4; jj++) {
        int m = m0 + wr * 128 + mi * 16 + lk * 4 + jj;
        float* drow = jb.Cf + (size_t)m * jb.c_stride + n0 + wc * 64;
        #pragma unroll
        for (int ni = 0; ni < 4; ni++) drow[ni * 16 + lr] = acc[mi][ni][jj];
      }
  } else {
    #pragma unroll
    for (int mi = 0; mi < 8; mi++)
      #pragma unroll
      for (int jj = 0; jj < 4; jj++) {
        int m = m0 + wr * 128 + mi * 16 + lk * 4 + jj;
        int crow = jb.c_base + m + ((m >> jb.c_lsh) * jb.c_lskip);
        bf16* drow = jb.Cb + (size_t)crow * jb.c_stride + n0 + wc * 64;
        #pragma unroll
        for (int ni = 0; ni < 4; ni++) drow[ni * 16 + lr] = f2bf(acc[mi][ni][jj]);
      }
  }
}

// ---------------------------------------------------------------------------
// Down split-K reduce: img out += p1+p2+p3+x ; txt out += q1..q7+x
// ---------------------------------------------------------------------------
__global__ __launch_bounds__(256) void reduce_down(
    float* __restrict__ oi, const float* __restrict__ a1,
    const float* __restrict__ a2, const float* __restrict__ a3,
    const float* __restrict__ xi, int n4i,
    float* __restrict__ ot, const float* __restrict__ b1,
    const float* __restrict__ b2, const float* __restrict__ b3,
    const float* __restrict__ b4, const float* __restrict__ b5,
    const float* __restrict__ b6, const float* __restrict__ b7,
    const float* __restrict__ xt, int n4t) {
  int tot = n4i + n4t;
  for (int idx = blockIdx.x * 256 + threadIdx.x; idx < tot; idx += gridDim.x * 256) {
    if (idx < n4i) {
      float4 d = ((const float4*)oi)[idx];
      float4 a = ((const float4*)a1)[idx];
      float4 b = ((const float4*)a2)[idx];
      float4 c = ((const float4*)a3)[idx];
      float4 e = ((const float4*)xi)[idx];
      ((float4*)oi)[idx] = make_float4(d.x + a.x + b.x + c.x + e.x,
                                       d.y + a.y + b.y + c.y + e.y,
                                       d.z + a.z + b.z + c.z + e.z,
                                       d.w + a.w + b.w + c.w + e.w);
    } else {
      int i = idx - n4i;
      float4 d = ((const float4*)ot)[i];
      float4 p1 = ((const float4*)b1)[i];
      float4 p2 = ((const float4*)b2)[i];
      float4 p3 = ((const float4*)b3)[i];
      float4 p4 = ((const float4*)b4)[i];
      float4 p5 = ((const float4*)b5)[i];
      float4 p6 = ((const float4*)b6)[i];
      float4 p7 = ((const float4*)b7)[i];
      float4 e = ((const float4*)xt)[i];
      ((float4*)ot)[i] = make_float4(
          d.x + p1.x + p2.x + p3.x + p4.x + p5.x + p6.x + p7.x + e.x,
          d.y + p1.y + p2.y + p3.y + p4.y + p5.y + p6.y + p7.y + e.y,
          d.z + p1.z + p2.z + p3.z + p4.z + p5.z + p6.z + p7.z + e.z,
          d.w + p1.w + p2.w + p3.w + p4.w + p5.w + p6.w + p7.w + e.w);
    }
  }
}

// ---------------------------------------------------------------------------
// In-place GELU(gate)*up over gu buffers: act written to gate half.
// ---------------------------------------------------------------------------
__global__ __launch_bounds__(256) void gelu_mul(bf16* __restrict__ gu_i,
                                                bf16* __restrict__ gu_t) {
  const int IMG_CH = 2048 * 8192 / 8;
  const int TXT_CH = 1024 * 4096 / 8;
  int idx = blockIdx.x * 256 + threadIdx.x;
  int total = IMG_CH + TXT_CH;
  if (idx >= total) return;
  bf16* base;
  int half, ci;
  if (idx < IMG_CH) { base = gu_i; half = 8192; ci = idx; }
  else              { base = gu_t; half = 4096; ci = idx - IMG_CH; }
  int rowlen = half * 2;
  int perrow = half / 8;
  int m = ci / perrow, n8 = ci - m * perrow;
  bf16* gp = base + (size_t)m * rowlen + n8 * 8;
  bf16* up = gp + half;
  bf16x8 g8 = *reinterpret_cast<const bf16x8*>(gp);
  bf16x8 u8 = *reinterpret_cast<const bf16x8*>(up);
  bf16x8 o8;
  #pragma unroll
  for (int i = 0; i < 8; i++) {
    float g = (float)g8[i], u = (float)u8[i];
    float t = tanhf(0.7978845608028654f * (g + 0.044715f * g * g * g));
    o8[i] = (__bf16)(0.5f * g * (1.f + t) * u);
  }
  *reinterpret_cast<bf16x8*>(gp) = o8;
}

// ---------------------------------------------------------------------------
// Fused: attention (blocks 0..767) + FFN weight transpose (blocks 768+).
// Attention: reg-staged K/V double buffer, raw barriers, fast softcap,
// lane-local denominator, RoPE-q applied in-register at Q load.
// smem = 32768: Ksm [0,16K) (Psm aliases it), Vsm [16K,32K).
// ---------------------------------------------------------------------------
struct FAArgs {
  const bf16* q_all; const bf16* k_all; const bf16* vt; bf16* attn_o;
  TJob j[6]; int cum[7];
};

__global__ __launch_bounds__(256) void attn_wt(FAArgs A) {
  __shared__ __align__(16) char smem[32768];
  const int bid = blockIdx.x;
  const int tid = threadIdx.x;
  if (bid >= 768) {
    int rel = bid - 768;
    int ji = 0;
    while (ji < 5 && rel >= A.cum[ji + 1]) ji++;
    wt_body(A.j[ji], rel - A.cum[ji], tid, smem);
    return;
  }
  const int qt = bid % 24;
  const int n = (bid / 24) & 15;
  const int b = bid / 384;
  const int kv = n >> 1;
  const int w = tid >> 6, l = tid & 63;
  const int lr = l & 15, lk = l >> 4;
  bf16* Ksm = (bf16*)smem;
  bf16* Vsm = (bf16*)(smem + 16384);
  typedef bf16 PsmRow[16][72];
  PsmRow* Psm = (PsmRow*)smem;

  bf16x8 qf[4];
  {
    int tok = qt * 64 + w * 16 + lr;
    const bf16* qp = A.q_all + ((size_t)(b * TT + tok) * NHQ + n) * HDM;
    #pragma unroll
    for (int kk = 0; kk < 4; kk++)
      qf[kk] = *reinterpret_cast<const bf16x8*>(qp + kk * 32 + lk * 8);
    // RoPE-q in-register: pair (i, i+64) = (qf[kk][m], qf[kk+2][m]), kk<2
    const float SC = 0.08838834764831845f;  // HD^-0.5
    #pragma unroll
    for (int kk = 0; kk < 2; kk++)
      #pragma unroll
      for (int m = 0; m < 8; m++) {
        int i = kk * 32 + lk * 8 + m;
        float fr = __expf(-0.14391156831212787f * (float)i);
        float th = (float)tok * fr;
        float s, c;
        __sincosf(th, &s, &c);
        float x1 = bf2f(qf[kk][m]), x2 = bf2f(qf[kk + 2][m]);
        qf[kk][m]     = (__bf16)((x1 * c - x2 * s) * SC);
        qf[kk + 2][m] = (__bf16)((x2 * c + x1 * s) * SC);
      }
  }
  int kwo[4], vwo[4];
  const bf16* kp[4];
  const bf16* vp[4];
  #pragma unroll
  for (int i = 0; i < 4; i++) {
    int c = i * 256 + tid;
    int krow = c >> 4, kcol = c & 15;
    kwo[i] = krow * 128 + ((kcol ^ (krow & 7)) << 3);
    kp[i] = A.k_all + ((size_t)(b * TT + krow) * NKVH + kv) * HDM + kcol * 8;
    int vrow = c >> 3, vcol = c & 7;
    vwo[i] = vrow * 64 + ((vcol ^ (vrow & 7)) << 3);
    vp[i] = A.vt + ((size_t)(b * NKVH + kv) * HDM + vrow) * TT + vcol * 8;
  }
  bf16x8 kreg[4], vreg[4];
  #pragma unroll
  for (int i = 0; i < 4; i++) {
    kreg[i] = *reinterpret_cast<const bf16x8*>(kp[i]); kp[i] += 64 * NKVH * HDM;
    vreg[i] = *reinterpret_cast<const bf16x8*>(vp[i]); vp[i] += 64;
  }

  f32x4 acc_o[8];
  #pragma unroll
  for (int i = 0; i < 8; i++) acc_o[i] = (f32x4){0.f, 0.f, 0.f, 0.f};
  float den[4] = {0.f, 0.f, 0.f, 0.f};

  for (int st = 0; st < TT / 64; st++) {
    asm volatile("s_waitcnt vmcnt(0)" ::: "memory");
    __builtin_amdgcn_s_barrier();
    asm volatile("" ::: "memory");
    #pragma unroll
    for (int i = 0; i < 4; i++) {
      *reinterpret_cast<bf16x8*>(Ksm + kwo[i]) = kreg[i];
      *reinterpret_cast<bf16x8*>(Vsm + vwo[i]) = vreg[i];
    }
    if (st + 1 < TT / 64) {
      #pragma unroll
      for (int i = 0; i < 4; i++) {
        kreg[i] = *reinterpret_cast<const bf16x8*>(kp[i]); kp[i] += 64 * NKVH * HDM;
        vreg[i] = *reinterpret_cast<const bf16x8*>(vp[i]); vp[i] += 64;
      }
    }
    asm volatile("s_waitcnt lgkmcnt(0)" ::: "memory");
    __builtin_amdgcn_s_barrier();
    asm volatile("" ::: "memory");
    f32x4 sq[4];
    #pragma unroll
    for (int sf = 0; sf < 4; sf++) {
      f32x4 s4 = (f32x4){0.f, 0.f, 0.f, 0.f};
      int sl = sf * 16 + lr;
      #pragma unroll
      for (int kk = 0; kk < 4; kk++) {
        int e = kk * 32 + lk * 8;
        bf16x8 kf = *reinterpret_cast<const bf16x8*>(
            Ksm + sl * 128 + ((((e >> 3) ^ (sl & 7))) << 3));
        s4 = mfma16(qf[kk], kf, s4);
      }
      sq[sf] = s4;
    }
    asm volatile("s_waitcnt lgkmcnt(0)" ::: "memory");
    __builtin_amdgcn_s_barrier();
    asm volatile("" ::: "memory");
    #pragma unroll
    for (int sf = 0; sf < 4; sf++) {
      #pragma unroll
      for (int j = 0; j < 4; j++) {
        float xv = sq[sf][j];
        float e2 = __expf(xv * 0.04f);
        float rr = __builtin_amdgcn_rcpf(e2 + 1.0f);
        float p = __expf(50.0f - 100.0f * rr);
        Psm[w][lk * 4 + j][sf * 16 + lr] = f2bf(p);
        den[j] += p;
      }
    }
    #pragma unroll
    for (int kk2 = 0; kk2 < 2; kk2++) {
      bf16x8 pa = *reinterpret_cast<const bf16x8*>(&Psm[w][lr][kk2 * 32 + lk * 8]);
      #pragma unroll
      for (int hf = 0; hf < 8; hf++) {
        int h = hf * 16 + lr;
        int e2i = kk2 * 32 + lk * 8;
        bf16x8 vb = *reinterpret_cast<const bf16x8*>(
            Vsm + h * 64 + ((((e2i >> 3) ^ (h & 7))) << 3));
        acc_o[hf] = mfma16(pa, vb, acc_o[hf]);
      }
    }
  }
  #pragma unroll
  for (int j = 0; j < 4; j++) {
    den[j] += __shfl_xor(den[j], 1);
    den[j] += __shfl_xor(den[j], 2);
    den[j] += __shfl_xor(den[j], 4);
    den[j] += __shfl_xor(den[j], 8);
  }
  #pragma unroll
  for (int hf = 0; hf < 8; hf++)
    #pragma unroll
    for (int j = 0; j < 4; j++) {
      int t = qt * 64 + w * 16 + lk * 4 + j;
      float val = acc_o[hf][j] / den[j];
      A.attn_o[((size_t)(b * TT + t)) * (NHQ * HDM) + n * HDM + hf * 16 + lr] =
          f2bf(val);
    }
}

// ---------------------------------------------------------------------------
extern "C" void kernel_launch(void* const* d_in, const int* in_sizes, int n_in,
                              void* d_out, int out_size, void* d_ws,
                              size_t ws_size, hipStream_t stream) {
  const float* x_img = (const float*)d_in[0];
  const float* x_txt = (const float*)d_in[1];
  const float* sc_attn_i = (const float*)d_in[3];
  const float* wq_i = (const float*)d_in[4];
  const float* wk_i = (const float*)d_in[5];
  const float* wv_i = (const float*)d_in[6];
  const float* wo_i = (const float*)d_in[7];
  const float* sc_ffw_i = (const float*)d_in[8];
  const float* wg_i = (const float*)d_in[9];
  const float* wu_i = (const float*)d_in[10];
  const float* wd_i = (const float*)d_in[11];
  const float* sc_attn_t = (const float*)d_in[12];
  const float* wq_t = (const float*)d_in[13];
  const float* wk_t = (const float*)d_in[14];
  const float* wv_t = (const float*)d_in[15];
  const float* wo_t = (const float*)d_in[16];
  const float* sc_ffw_t = (const float*)d_in[17];
  const float* wg_t = (const float*)d_in[18];
  const float* wu_t = (const float*)d_in[19];
  const float* wd_t = (const float*)d_in[20];
  float* outp = (float*)d_out;
  float* outp_t = outp + (size_t)2 * 1024 * 2048;

  char* ws = (char*)d_ws;
  size_t off = 0;
  auto alloc = [&](size_t n) {
    char* p = ws + off;
    off += (n + 255) & ~(size_t)255;
    return p;
  };
  bf16* WqT_i = (bf16*)alloc((size_t)2048 * 2048 * 2);
  bf16* WkT_i = (bf16*)alloc((size_t)1024 * 2048 * 2);
  bf16* WvT_i = (bf16*)alloc((size_t)1024 * 2048 * 2);
  bf16* WoT_i = (bf16*)alloc((size_t)2048 * 2048 * 2);
  bf16* WguT_i = (bf16*)alloc((size_t)16384 * 2048 * 2);  // 64 MB
  bf16* WdT_i = (bf16*)alloc((size_t)2048 * 8192 * 2);
  bf16* WqT_t = (bf16*)alloc((size_t)2048 * 1024 * 2);
  bf16* WkT_t = (bf16*)alloc((size_t)1024 * 1024 * 2);
  bf16* WvT_t = (bf16*)alloc((size_t)1024 * 1024 * 2);
  bf16* WoT_t = (bf16*)alloc((size_t)1024 * 2048 * 2);
  bf16* WguT_t = (bf16*)alloc((size_t)8192 * 1024 * 2);   // 16 MB
  bf16* WdT_t = (bf16*)alloc((size_t)1024 * 4096 * 2);
  bf16* xn_i = (bf16*)alloc((size_t)2048 * 2048 * 2);
  bf16* xn_t = (bf16*)alloc((size_t)1024 * 1024 * 2);
  float* h_i = (float*)alloc((size_t)2048 * 2048 * 4);  // wo p0 img
  float* h_t = (float*)alloc((size_t)1024 * 1024 * 4);  // wo p0 txt
  char* S = (char*)alloc((size_t)84 * 1024 * 1024);
  (void)ws_size;

  const size_t MB = 1024 * 1024;
  bf16* q_all = (bf16*)S;
  bf16* k_all = (bf16*)(S + 12 * MB);
  bf16* v_all = (bf16*)(S + 18 * MB);
  bf16* vtr   = (bf16*)(S + 24 * MB);
  bf16* attn_o= (bf16*)(S + 30 * MB);
  float* wp1_i = (float*)S;
  float* wp1_t = (float*)(S + 16 * MB);
  bf16* gu_i  = (bf16*)S;
  bf16* gu_t  = (bf16*)(S + 64 * MB);
  float* dp1 = (float*)WguT_i;
  float* dp2 = (float*)((char*)WguT_i + 16 * MB);
  float* dp3 = (float*)((char*)WguT_i + 32 * MB);
  float* dt1 = (float*)((char*)WguT_i + 48 * MB);
  float* dt2 = (float*)((char*)WguT_i + 52 * MB);
  float* dt3 = (float*)((char*)WguT_i + 56 * MB);
  float* dt4 = (float*)((char*)WguT_i + 60 * MB);
  float* dt5 = (float*)WguT_t;
  float* dt6 = (float*)((char*)WguT_t + 4 * MB);
  float* dt7 = (float*)((char*)WguT_t + 8 * MB);

  (void)hipFuncSetAttribute(reinterpret_cast<const void*>(gemm8),
                            hipFuncAttributeMaxDynamicSharedMemorySize, 131072);

  // 1. pre_k: rmsnorm img/txt + attn weight transpose
  {
    PreArgs A;
    A.xi = x_img; A.sci = sc_attn_i; A.oi = xn_i;
    A.xt = x_txt; A.sct = sc_attn_t; A.ot = xn_t;
    auto setj = [&](int idx, const float* s, bf16* d, int K, int N) {
      A.j[idx].src = s; A.j[idx].dst = d; A.j[idx].K = K; A.j[idx].N = N;
    };
    setj(0, wq_i, WqT_i, 2048, 2048);
    setj(1, wk_i, WkT_i, 2048, 1024);
    setj(2, wv_i, WvT_i, 2048, 1024);
    setj(3, wo_i, WoT_i, 2048, 2048);
    setj(4, wq_t, WqT_t, 1024, 2048);
    setj(5, wk_t, WkT_t, 1024, 1024);
    setj(6, wv_t, WvT_t, 1024, 1024);
    setj(7, wo_t, WoT_t, 2048, 1024);
    A.cum[0] = 0;
    for (int i = 0; i < 8; i++)
      A.cum[i + 1] = A.cum[i] + (A.j[i].K >> 6) * (A.j[i].N >> 6);
    pre_k<<<3072 + A.cum[8], 256, 0, stream>>>(A);
  }

  auto mk8b = [](const bf16* A, const bf16* B, bf16* Cb, int K, int N, int lda,
                 int ldb, int ab, int ash, int ask, int cb2, int csh, int csk,
                 int cstr) {
    G8Job g{};
    g.A = A; g.B = B; g.Cb = Cb; g.Cf = nullptr;
    g.K = K; g.N = N; g.lda = lda; g.ldb = ldb;
    g.a_base = ab; g.a_lsh = ash; g.a_lskip = ask;
    g.c_base = cb2; g.c_lsh = csh; g.c_lskip = csk; g.c_stride = cstr;
    return g;
  };
  auto mk8f = [](const bf16* A, const bf16* B, float* Cf, int K, int N, int lda,
                 int ldb, int ab, int ash, int ask, int cstr) {
    G8Job g{};
    g.A = A; g.B = B; g.Cb = nullptr; g.Cf = Cf;
    g.K = K; g.N = N; g.lda = lda; g.ldb = ldb;
    g.a_base = ab; g.a_lsh = ash; g.a_lskip = ask;
    g.c_base = 0; g.c_lsh = 30; g.c_lskip = 0; g.c_stride = cstr;
    return g;
  };
  auto launch8 = [&](G8Jobs& P, int nj, const int* Mt) {
    P.nj = nj;
    P.cum[0] = 0;
    for (int i = 0; i < nj; i++) P.cum[i + 1] = P.cum[i] + Mt[i] * (P.j[i].N >> 8);
    gemm8<<<P.cum[nj], 512, 131072, stream>>>(P);
  };

  // 2. QKV via gemm8 (192 blocks); q written RAW (rope applied in attn)
  {
    G8Jobs P;
    P.j[0] = mk8b(xn_i, WqT_i, q_all, 2048, 2048, 2048, 2048, 0, 30, 0, 0, 10, 512, 2048);
    P.j[1] = mk8b(xn_i, WkT_i, k_all, 2048, 1024, 2048, 2048, 0, 30, 0, 0, 10, 512, 1024);
    P.j[2] = mk8b(xn_i, WvT_i, v_all, 2048, 1024, 2048, 2048, 0, 30, 0, 0, 10, 512, 1024);
    P.j[3] = mk8b(xn_t, WqT_t, q_all, 1024, 2048, 1024, 1024, 0, 30, 0, 1024, 9, 1024, 2048);
    P.j[4] = mk8b(xn_t, WkT_t, k_all, 1024, 1024, 1024, 1024, 0, 30, 0, 1024, 9, 1024, 1024);
    P.j[5] = mk8b(xn_t, WvT_t, v_all, 1024, 1024, 1024, 1024, 0, 30, 0, 1024, 9, 1024, 1024);
    int Mt[6] = {8, 8, 8, 4, 4, 4};
    launch8(P, 6, Mt);
  }

  // 3. mid_k: rope k + V transpose (6912 blocks)
  {
    MidArgs A;
    A.k = k_all; A.v = v_all; A.vt = vtr;
    mid_k<<<6912, 256, 0, stream>>>(A);
  }

  // 4. attention + FFN weight transpose fused (768 + 15360 blocks)
  {
    FAArgs A;
    A.q_all = q_all; A.k_all = k_all; A.vt = vtr; A.attn_o = attn_o;
    auto setf = [&](int idx, const float* s, bf16* d, int K, int N) {
      A.j[idx].src = s; A.j[idx].dst = d; A.j[idx].K = K; A.j[idx].N = N;
    };
    setf(0, wg_i, WguT_i, 2048, 8192);
    setf(1, wu_i, WguT_i + (size_t)8192 * 2048, 2048, 8192);
    setf(2, wd_i, WdT_i, 8192, 2048);
    setf(3, wg_t, WguT_t, 1024, 4096);
    setf(4, wu_t, WguT_t + (size_t)4096 * 1024, 1024, 4096);
    setf(5, wd_t, WdT_t, 4096, 1024);
    A.cum[0] = 0;
    for (int i = 0; i < 6; i++)
      A.cum[i + 1] = A.cum[i] + (A.j[i].K >> 6) * (A.j[i].N >> 6);
    attn_wt<<<768 + A.cum[6], 256, 0, stream>>>(A);
  }

  // 5. WO split-K=2 (160 blocks): p0 -> h, p1 -> wp1
  {
    G8Jobs P;
    P.j[0] = mk8f(attn_o,        WoT_i,        h_i,   1024, 2048, 2048, 2048, 0, 10, 512, 2048);
    P.j[1] = mk8f(attn_o + 1024, WoT_i + 1024, wp1_i, 1024, 2048, 2048, 2048, 0, 10, 512, 2048);
    P.j[2] = mk8f(attn_o,        WoT_t,        h_t,   1024, 1024, 2048, 2048, 1024, 9, 1024, 1024);
    P.j[3] = mk8f(attn_o + 1024, WoT_t + 1024, wp1_t, 1024, 1024, 2048, 2048, 1024, 9, 1024, 1024);
    int Mt[4] = {8, 8, 4, 4};
    launch8(P, 4, Mt);
  }

  // 6. fused (p0+p1+x) RMSNorm -> xn (img+txt one launch)
  rmsnorm2_all<<<3072, 256, 0, stream>>>(h_i, wp1_i, x_img, sc_ffw_i, xn_i,
                                         h_t, wp1_t, x_txt, sc_ffw_t, xn_t);

  // 7. gate|up via gemm8 -> gu (bf16), single launch (640 blocks)
  {
    G8Jobs P;
    P.j[0] = mk8b(xn_i, WguT_i, gu_i, 2048, 16384, 2048, 2048, 0, 30, 0, 0, 30, 0, 16384);
    P.j[1] = mk8b(xn_t, WguT_t, gu_t, 1024, 8192, 1024, 1024, 0, 30, 0, 0, 30, 0, 8192);
    int Mt[2] = {8, 4};
    launch8(P, 2, Mt);
  }
  {
    int total = 2048 * 8192 / 8 + 1024 * 4096 / 8;
    gelu_mul<<<(total + 255) / 256, 256, 0, stream>>>(gu_i, gu_t);
  }

  // 8. DOWN: img split-4 + txt split-8 in one 12-job launch (384 blocks)
  {
    G8Jobs P;
    P.j[0] = mk8f(gu_i,        WdT_i,        outp, 2048, 2048, 16384, 8192, 0, 30, 0, 2048);
    P.j[1] = mk8f(gu_i + 2048, WdT_i + 2048, dp1,  2048, 2048, 16384, 8192, 0, 30, 0, 2048);
    P.j[2] = mk8f(gu_i + 4096, WdT_i + 4096, dp2,  2048, 2048, 16384, 8192, 0, 30, 0, 2048);
    P.j[3] = mk8f(gu_i + 6144, WdT_i + 6144, dp3,  2048, 2048, 16384, 8192, 0, 30, 0, 2048);
    float* dstT[8] = {outp_t, dt1, dt2, dt3, dt4, dt5, dt6, dt7};
    for (int s = 0; s < 8; s++)
      P.j[4 + s] = mk8f(gu_t + s * 512, WdT_t + s * 512, dstT[s], 512, 1024,
                        8192, 4096, 0, 30, 0, 1024);
    int Mt[12] = {8, 8, 8, 8, 4, 4, 4, 4, 4, 4, 4, 4};
    launch8(P, 12, Mt);
  }
  reduce_down<<<2048, 256, 0, stream>>>(
      outp, dp1, dp2, dp3, x_img, 2048 * 2048 / 4,
      outp_t, dt1, dt2, dt3, dt4, dt5, dt6, dt7, x_txt, 1024 * 1024 / 4);
}